// Round 5
// baseline (549.533 us; speedup 1.0000x reference)
//
#include <hip/hip_runtime.h>
#include <math.h>

#define D_MODEL 512
#define NHEADS 8
#define DK 64
#define BATCH 2
#define SEQ 4096
// log2(e)/8 folded into Q projection: scores in log2 domain, softmax uses exp2.
#define ATTN_SCALE 0.18033688011112043f
#define SPLIT_SCALE 2048.0f     // 2^11: lo plane pre-scaled to stay in fp16 normal range
#define INV_SPLIT  (1.0f/2048.0f)

typedef _Float16 half8 __attribute__((ext_vector_type(8)));
typedef float f32x4 __attribute__((ext_vector_type(4)));

union Pk8 { _Float16 h[8]; uint4 u; };
union Pk4 { _Float16 h[4]; uint2 u; };

#define MFMA16(a, b, c) __builtin_amdgcn_mfma_f32_16x16x32_f16((a), (b), (c), 0, 0, 0)

// ============================================================================
// split4: one launch splits all four weight matrices into hi + lo*2048 planes.
// grid = (n/1024, 4)
// ============================================================================
__global__ __launch_bounds__(256)
void split4(const float* __restrict__ s0, const float* __restrict__ s1,
            const float* __restrict__ s2, const float* __restrict__ s3,
            _Float16* __restrict__ h0, _Float16* __restrict__ l0,
            _Float16* __restrict__ h1, _Float16* __restrict__ l1,
            _Float16* __restrict__ h2, _Float16* __restrict__ l2,
            _Float16* __restrict__ h3, _Float16* __restrict__ l3, int n) {
    const int w = blockIdx.y;
    const float* src = w == 0 ? s0 : (w == 1 ? s1 : (w == 2 ? s2 : s3));
    _Float16* hi = w == 0 ? h0 : (w == 1 ? h1 : (w == 2 ? h2 : h3));
    _Float16* lo = w == 0 ? l0 : (w == 1 ? l1 : (w == 2 ? l2 : l3));
    const int i = (blockIdx.x * 256 + threadIdx.x) * 4;
    if (i >= n) return;
    float4 v = *(const float4*)(src + i);
    Pk4 h, l;
    h.h[0] = (_Float16)v.x; h.h[1] = (_Float16)v.y;
    h.h[2] = (_Float16)v.z; h.h[3] = (_Float16)v.w;
    l.h[0] = (_Float16)((v.x - (float)h.h[0]) * SPLIT_SCALE);
    l.h[1] = (_Float16)((v.y - (float)h.h[1]) * SPLIT_SCALE);
    l.h[2] = (_Float16)((v.z - (float)h.h[2]) * SPLIT_SCALE);
    l.h[3] = (_Float16)((v.w - (float)h.h[3]) * SPLIT_SCALE);
    *(uint2*)(hi + i) = h.u;
    *(uint2*)(lo + i) = l.u;
}

// ============================================================================
// QKV projection GEMM, MFMA fp16. A fp16-hi at staging, W pre-split.
// z=0: Q (alpha=ATTN_SCALE)  z=1: K  z=2: V transposed per-head [b*8+h][d][s].
// Block 128x128, BK=64, 4 waves (2x2), software-pipelined staging.
// ============================================================================
__global__ __launch_bounds__(256)
void gemm_qkv(const float* __restrict__ Aq, const float* __restrict__ Ak,
              const float* __restrict__ Av,
              const _Float16* __restrict__ Whq, const _Float16* __restrict__ Wlq,
              const _Float16* __restrict__ Whk, const _Float16* __restrict__ Wlk,
              const _Float16* __restrict__ Whv, const _Float16* __restrict__ Wlv,
              const float* __restrict__ bq, const float* __restrict__ bk,
              const float* __restrict__ bv,
              _Float16* __restrict__ Qf, _Float16* __restrict__ Kf,
              _Float16* __restrict__ Vtf) {
    const int z = blockIdx.z;
    const float*     A    = z == 0 ? Aq  : (z == 1 ? Ak  : Av);
    const _Float16*  Wh   = z == 0 ? Whq : (z == 1 ? Whk : Whv);
    const _Float16*  Wl   = z == 0 ? Wlq : (z == 1 ? Wlk : Wlv);
    const float*     bias = z == 0 ? bq  : (z == 1 ? bk  : bv);

    __shared__ __align__(16) _Float16 sA [128 * 72];
    __shared__ __align__(16) _Float16 sWh[128 * 72];
    __shared__ __align__(16) _Float16 sWl[128 * 72];

    const int t    = threadIdx.x;
    const int lane = t & 63, wave = t >> 6;
    const int col  = lane & 15, quad = lane >> 4;
    const int wm   = (wave & 1) * 64, wn = (wave >> 1) * 64;
    const int m0   = blockIdx.y * 128, n0 = blockIdx.x * 128;

    f32x4 acc_h[4][4] = {};
    f32x4 acc_x[4][4] = {};

    float4 a0[4], a1[4];
    uint4  wh4[4], wl4[4];

    // prefetch chunk 0
    #pragma unroll
    for (int i2 = 0; i2 < 4; ++i2) {
        const int slot = t + i2 * 256;
        const int r = slot >> 3, sl = slot & 7;
        const float* ap = A + (size_t)(m0 + r) * 512 + sl * 8;
        a0[i2] = *(const float4*)ap;
        a1[i2] = *(const float4*)(ap + 4);
        wh4[i2] = *(const uint4*)(Wh + (size_t)(n0 + r) * 512 + sl * 8);
        wl4[i2] = *(const uint4*)(Wl + (size_t)(n0 + r) * 512 + sl * 8);
    }

    for (int k0 = 0; k0 < 512; k0 += 64) {
        __syncthreads();   // prior chunk frag reads complete
        #pragma unroll
        for (int i2 = 0; i2 < 4; ++i2) {
            const int slot = t + i2 * 256;
            const int r = slot >> 3, sl = slot & 7;
            Pk8 pk;
            pk.h[0] = (_Float16)a0[i2].x; pk.h[1] = (_Float16)a0[i2].y;
            pk.h[2] = (_Float16)a0[i2].z; pk.h[3] = (_Float16)a0[i2].w;
            pk.h[4] = (_Float16)a1[i2].x; pk.h[5] = (_Float16)a1[i2].y;
            pk.h[6] = (_Float16)a1[i2].z; pk.h[7] = (_Float16)a1[i2].w;
            *(uint4*)&sA [r * 72 + sl * 8] = pk.u;
            *(uint4*)&sWh[r * 72 + sl * 8] = wh4[i2];
            *(uint4*)&sWl[r * 72 + sl * 8] = wl4[i2];
        }
        __syncthreads();

        // prefetch next chunk (overlaps the MFMA section below)
        if (k0 + 64 < 512) {
            #pragma unroll
            for (int i2 = 0; i2 < 4; ++i2) {
                const int slot = t + i2 * 256;
                const int r = slot >> 3, sl = slot & 7;
                const float* ap = A + (size_t)(m0 + r) * 512 + k0 + 64 + sl * 8;
                a0[i2] = *(const float4*)ap;
                a1[i2] = *(const float4*)(ap + 4);
                wh4[i2] = *(const uint4*)(Wh + (size_t)(n0 + r) * 512 + k0 + 64 + sl * 8);
                wl4[i2] = *(const uint4*)(Wl + (size_t)(n0 + r) * 512 + k0 + 64 + sl * 8);
            }
        }

        #pragma unroll
        for (int kc = 0; kc < 2; ++kc) {
            half8 af[4], whf[4], wlf[4];
            #pragma unroll
            for (int mt = 0; mt < 4; ++mt)
                af[mt] = *(const half8*)&sA[(wm + mt * 16 + col) * 72 + kc * 32 + quad * 8];
            #pragma unroll
            for (int nt = 0; nt < 4; ++nt) {
                whf[nt] = *(const half8*)&sWh[(wn + nt * 16 + col) * 72 + kc * 32 + quad * 8];
                wlf[nt] = *(const half8*)&sWl[(wn + nt * 16 + col) * 72 + kc * 32 + quad * 8];
            }
            #pragma unroll
            for (int mt = 0; mt < 4; ++mt)
                #pragma unroll
                for (int nt = 0; nt < 4; ++nt) {
                    acc_h[mt][nt] = MFMA16(af[mt], whf[nt], acc_h[mt][nt]);
                    acc_x[mt][nt] = MFMA16(af[mt], wlf[nt], acc_x[mt][nt]);
                }
        }
    }

    float bv4[4];
    #pragma unroll
    for (int nt = 0; nt < 4; ++nt) bv4[nt] = bias[n0 + wn + nt * 16 + col];

    if (z < 2) {
        _Float16* Out = z == 0 ? Qf : Kf;
        const float alpha = z == 0 ? ATTN_SCALE : 1.0f;
        #pragma unroll
        for (int mt = 0; mt < 4; ++mt) {
            const int m = m0 + wm + mt * 16 + quad * 4;
            #pragma unroll
            for (int nt = 0; nt < 4; ++nt) {
                const int n = n0 + wn + nt * 16 + col;
                #pragma unroll
                for (int r = 0; r < 4; ++r) {
                    const float c = (acc_h[mt][nt][r] + acc_x[mt][nt][r] * INV_SPLIT + bv4[nt]) * alpha;
                    Out[(size_t)(m + r) * 512 + n] = (_Float16)c;
                }
            }
        }
    } else {
        #pragma unroll
        for (int mt = 0; mt < 4; ++mt) {
            const int m = m0 + wm + mt * 16 + quad * 4;
            const int b = m >> 12, s = m & (SEQ - 1);
            #pragma unroll
            for (int nt = 0; nt < 4; ++nt) {
                const int n = n0 + wn + nt * 16 + col;
                const int hh = n >> 6, d = n & (DK - 1);
                Pk4 p;
                #pragma unroll
                for (int r = 0; r < 4; ++r)
                    p.h[r] = (_Float16)(acc_h[mt][nt][r] + acc_x[mt][nt][r] * INV_SPLIT + bv4[nt]);
                *(uint2*)&Vtf[((size_t)((b * NHEADS + hh) * DK + d)) * SEQ + s] = p.u;
            }
        }
    }
}

// ============================================================================
// Flash attention, fp16 MFMA. 64 queries/block (16/wave), 64-key iterations.
// Grid 1024 blocks -> 4 blocks/CU (16 waves/CU). Pipelined K/V staging.
// ============================================================================
__global__ __launch_bounds__(256)
void attn_mfma(const _Float16* __restrict__ Qf, const _Float16* __restrict__ Kf,
               const _Float16* __restrict__ Vtf,
               _Float16* __restrict__ Oh, _Float16* __restrict__ Ol) {
    __shared__ __align__(16) _Float16 sQ[64 * 72];   // becomes per-wave P after Q-frag load
    __shared__ __align__(16) _Float16 sK[64 * 72];
    __shared__ __align__(16) _Float16 sV[64 * 72];   // dim-major (V^T)

    const int t    = threadIdx.x;
    const int lane = t & 63;
    const int wave = t >> 6;
    const int col  = lane & 15;
    const int quad = lane >> 4;

    const int q0 = blockIdx.x * 64;
    const int h  = blockIdx.y;
    const int b  = blockIdx.z;

    const size_t rowBase = (size_t)b * SEQ;
    const size_t vBase   = ((size_t)(b * NHEADS + h)) * DK * SEQ;

    // ---- stage Q tile (64 x 64 halves): 512 slots, 2/thread ----
    {
        uint4 qv[2];
        #pragma unroll
        for (int i2 = 0; i2 < 2; ++i2) {
            const int slot = t + i2 * 256;
            const int r = slot >> 3, sl = slot & 7;
            qv[i2] = *(const uint4*)(Qf + (rowBase + q0 + r) * 512 + h * 64 + sl * 8);
        }
        #pragma unroll
        for (int i2 = 0; i2 < 2; ++i2) {
            const int slot = t + i2 * 256;
            const int r = slot >> 3, sl = slot & 7;
            *(uint4*)&sQ[r * 72 + sl * 8] = qv[i2];
        }
    }
    __syncthreads();

    half8 qf[2];
    #pragma unroll
    for (int kc = 0; kc < 2; ++kc)
        qf[kc] = *(const half8*)&sQ[(wave * 16 + col) * 72 + kc * 32 + quad * 8];
    __syncthreads();   // sQ dead -> per-wave P staging

    _Float16* Ps = sQ + wave * 16 * 72;   // 16 rows x 72, private to this wave

    float m_r = -INFINITY;
    float l_r = 0.0f;
    f32x4 of[4] = {};

    // ---- prefetch first K/V tile ----
    uint4 kv[2], vv[2];
    #pragma unroll
    for (int i2 = 0; i2 < 2; ++i2) {
        const int slot = t + i2 * 256;
        const int r = slot >> 3, sl = slot & 7;
        kv[i2] = *(const uint4*)(Kf + (rowBase + r) * 512 + h * 64 + sl * 8);
        vv[i2] = *(const uint4*)(Vtf + vBase + (size_t)r * SEQ + sl * 8);
    }

    for (int k0 = 0; k0 < SEQ; k0 += 64) {
        __syncthreads();   // prior iteration done with sK/sV
        #pragma unroll
        for (int i2 = 0; i2 < 2; ++i2) {
            const int slot = t + i2 * 256;
            const int r = slot >> 3, sl = slot & 7;
            *(uint4*)&sK[r * 72 + sl * 8] = kv[i2];
            *(uint4*)&sV[r * 72 + sl * 8] = vv[i2];
        }
        __syncthreads();

        // prefetch next K/V tile (overlaps MFMA + softmax below)
        if (k0 + 64 < SEQ) {
            #pragma unroll
            for (int i2 = 0; i2 < 2; ++i2) {
                const int slot = t + i2 * 256;
                const int r = slot >> 3, sl = slot & 7;
                kv[i2] = *(const uint4*)(Kf + (rowBase + k0 + 64 + r) * 512 + h * 64 + sl * 8);
                vv[i2] = *(const uint4*)(Vtf + vBase + (size_t)r * SEQ + k0 + 64 + sl * 8);
            }
        }

        // ---- S^T = K · Q^T : 8 MFMA ----
        f32x4 sf[4] = {};
        #pragma unroll
        for (int kc = 0; kc < 2; ++kc)
            #pragma unroll
            for (int kt = 0; kt < 4; ++kt) {
                half8 kf = *(const half8*)&sK[(kt * 16 + col) * 72 + kc * 32 + quad * 8];
                sf[kt] = MFMA16(kf, qf[kc], sf[kt]);
            }

        // ---- online softmax (log2 domain), per-lane state ----
        float mx = sf[0][0];
        #pragma unroll
        for (int kt = 0; kt < 4; ++kt)
            #pragma unroll
            for (int r = 0; r < 4; ++r)
                mx = fmaxf(mx, sf[kt][r]);
        mx = fmaxf(mx, __shfl_xor(mx, 16));
        mx = fmaxf(mx, __shfl_xor(mx, 32));
        const float mnew = fmaxf(m_r, mx);
        if (__any(mnew > m_r)) {           // exact skip: al would be 1.0
            const float al = exp2f(m_r - mnew);
            l_r *= al;
            #pragma unroll
            for (int dt = 0; dt < 4; ++dt)
                #pragma unroll
                for (int r = 0; r < 4; ++r)
                    of[dt][r] *= al;
        }
        m_r = mnew;

        float rs = 0.0f;
        #pragma unroll
        for (int kt = 0; kt < 4; ++kt) {
            const float p0 = exp2f(sf[kt][0] - mnew);
            const float p1 = exp2f(sf[kt][1] - mnew);
            const float p2 = exp2f(sf[kt][2] - mnew);
            const float p3 = exp2f(sf[kt][3] - mnew);
            rs += (p0 + p1) + (p2 + p3);
            Pk4 z;
            z.h[0] = (_Float16)p0; z.h[1] = (_Float16)p1;
            z.h[2] = (_Float16)p2; z.h[3] = (_Float16)p3;
            *(uint2*)&Ps[col * 72 + kt * 16 + quad * 4] = z.u;
        }
        rs += __shfl_xor(rs, 16);
        rs += __shfl_xor(rs, 32);
        l_r += rs;

        // ---- O^T += V^T · P^T : 8 MFMA (intra-wave Ps round-trip, no barrier) ----
        #pragma unroll
        for (int kc = 0; kc < 2; ++kc) {
            half8 pf = *(const half8*)&Ps[col * 72 + kc * 32 + quad * 8];
            #pragma unroll
            for (int dt = 0; dt < 4; ++dt) {
                half8 vf = *(const half8*)&sV[(dt * 16 + col) * 72 + kc * 32 + quad * 8];
                of[dt] = MFMA16(vf, pf, of[dt]);
            }
        }
    }

    // ---- normalize, store hi + lo' planes ----
    const float inv = 1.0f / l_r;
    const size_t base = (rowBase + q0 + wave * 16 + col) * 512 + h * 64;
    #pragma unroll
    for (int dt = 0; dt < 4; ++dt) {
        float v[4];
        #pragma unroll
        for (int r = 0; r < 4; ++r) v[r] = of[dt][r] * inv;
        Pk4 hh, ll;
        #pragma unroll
        for (int r = 0; r < 4; ++r) {
            hh.h[r] = (_Float16)v[r];
            ll.h[r] = (_Float16)((v[r] - (float)hh.h[r]) * SPLIT_SCALE);
        }
        *(uint2*)(Oh + base + dt * 16 + quad * 4) = hh.u;
        *(uint2*)(Ol + base + dt * 16 + quad * 4) = ll.u;
    }
}

// ============================================================================
// Output projection: full split-fp16 (3 MFMA/tile), fp32 out + bias. Pipelined.
// ============================================================================
__global__ __launch_bounds__(256)
void gemm_out(const _Float16* __restrict__ Ah, const _Float16* __restrict__ Al,
              const _Float16* __restrict__ Wh, const _Float16* __restrict__ Wl,
              const float* __restrict__ bias, float* __restrict__ C) {
    __shared__ __align__(16) _Float16 sAh[128 * 72];
    __shared__ __align__(16) _Float16 sAl[128 * 72];
    __shared__ __align__(16) _Float16 sWh[128 * 72];
    __shared__ __align__(16) _Float16 sWl[128 * 72];

    const int t    = threadIdx.x;
    const int lane = t & 63, wave = t >> 6;
    const int col  = lane & 15, quad = lane >> 4;
    const int wm   = (wave & 1) * 64, wn = (wave >> 1) * 64;
    const int m0   = blockIdx.y * 128, n0 = blockIdx.x * 128;

    f32x4 acc_h[4][4] = {};
    f32x4 acc_x[4][4] = {};

    uint4 ah4[4], al4[4], wh4[4], wl4[4];
    #pragma unroll
    for (int i2 = 0; i2 < 4; ++i2) {
        const int slot = t + i2 * 256;
        const int r = slot >> 3, sl = slot & 7;
        ah4[i2] = *(const uint4*)(Ah + (size_t)(m0 + r) * 512 + sl * 8);
        al4[i2] = *(const uint4*)(Al + (size_t)(m0 + r) * 512 + sl * 8);
        wh4[i2] = *(const uint4*)(Wh + (size_t)(n0 + r) * 512 + sl * 8);
        wl4[i2] = *(const uint4*)(Wl + (size_t)(n0 + r) * 512 + sl * 8);
    }

    for (int k0 = 0; k0 < 512; k0 += 64) {
        __syncthreads();
        #pragma unroll
        for (int i2 = 0; i2 < 4; ++i2) {
            const int slot = t + i2 * 256;
            const int r = slot >> 3, sl = slot & 7;
            *(uint4*)&sAh[r * 72 + sl * 8] = ah4[i2];
            *(uint4*)&sAl[r * 72 + sl * 8] = al4[i2];
            *(uint4*)&sWh[r * 72 + sl * 8] = wh4[i2];
            *(uint4*)&sWl[r * 72 + sl * 8] = wl4[i2];
        }
        __syncthreads();

        if (k0 + 64 < 512) {
            #pragma unroll
            for (int i2 = 0; i2 < 4; ++i2) {
                const int slot = t + i2 * 256;
                const int r = slot >> 3, sl = slot & 7;
                ah4[i2] = *(const uint4*)(Ah + (size_t)(m0 + r) * 512 + k0 + 64 + sl * 8);
                al4[i2] = *(const uint4*)(Al + (size_t)(m0 + r) * 512 + k0 + 64 + sl * 8);
                wh4[i2] = *(const uint4*)(Wh + (size_t)(n0 + r) * 512 + k0 + 64 + sl * 8);
                wl4[i2] = *(const uint4*)(Wl + (size_t)(n0 + r) * 512 + k0 + 64 + sl * 8);
            }
        }

        #pragma unroll
        for (int kc = 0; kc < 2; ++kc) {
            half8 ahf[4], alf[4], whf[4], wlf[4];
            #pragma unroll
            for (int mt = 0; mt < 4; ++mt) {
                ahf[mt] = *(const half8*)&sAh[(wm + mt * 16 + col) * 72 + kc * 32 + quad * 8];
                alf[mt] = *(const half8*)&sAl[(wm + mt * 16 + col) * 72 + kc * 32 + quad * 8];
            }
            #pragma unroll
            for (int nt = 0; nt < 4; ++nt) {
                whf[nt] = *(const half8*)&sWh[(wn + nt * 16 + col) * 72 + kc * 32 + quad * 8];
                wlf[nt] = *(const half8*)&sWl[(wn + nt * 16 + col) * 72 + kc * 32 + quad * 8];
            }
            #pragma unroll
            for (int mt = 0; mt < 4; ++mt)
                #pragma unroll
                for (int nt = 0; nt < 4; ++nt) {
                    acc_h[mt][nt] = MFMA16(ahf[mt], whf[nt], acc_h[mt][nt]);
                    acc_x[mt][nt] = MFMA16(ahf[mt], wlf[nt], acc_x[mt][nt]);
                    acc_x[mt][nt] = MFMA16(alf[mt], whf[nt], acc_x[mt][nt]);
                }
        }
    }

    float bv4[4];
    #pragma unroll
    for (int nt = 0; nt < 4; ++nt) bv4[nt] = bias[n0 + wn + nt * 16 + col];

    #pragma unroll
    for (int mt = 0; mt < 4; ++mt) {
        const int m = m0 + wm + mt * 16 + quad * 4;
        #pragma unroll
        for (int nt = 0; nt < 4; ++nt) {
            const int n = n0 + wn + nt * 16 + col;
            #pragma unroll
            for (int r = 0; r < 4; ++r)
                C[(size_t)(m + r) * 512 + n] =
                    acc_h[mt][nt][r] + acc_x[mt][nt][r] * INV_SPLIT + bv4[nt];
        }
    }
}

// ============================================================================
extern "C" void kernel_launch(void* const* d_in, const int* in_sizes, int n_in,
                              void* d_out, int out_size, void* d_ws, size_t ws_size,
                              hipStream_t stream) {
    const float* query = (const float*)d_in[0];
    const float* key   = (const float*)d_in[1];
    const float* value = (const float*)d_in[2];
    const float* w_q   = (const float*)d_in[3];
    const float* b_q   = (const float*)d_in[4];
    const float* w_k   = (const float*)d_in[5];
    const float* b_k   = (const float*)d_in[6];
    const float* w_v   = (const float*)d_in[7];
    const float* b_v   = (const float*)d_in[8];
    const float* w_o   = (const float*)d_in[9];
    const float* b_o   = (const float*)d_in[10];
    float* out = (float*)d_out;

    const int WN = D_MODEL * D_MODEL;          // 262144
    _Float16* base = (_Float16*)d_ws;
    _Float16* whq = base;            _Float16* wlq = whq + WN;
    _Float16* whk = wlq + WN;        _Float16* wlk = whk + WN;
    _Float16* whv = wlk + WN;        _Float16* wlv = whv + WN;
    _Float16* who = wlv + WN;        _Float16* wlo = who + WN;
    const size_t plane = (size_t)BATCH * SEQ * D_MODEL;
    _Float16* Qf  = wlo + WN;
    _Float16* Kf  = Qf + plane;
    _Float16* Vtf = Kf + plane;
    _Float16* Oh  = Vtf + plane;
    _Float16* Ol  = Oh + plane;      // total ws: 4 MB + 5*8 MB = 44 MB

    dim3 blk(256);

    hipLaunchKernelGGL(split4, dim3(WN / 1024, 4), blk, 0, stream,
                       w_q, w_k, w_v, w_o,
                       whq, wlq, whk, wlk, whv, wlv, who, wlo, WN);

    hipLaunchKernelGGL(gemm_qkv, dim3(D_MODEL / 128, BATCH * SEQ / 128, 3), blk, 0, stream,
                       query, key, value,
                       whq, wlq, whk, wlk, whv, wlv,
                       b_q, b_k, b_v, Qf, Kf, Vtf);

    hipLaunchKernelGGL(attn_mfma, dim3(SEQ / 64, NHEADS, BATCH), blk, 0, stream,
                       Qf, Kf, Vtf, Oh, Ol);

    hipLaunchKernelGGL(gemm_out, dim3(D_MODEL / 128, BATCH * SEQ / 128), blk, 0, stream,
                       Oh, Ol, who, wlo, b_o, out);
}

// Round 6
// 518.150 us; speedup vs baseline: 1.0606x; 1.0606x over previous
//
#include <hip/hip_runtime.h>
#include <math.h>

#define D_MODEL 512
#define NHEADS 8
#define DK 64
#define BATCH 2
#define SEQ 4096
// log2(e)/8 folded into Q projection: scores in log2 domain, softmax uses exp2.
#define ATTN_SCALE 0.18033688011112043f
#define SPLIT_SCALE 2048.0f     // 2^11: lo plane pre-scaled to stay in fp16 normal range
#define INV_SPLIT  (1.0f/2048.0f)

typedef _Float16 half8 __attribute__((ext_vector_type(8)));
typedef float f32x4 __attribute__((ext_vector_type(4)));

union Pk8 { _Float16 h[8]; uint4 u; };
union Pk4 { _Float16 h[4]; uint2 u; };

#define MFMA16(a, b, c) __builtin_amdgcn_mfma_f32_16x16x32_f16((a), (b), (c), 0, 0, 0)

// ============================================================================
// split4: hi planes for all four weight matrices; lo plane only needed for w_o
// (out-projection keeps the full split; QKV uses hi-only — round-4 evidence:
// weight-lo contributes <1e-3 absmax). Still writes all lo planes (cheap).
// grid = (n/1024, 4)
// ============================================================================
__global__ __launch_bounds__(256)
void split4(const float* __restrict__ s0, const float* __restrict__ s1,
            const float* __restrict__ s2, const float* __restrict__ s3,
            _Float16* __restrict__ h0, _Float16* __restrict__ l0,
            _Float16* __restrict__ h1, _Float16* __restrict__ l1,
            _Float16* __restrict__ h2, _Float16* __restrict__ l2,
            _Float16* __restrict__ h3, _Float16* __restrict__ l3, int n) {
    const int w = blockIdx.y;
    const float* src = w == 0 ? s0 : (w == 1 ? s1 : (w == 2 ? s2 : s3));
    _Float16* hi = w == 0 ? h0 : (w == 1 ? h1 : (w == 2 ? h2 : h3));
    _Float16* lo = w == 0 ? l0 : (w == 1 ? l1 : (w == 2 ? l2 : l3));
    const int i = (blockIdx.x * 256 + threadIdx.x) * 4;
    if (i >= n) return;
    float4 v = *(const float4*)(src + i);
    Pk4 h, l;
    h.h[0] = (_Float16)v.x; h.h[1] = (_Float16)v.y;
    h.h[2] = (_Float16)v.z; h.h[3] = (_Float16)v.w;
    l.h[0] = (_Float16)((v.x - (float)h.h[0]) * SPLIT_SCALE);
    l.h[1] = (_Float16)((v.y - (float)h.h[1]) * SPLIT_SCALE);
    l.h[2] = (_Float16)((v.z - (float)h.h[2]) * SPLIT_SCALE);
    l.h[3] = (_Float16)((v.w - (float)h.h[3]) * SPLIT_SCALE);
    *(uint2*)(hi + i) = h.u;
    *(uint2*)(lo + i) = l.u;
}

// ============================================================================
// QKV projection GEMM, MFMA fp16, hi-only weights (1 MFMA/tile).
// z=0: Q (alpha=ATTN_SCALE)  z=1: K  z=2: V transposed per-head [b*8+h][d][s].
// Block 128x128, BK=64, 4 waves (2x2), software-pipelined staging.
// launch_bounds(256,2): VGPR cap 256 — prevents the round-5 spill squeeze.
// ============================================================================
__global__ __launch_bounds__(256, 2)
void gemm_qkv(const float* __restrict__ Aq, const float* __restrict__ Ak,
              const float* __restrict__ Av,
              const _Float16* __restrict__ Whq, const _Float16* __restrict__ Whk,
              const _Float16* __restrict__ Whv,
              const float* __restrict__ bq, const float* __restrict__ bk,
              const float* __restrict__ bv,
              _Float16* __restrict__ Qf, _Float16* __restrict__ Kf,
              _Float16* __restrict__ Vtf) {
    const int z = blockIdx.z;
    const float*     A    = z == 0 ? Aq  : (z == 1 ? Ak  : Av);
    const _Float16*  Wh   = z == 0 ? Whq : (z == 1 ? Whk : Whv);
    const float*     bias = z == 0 ? bq  : (z == 1 ? bk  : bv);

    __shared__ __align__(16) _Float16 sA [128 * 72];
    __shared__ __align__(16) _Float16 sWh[128 * 72];

    const int t    = threadIdx.x;
    const int lane = t & 63, wave = t >> 6;
    const int col  = lane & 15, quad = lane >> 4;
    const int wm   = (wave & 1) * 64, wn = (wave >> 1) * 64;
    const int m0   = blockIdx.y * 128, n0 = blockIdx.x * 128;

    f32x4 acc[4][4] = {};

    float4 a0[4], a1[4];
    uint4  wh4[4];

    // prefetch chunk 0
    #pragma unroll
    for (int i2 = 0; i2 < 4; ++i2) {
        const int slot = t + i2 * 256;
        const int r = slot >> 3, sl = slot & 7;
        const float* ap = A + (size_t)(m0 + r) * 512 + sl * 8;
        a0[i2] = *(const float4*)ap;
        a1[i2] = *(const float4*)(ap + 4);
        wh4[i2] = *(const uint4*)(Wh + (size_t)(n0 + r) * 512 + sl * 8);
    }

    for (int k0 = 0; k0 < 512; k0 += 64) {
        __syncthreads();   // prior chunk frag reads complete
        #pragma unroll
        for (int i2 = 0; i2 < 4; ++i2) {
            const int slot = t + i2 * 256;
            const int r = slot >> 3, sl = slot & 7;
            Pk8 pk;
            pk.h[0] = (_Float16)a0[i2].x; pk.h[1] = (_Float16)a0[i2].y;
            pk.h[2] = (_Float16)a0[i2].z; pk.h[3] = (_Float16)a0[i2].w;
            pk.h[4] = (_Float16)a1[i2].x; pk.h[5] = (_Float16)a1[i2].y;
            pk.h[6] = (_Float16)a1[i2].z; pk.h[7] = (_Float16)a1[i2].w;
            *(uint4*)&sA [r * 72 + sl * 8] = pk.u;
            *(uint4*)&sWh[r * 72 + sl * 8] = wh4[i2];
        }
        __syncthreads();

        // prefetch next chunk (overlaps the MFMA section below)
        if (k0 + 64 < 512) {
            #pragma unroll
            for (int i2 = 0; i2 < 4; ++i2) {
                const int slot = t + i2 * 256;
                const int r = slot >> 3, sl = slot & 7;
                const float* ap = A + (size_t)(m0 + r) * 512 + k0 + 64 + sl * 8;
                a0[i2] = *(const float4*)ap;
                a1[i2] = *(const float4*)(ap + 4);
                wh4[i2] = *(const uint4*)(Wh + (size_t)(n0 + r) * 512 + k0 + 64 + sl * 8);
            }
        }

        #pragma unroll
        for (int kc = 0; kc < 2; ++kc) {
            half8 af[4], whf[4];
            #pragma unroll
            for (int mt = 0; mt < 4; ++mt)
                af[mt] = *(const half8*)&sA[(wm + mt * 16 + col) * 72 + kc * 32 + quad * 8];
            #pragma unroll
            for (int nt = 0; nt < 4; ++nt)
                whf[nt] = *(const half8*)&sWh[(wn + nt * 16 + col) * 72 + kc * 32 + quad * 8];
            #pragma unroll
            for (int mt = 0; mt < 4; ++mt)
                #pragma unroll
                for (int nt = 0; nt < 4; ++nt)
                    acc[mt][nt] = MFMA16(af[mt], whf[nt], acc[mt][nt]);
        }
    }

    float bv4[4];
    #pragma unroll
    for (int nt = 0; nt < 4; ++nt) bv4[nt] = bias[n0 + wn + nt * 16 + col];

    if (z < 2) {
        _Float16* Out = z == 0 ? Qf : Kf;
        const float alpha = z == 0 ? ATTN_SCALE : 1.0f;
        #pragma unroll
        for (int mt = 0; mt < 4; ++mt) {
            const int m = m0 + wm + mt * 16 + quad * 4;
            #pragma unroll
            for (int nt = 0; nt < 4; ++nt) {
                const int n = n0 + wn + nt * 16 + col;
                #pragma unroll
                for (int r = 0; r < 4; ++r)
                    Out[(size_t)(m + r) * 512 + n] = (_Float16)((acc[mt][nt][r] + bv4[nt]) * alpha);
            }
        }
    } else {
        #pragma unroll
        for (int mt = 0; mt < 4; ++mt) {
            const int m = m0 + wm + mt * 16 + quad * 4;
            const int b = m >> 12, s = m & (SEQ - 1);
            #pragma unroll
            for (int nt = 0; nt < 4; ++nt) {
                const int n = n0 + wn + nt * 16 + col;
                const int hh = n >> 6, d = n & (DK - 1);
                Pk4 p;
                #pragma unroll
                for (int r = 0; r < 4; ++r)
                    p.h[r] = (_Float16)(acc[mt][nt][r] + bv4[nt]);
                *(uint2*)&Vtf[((size_t)((b * NHEADS + hh) * DK + d)) * SEQ + s] = p.u;
            }
        }
    }
}

// ============================================================================
// Flash attention, fp16 MFMA. 64 queries/block (16/wave), 64-key iterations.
// launch_bounds(256,4): VGPR cap 128 (need ~90) — prevents the round-5
// 44-VGPR spill squeeze (528 MB scratch writes). 4 blocks/CU, pipelined K/V.
// ============================================================================
__global__ __launch_bounds__(256, 4)
void attn_mfma(const _Float16* __restrict__ Qf, const _Float16* __restrict__ Kf,
               const _Float16* __restrict__ Vtf,
               _Float16* __restrict__ Oh, _Float16* __restrict__ Ol) {
    __shared__ __align__(16) _Float16 sQ[64 * 72];   // becomes per-wave P after Q-frag load
    __shared__ __align__(16) _Float16 sK[64 * 72];
    __shared__ __align__(16) _Float16 sV[64 * 72];   // dim-major (V^T)

    const int t    = threadIdx.x;
    const int lane = t & 63;
    const int wave = t >> 6;
    const int col  = lane & 15;
    const int quad = lane >> 4;

    const int q0 = blockIdx.x * 64;
    const int h  = blockIdx.y;
    const int b  = blockIdx.z;

    const size_t rowBase = (size_t)b * SEQ;
    const size_t vBase   = ((size_t)(b * NHEADS + h)) * DK * SEQ;

    // ---- stage Q tile (64 x 64 halves): 512 slots, 2/thread ----
    {
        uint4 qv[2];
        #pragma unroll
        for (int i2 = 0; i2 < 2; ++i2) {
            const int slot = t + i2 * 256;
            const int r = slot >> 3, sl = slot & 7;
            qv[i2] = *(const uint4*)(Qf + (rowBase + q0 + r) * 512 + h * 64 + sl * 8);
        }
        #pragma unroll
        for (int i2 = 0; i2 < 2; ++i2) {
            const int slot = t + i2 * 256;
            const int r = slot >> 3, sl = slot & 7;
            *(uint4*)&sQ[r * 72 + sl * 8] = qv[i2];
        }
    }
    __syncthreads();

    half8 qf[2];
    #pragma unroll
    for (int kc = 0; kc < 2; ++kc)
        qf[kc] = *(const half8*)&sQ[(wave * 16 + col) * 72 + kc * 32 + quad * 8];
    __syncthreads();   // sQ dead -> per-wave P staging

    _Float16* Ps = sQ + wave * 16 * 72;   // 16 rows x 72, private to this wave

    float m_r = -INFINITY;
    float l_r = 0.0f;
    f32x4 of[4] = {};

    // ---- prefetch first K/V tile ----
    uint4 kv[2], vv[2];
    #pragma unroll
    for (int i2 = 0; i2 < 2; ++i2) {
        const int slot = t + i2 * 256;
        const int r = slot >> 3, sl = slot & 7;
        kv[i2] = *(const uint4*)(Kf + (rowBase + r) * 512 + h * 64 + sl * 8);
        vv[i2] = *(const uint4*)(Vtf + vBase + (size_t)r * SEQ + sl * 8);
    }

    for (int k0 = 0; k0 < SEQ; k0 += 64) {
        __syncthreads();   // prior iteration done with sK/sV
        #pragma unroll
        for (int i2 = 0; i2 < 2; ++i2) {
            const int slot = t + i2 * 256;
            const int r = slot >> 3, sl = slot & 7;
            *(uint4*)&sK[r * 72 + sl * 8] = kv[i2];
            *(uint4*)&sV[r * 72 + sl * 8] = vv[i2];
        }
        __syncthreads();

        // prefetch next K/V tile (overlaps MFMA + softmax below)
        if (k0 + 64 < SEQ) {
            #pragma unroll
            for (int i2 = 0; i2 < 2; ++i2) {
                const int slot = t + i2 * 256;
                const int r = slot >> 3, sl = slot & 7;
                kv[i2] = *(const uint4*)(Kf + (rowBase + k0 + 64 + r) * 512 + h * 64 + sl * 8);
                vv[i2] = *(const uint4*)(Vtf + vBase + (size_t)r * SEQ + k0 + 64 + sl * 8);
            }
        }

        // ---- S^T = K · Q^T : 8 MFMA ----
        f32x4 sf[4] = {};
        #pragma unroll
        for (int kc = 0; kc < 2; ++kc)
            #pragma unroll
            for (int kt = 0; kt < 4; ++kt) {
                half8 kf = *(const half8*)&sK[(kt * 16 + col) * 72 + kc * 32 + quad * 8];
                sf[kt] = MFMA16(kf, qf[kc], sf[kt]);
            }

        // ---- online softmax (log2 domain), per-lane state ----
        float mx = sf[0][0];
        #pragma unroll
        for (int kt = 0; kt < 4; ++kt)
            #pragma unroll
            for (int r = 0; r < 4; ++r)
                mx = fmaxf(mx, sf[kt][r]);
        mx = fmaxf(mx, __shfl_xor(mx, 16));
        mx = fmaxf(mx, __shfl_xor(mx, 32));
        const float mnew = fmaxf(m_r, mx);
        if (__any(mnew > m_r)) {           // exact skip: al would be 1.0
            const float al = exp2f(m_r - mnew);
            l_r *= al;
            #pragma unroll
            for (int dt = 0; dt < 4; ++dt)
                #pragma unroll
                for (int r = 0; r < 4; ++r)
                    of[dt][r] *= al;
        }
        m_r = mnew;

        float rs = 0.0f;
        #pragma unroll
        for (int kt = 0; kt < 4; ++kt) {
            const float p0 = exp2f(sf[kt][0] - mnew);
            const float p1 = exp2f(sf[kt][1] - mnew);
            const float p2 = exp2f(sf[kt][2] - mnew);
            const float p3 = exp2f(sf[kt][3] - mnew);
            rs += (p0 + p1) + (p2 + p3);
            Pk4 z;
            z.h[0] = (_Float16)p0; z.h[1] = (_Float16)p1;
            z.h[2] = (_Float16)p2; z.h[3] = (_Float16)p3;
            *(uint2*)&Ps[col * 72 + kt * 16 + quad * 4] = z.u;
        }
        rs += __shfl_xor(rs, 16);
        rs += __shfl_xor(rs, 32);
        l_r += rs;

        // ---- O^T += V^T · P^T : 8 MFMA (intra-wave Ps round-trip, no barrier) ----
        #pragma unroll
        for (int kc = 0; kc < 2; ++kc) {
            half8 pf = *(const half8*)&Ps[col * 72 + kc * 32 + quad * 8];
            #pragma unroll
            for (int dt = 0; dt < 4; ++dt) {
                half8 vf = *(const half8*)&sV[(dt * 16 + col) * 72 + kc * 32 + quad * 8];
                of[dt] = MFMA16(vf, pf, of[dt]);
            }
        }
    }

    // ---- normalize, store hi + lo' planes ----
    const float inv = 1.0f / l_r;
    const size_t base = (rowBase + q0 + wave * 16 + col) * 512 + h * 64;
    #pragma unroll
    for (int dt = 0; dt < 4; ++dt) {
        float v[4];
        #pragma unroll
        for (int r = 0; r < 4; ++r) v[r] = of[dt][r] * inv;
        Pk4 hh, ll;
        #pragma unroll
        for (int r = 0; r < 4; ++r) {
            hh.h[r] = (_Float16)v[r];
            ll.h[r] = (_Float16)((v[r] - (float)hh.h[r]) * SPLIT_SCALE);
        }
        *(uint2*)(Oh + base + dt * 16 + quad * 4) = hh.u;
        *(uint2*)(Ol + base + dt * 16 + quad * 4) = ll.u;
    }
}

// ============================================================================
// Output projection: full split-fp16 (3 MFMA/tile), fp32 out + bias. Pipelined.
// launch_bounds(256,1): needs ~280 unified VGPR+AGPR — never spill.
// ============================================================================
__global__ __launch_bounds__(256, 1)
void gemm_out(const _Float16* __restrict__ Ah, const _Float16* __restrict__ Al,
              const _Float16* __restrict__ Wh, const _Float16* __restrict__ Wl,
              const float* __restrict__ bias, float* __restrict__ C) {
    __shared__ __align__(16) _Float16 sAh[128 * 72];
    __shared__ __align__(16) _Float16 sAl[128 * 72];
    __shared__ __align__(16) _Float16 sWh[128 * 72];
    __shared__ __align__(16) _Float16 sWl[128 * 72];

    const int t    = threadIdx.x;
    const int lane = t & 63, wave = t >> 6;
    const int col  = lane & 15, quad = lane >> 4;
    const int wm   = (wave & 1) * 64, wn = (wave >> 1) * 64;
    const int m0   = blockIdx.y * 128, n0 = blockIdx.x * 128;

    f32x4 acc_h[4][4] = {};
    f32x4 acc_x[4][4] = {};

    uint4 ah4[4], al4[4], wh4[4], wl4[4];
    #pragma unroll
    for (int i2 = 0; i2 < 4; ++i2) {
        const int slot = t + i2 * 256;
        const int r = slot >> 3, sl = slot & 7;
        ah4[i2] = *(const uint4*)(Ah + (size_t)(m0 + r) * 512 + sl * 8);
        al4[i2] = *(const uint4*)(Al + (size_t)(m0 + r) * 512 + sl * 8);
        wh4[i2] = *(const uint4*)(Wh + (size_t)(n0 + r) * 512 + sl * 8);
        wl4[i2] = *(const uint4*)(Wl + (size_t)(n0 + r) * 512 + sl * 8);
    }

    for (int k0 = 0; k0 < 512; k0 += 64) {
        __syncthreads();
        #pragma unroll
        for (int i2 = 0; i2 < 4; ++i2) {
            const int slot = t + i2 * 256;
            const int r = slot >> 3, sl = slot & 7;
            *(uint4*)&sAh[r * 72 + sl * 8] = ah4[i2];
            *(uint4*)&sAl[r * 72 + sl * 8] = al4[i2];
            *(uint4*)&sWh[r * 72 + sl * 8] = wh4[i2];
            *(uint4*)&sWl[r * 72 + sl * 8] = wl4[i2];
        }
        __syncthreads();

        if (k0 + 64 < 512) {
            #pragma unroll
            for (int i2 = 0; i2 < 4; ++i2) {
                const int slot = t + i2 * 256;
                const int r = slot >> 3, sl = slot & 7;
                ah4[i2] = *(const uint4*)(Ah + (size_t)(m0 + r) * 512 + k0 + 64 + sl * 8);
                al4[i2] = *(const uint4*)(Al + (size_t)(m0 + r) * 512 + k0 + 64 + sl * 8);
                wh4[i2] = *(const uint4*)(Wh + (size_t)(n0 + r) * 512 + k0 + 64 + sl * 8);
                wl4[i2] = *(const uint4*)(Wl + (size_t)(n0 + r) * 512 + k0 + 64 + sl * 8);
            }
        }

        #pragma unroll
        for (int kc = 0; kc < 2; ++kc) {
            half8 ahf[4], alf[4], whf[4], wlf[4];
            #pragma unroll
            for (int mt = 0; mt < 4; ++mt) {
                ahf[mt] = *(const half8*)&sAh[(wm + mt * 16 + col) * 72 + kc * 32 + quad * 8];
                alf[mt] = *(const half8*)&sAl[(wm + mt * 16 + col) * 72 + kc * 32 + quad * 8];
            }
            #pragma unroll
            for (int nt = 0; nt < 4; ++nt) {
                whf[nt] = *(const half8*)&sWh[(wn + nt * 16 + col) * 72 + kc * 32 + quad * 8];
                wlf[nt] = *(const half8*)&sWl[(wn + nt * 16 + col) * 72 + kc * 32 + quad * 8];
            }
            #pragma unroll
            for (int mt = 0; mt < 4; ++mt)
                #pragma unroll
                for (int nt = 0; nt < 4; ++nt) {
                    acc_h[mt][nt] = MFMA16(ahf[mt], whf[nt], acc_h[mt][nt]);
                    acc_x[mt][nt] = MFMA16(ahf[mt], wlf[nt], acc_x[mt][nt]);
                    acc_x[mt][nt] = MFMA16(alf[mt], whf[nt], acc_x[mt][nt]);
                }
        }
    }

    float bv4[4];
    #pragma unroll
    for (int nt = 0; nt < 4; ++nt) bv4[nt] = bias[n0 + wn + nt * 16 + col];

    #pragma unroll
    for (int mt = 0; mt < 4; ++mt) {
        const int m = m0 + wm + mt * 16 + quad * 4;
        #pragma unroll
        for (int nt = 0; nt < 4; ++nt) {
            const int n = n0 + wn + nt * 16 + col;
            #pragma unroll
            for (int r = 0; r < 4; ++r)
                C[(size_t)(m + r) * 512 + n] =
                    acc_h[mt][nt][r] + acc_x[mt][nt][r] * INV_SPLIT + bv4[nt];
        }
    }
}

// ============================================================================
extern "C" void kernel_launch(void* const* d_in, const int* in_sizes, int n_in,
                              void* d_out, int out_size, void* d_ws, size_t ws_size,
                              hipStream_t stream) {
    const float* query = (const float*)d_in[0];
    const float* key   = (const float*)d_in[1];
    const float* value = (const float*)d_in[2];
    const float* w_q   = (const float*)d_in[3];
    const float* b_q   = (const float*)d_in[4];
    const float* w_k   = (const float*)d_in[5];
    const float* b_k   = (const float*)d_in[6];
    const float* w_v   = (const float*)d_in[7];
    const float* b_v   = (const float*)d_in[8];
    const float* w_o   = (const float*)d_in[9];
    const float* b_o   = (const float*)d_in[10];
    float* out = (float*)d_out;

    const int WN = D_MODEL * D_MODEL;          // 262144
    _Float16* base = (_Float16*)d_ws;
    _Float16* whq = base;            _Float16* wlq = whq + WN;
    _Float16* whk = wlq + WN;        _Float16* wlk = whk + WN;
    _Float16* whv = wlk + WN;        _Float16* wlv = whv + WN;
    _Float16* who = wlv + WN;        _Float16* wlo = who + WN;
    const size_t plane = (size_t)BATCH * SEQ * D_MODEL;
    _Float16* Qf  = wlo + WN;
    _Float16* Kf  = Qf + plane;
    _Float16* Vtf = Kf + plane;
    _Float16* Oh  = Vtf + plane;
    _Float16* Ol  = Oh + plane;      // total ws: 4 MB + 5*8 MB = 44 MB

    dim3 blk(256);

    hipLaunchKernelGGL(split4, dim3(WN / 1024, 4), blk, 0, stream,
                       w_q, w_k, w_v, w_o,
                       whq, wlq, whk, wlk, whv, wlv, who, wlo, WN);

    hipLaunchKernelGGL(gemm_qkv, dim3(D_MODEL / 128, BATCH * SEQ / 128, 3), blk, 0, stream,
                       query, key, value,
                       whq, whk, whv,
                       b_q, b_k, b_v, Qf, Kf, Vtf);

    hipLaunchKernelGGL(attn_mfma, dim3(SEQ / 64, NHEADS, BATCH), blk, 0, stream,
                       Qf, Kf, Vtf, Oh, Ol);

    hipLaunchKernelGGL(gemm_out, dim3(D_MODEL / 128, BATCH * SEQ / 128), blk, 0, stream,
                       Oh, Ol, who, wlo, b_o, out);
}

// Round 7
// 402.535 us; speedup vs baseline: 1.3652x; 1.2872x over previous
//
#include <hip/hip_runtime.h>
#include <math.h>

#define D_MODEL 512
#define NHEADS 8
#define DK 64
#define BATCH 2
#define SEQ 4096
// log2(e)/8 folded into Q projection: scores in log2 domain, softmax uses exp2.
#define ATTN_SCALE 0.18033688011112043f
#define SPLIT_SCALE 2048.0f     // 2^11: lo plane pre-scaled to stay in fp16 normal range
#define INV_SPLIT  (1.0f/2048.0f)

typedef _Float16 half8 __attribute__((ext_vector_type(8)));
typedef float f32x4 __attribute__((ext_vector_type(4)));

union Pk8 { _Float16 h[8]; uint4 u; };
union Pk4 { _Float16 h[4]; uint2 u; };

#define MFMA16(a, b, c) __builtin_amdgcn_mfma_f32_16x16x32_f16((a), (b), (c), 0, 0, 0)

// async global->LDS, 16 B/lane; LDS dest = wave-uniform base + lane*16
__device__ __forceinline__ void gload_lds16(const _Float16* g, _Float16* l) {
    __builtin_amdgcn_global_load_lds(
        (const __attribute__((address_space(1))) void*)g,
        (__attribute__((address_space(3))) void*)l, 16, 0, 0);
}

// ============================================================================
// split4: hi planes for all four weights; lo plane only for w_o (w==3).
// grid = (n/1024, 4)
// ============================================================================
__global__ __launch_bounds__(256)
void split4(const float* __restrict__ s0, const float* __restrict__ s1,
            const float* __restrict__ s2, const float* __restrict__ s3,
            _Float16* __restrict__ h0, _Float16* __restrict__ h1,
            _Float16* __restrict__ h2, _Float16* __restrict__ h3,
            _Float16* __restrict__ l3, int n) {
    const int w = blockIdx.y;
    const float* src = w == 0 ? s0 : (w == 1 ? s1 : (w == 2 ? s2 : s3));
    _Float16* hi = w == 0 ? h0 : (w == 1 ? h1 : (w == 2 ? h2 : h3));
    const int i = (blockIdx.x * 256 + threadIdx.x) * 4;
    if (i >= n) return;
    float4 v = *(const float4*)(src + i);
    Pk4 h;
    h.h[0] = (_Float16)v.x; h.h[1] = (_Float16)v.y;
    h.h[2] = (_Float16)v.z; h.h[3] = (_Float16)v.w;
    *(uint2*)(hi + i) = h.u;
    if (w == 3) {
        Pk4 l;
        l.h[0] = (_Float16)((v.x - (float)h.h[0]) * SPLIT_SCALE);
        l.h[1] = (_Float16)((v.y - (float)h.h[1]) * SPLIT_SCALE);
        l.h[2] = (_Float16)((v.z - (float)h.h[2]) * SPLIT_SCALE);
        l.h[3] = (_Float16)((v.w - (float)h.h[3]) * SPLIT_SCALE);
        *(uint2*)(l3 + i) = l.u;
    }
}

// ============================================================================
// QKV projection GEMM, MFMA fp16, hi-only weights (1 MFMA/tile).
// z=0: Q (alpha=ATTN_SCALE)  z=1: K  z=2: V transposed per-head [b*8+h][d][s].
// Block 128x128, BK=64, 4 waves (2x2), software-pipelined staging.
// ============================================================================
__global__ __launch_bounds__(256, 2)
void gemm_qkv(const float* __restrict__ Aq, const float* __restrict__ Ak,
              const float* __restrict__ Av,
              const _Float16* __restrict__ Whq, const _Float16* __restrict__ Whk,
              const _Float16* __restrict__ Whv,
              const float* __restrict__ bq, const float* __restrict__ bk,
              const float* __restrict__ bv,
              _Float16* __restrict__ Qf, _Float16* __restrict__ Kf,
              _Float16* __restrict__ Vtf) {
    const int z = blockIdx.z;
    const float*     A    = z == 0 ? Aq  : (z == 1 ? Ak  : Av);
    const _Float16*  Wh   = z == 0 ? Whq : (z == 1 ? Whk : Whv);
    const float*     bias = z == 0 ? bq  : (z == 1 ? bk  : bv);

    __shared__ __align__(16) _Float16 sA [128 * 72];
    __shared__ __align__(16) _Float16 sWh[128 * 72];

    const int t    = threadIdx.x;
    const int lane = t & 63, wave = t >> 6;
    const int col  = lane & 15, quad = lane >> 4;
    const int wm   = (wave & 1) * 64, wn = (wave >> 1) * 64;
    const int m0   = blockIdx.y * 128, n0 = blockIdx.x * 128;

    f32x4 acc[4][4] = {};

    float4 a0[4], a1[4];
    uint4  wh4[4];

    #pragma unroll
    for (int i2 = 0; i2 < 4; ++i2) {
        const int slot = t + i2 * 256;
        const int r = slot >> 3, sl = slot & 7;
        const float* ap = A + (size_t)(m0 + r) * 512 + sl * 8;
        a0[i2] = *(const float4*)ap;
        a1[i2] = *(const float4*)(ap + 4);
        wh4[i2] = *(const uint4*)(Wh + (size_t)(n0 + r) * 512 + sl * 8);
    }

    for (int k0 = 0; k0 < 512; k0 += 64) {
        __syncthreads();
        #pragma unroll
        for (int i2 = 0; i2 < 4; ++i2) {
            const int slot = t + i2 * 256;
            const int r = slot >> 3, sl = slot & 7;
            Pk8 pk;
            pk.h[0] = (_Float16)a0[i2].x; pk.h[1] = (_Float16)a0[i2].y;
            pk.h[2] = (_Float16)a0[i2].z; pk.h[3] = (_Float16)a0[i2].w;
            pk.h[4] = (_Float16)a1[i2].x; pk.h[5] = (_Float16)a1[i2].y;
            pk.h[6] = (_Float16)a1[i2].z; pk.h[7] = (_Float16)a1[i2].w;
            *(uint4*)&sA [r * 72 + sl * 8] = pk.u;
            *(uint4*)&sWh[r * 72 + sl * 8] = wh4[i2];
        }
        __syncthreads();

        if (k0 + 64 < 512) {
            #pragma unroll
            for (int i2 = 0; i2 < 4; ++i2) {
                const int slot = t + i2 * 256;
                const int r = slot >> 3, sl = slot & 7;
                const float* ap = A + (size_t)(m0 + r) * 512 + k0 + 64 + sl * 8;
                a0[i2] = *(const float4*)ap;
                a1[i2] = *(const float4*)(ap + 4);
                wh4[i2] = *(const uint4*)(Wh + (size_t)(n0 + r) * 512 + k0 + 64 + sl * 8);
            }
        }

        #pragma unroll
        for (int kc = 0; kc < 2; ++kc) {
            half8 af[4], whf[4];
            #pragma unroll
            for (int mt = 0; mt < 4; ++mt)
                af[mt] = *(const half8*)&sA[(wm + mt * 16 + col) * 72 + kc * 32 + quad * 8];
            #pragma unroll
            for (int nt = 0; nt < 4; ++nt)
                whf[nt] = *(const half8*)&sWh[(wn + nt * 16 + col) * 72 + kc * 32 + quad * 8];
            #pragma unroll
            for (int mt = 0; mt < 4; ++mt)
                #pragma unroll
                for (int nt = 0; nt < 4; ++nt)
                    acc[mt][nt] = MFMA16(af[mt], whf[nt], acc[mt][nt]);
        }
    }

    float bv4[4];
    #pragma unroll
    for (int nt = 0; nt < 4; ++nt) bv4[nt] = bias[n0 + wn + nt * 16 + col];

    if (z < 2) {
        _Float16* Out = z == 0 ? Qf : Kf;
        const float alpha = z == 0 ? ATTN_SCALE : 1.0f;
        #pragma unroll
        for (int mt = 0; mt < 4; ++mt) {
            const int m = m0 + wm + mt * 16 + quad * 4;
            #pragma unroll
            for (int nt = 0; nt < 4; ++nt) {
                const int n = n0 + wn + nt * 16 + col;
                #pragma unroll
                for (int r = 0; r < 4; ++r)
                    Out[(size_t)(m + r) * 512 + n] = (_Float16)((acc[mt][nt][r] + bv4[nt]) * alpha);
            }
        }
    } else {
        #pragma unroll
        for (int mt = 0; mt < 4; ++mt) {
            const int m = m0 + wm + mt * 16 + quad * 4;
            const int b = m >> 12, s = m & (SEQ - 1);
            #pragma unroll
            for (int nt = 0; nt < 4; ++nt) {
                const int n = n0 + wn + nt * 16 + col;
                const int hh = n >> 6, d = n & (DK - 1);
                Pk4 p;
                #pragma unroll
                for (int r = 0; r < 4; ++r)
                    p.h[r] = (_Float16)(acc[mt][nt][r] + bv4[nt]);
                *(uint2*)&Vtf[((size_t)((b * NHEADS + hh) * DK + d)) * SEQ + s] = p.u;
            }
        }
    }
}

// ============================================================================
// Flash attention, fp16 MFMA. 64 queries/block (16/wave).
// K/V staged via global_load_lds (async DMA, zero staging registers -> the
// round-5/6 spill cannot recur) into double-buffered UNPADDED 64x64 tiles with
// XOR chunk swizzle (chunk ^= row&7) applied on the global source address:
// frag reads land 2 lanes/bank (free). One barrier per iteration; prefetch of
// tile i+1 issued right after the barrier, lands during compute of tile i.
// ============================================================================
__global__ __launch_bounds__(256)
void attn_mfma(const _Float16* __restrict__ Qf, const _Float16* __restrict__ Kf,
               const _Float16* __restrict__ Vtf,
               _Float16* __restrict__ Oh, _Float16* __restrict__ Ol) {
    __shared__ __align__(16) _Float16 sQ[64 * 72];      // becomes per-wave P buffer
    __shared__ __align__(16) _Float16 sK[2][64 * 64];   // swizzled, DMA-filled
    __shared__ __align__(16) _Float16 sV[2][64 * 64];   // dim-major (V^T), swizzled

    const int t    = threadIdx.x;
    const int lane = t & 63;
    const int wave = t >> 6;
    const int col  = lane & 15;
    const int quad = lane >> 4;

    const int q0 = blockIdx.x * 64;
    const int h  = blockIdx.y;
    const int b  = blockIdx.z;

    const size_t rowBase = (size_t)b * SEQ;
    const size_t vBase   = ((size_t)(b * NHEADS + h)) * DK * SEQ;

    // ---- stage Q tile (64 x 64 halves) into padded sQ ----
    {
        uint4 qv[2];
        #pragma unroll
        for (int i2 = 0; i2 < 2; ++i2) {
            const int slot = t + i2 * 256;
            const int r = slot >> 3, sl = slot & 7;
            qv[i2] = *(const uint4*)(Qf + (rowBase + q0 + r) * 512 + h * 64 + sl * 8);
        }
        #pragma unroll
        for (int i2 = 0; i2 < 2; ++i2) {
            const int slot = t + i2 * 256;
            const int r = slot >> 3, sl = slot & 7;
            *(uint4*)&sQ[r * 72 + sl * 8] = qv[i2];
        }
    }
    __syncthreads();

    // ---- issue first K/V tile DMA (lands while we read Q frags) ----
    const int subrow = lane >> 3;          // 0..7
    const int schunk = ((lane & 7) ^ subrow) * 8;   // swizzled source chunk (halves)
    #define STAGE_KV(K0, BUF)                                                        \
        do {                                                                          \
            _Pragma("unroll")                                                         \
            for (int j = 0; j < 2; ++j) {                                             \
                const int rw = wave * 16 + j * 8;                                     \
                gload_lds16(Kf + (rowBase + (K0) + rw + subrow) * 512 + h * 64 + schunk, \
                            &sK[BUF][rw * 64]);                                       \
                gload_lds16(Vtf + vBase + (size_t)(rw + subrow) * SEQ + (K0) + schunk,   \
                            &sV[BUF][rw * 64]);                                       \
            }                                                                         \
        } while (0)

    STAGE_KV(0, 0);

    half8 qf[2];
    #pragma unroll
    for (int kc = 0; kc < 2; ++kc)
        qf[kc] = *(const half8*)&sQ[(wave * 16 + col) * 72 + kc * 32 + quad * 8];
    __syncthreads();   // sQ dead -> per-wave P staging

    _Float16* Ps = sQ + wave * 16 * 72;   // 16 rows x 72, private to this wave

    float m_r = -INFINITY;
    float l_r = 0.0f;
    f32x4 of[4] = {};

    for (int it = 0; it < SEQ / 64; ++it) {
        const int cur = it & 1;
        __syncthreads();   // drains my prefetch (vmcnt) + all waves done with alt buffer
        if (it + 1 < SEQ / 64) STAGE_KV((it + 1) * 64, cur ^ 1);

        const _Float16* Kc = sK[cur];
        const _Float16* Vc = sV[cur];

        // ---- S^T = K · Q^T : 8 MFMA (swizzled frag reads) ----
        f32x4 sf[4] = {};
        #pragma unroll
        for (int kc = 0; kc < 2; ++kc) {
            #pragma unroll
            for (int kt = 0; kt < 4; ++kt) {
                const int pos = (((kc * 4 + quad) ^ (col & 7))) * 8;
                half8 kf = *(const half8*)&Kc[(kt * 16 + col) * 64 + pos];
                sf[kt] = MFMA16(kf, qf[kc], sf[kt]);
            }
        }

        // ---- online softmax (log2 domain), per-lane state ----
        float mx = sf[0][0];
        #pragma unroll
        for (int kt = 0; kt < 4; ++kt)
            #pragma unroll
            for (int r = 0; r < 4; ++r)
                mx = fmaxf(mx, sf[kt][r]);
        mx = fmaxf(mx, __shfl_xor(mx, 16));
        mx = fmaxf(mx, __shfl_xor(mx, 32));
        const float mnew = fmaxf(m_r, mx);
        if (__any(mnew > m_r)) {           // exact skip: al would be 1.0
            const float al = exp2f(m_r - mnew);
            l_r *= al;
            #pragma unroll
            for (int dt = 0; dt < 4; ++dt)
                #pragma unroll
                for (int r = 0; r < 4; ++r)
                    of[dt][r] *= al;
        }
        m_r = mnew;

        float rs = 0.0f;
        #pragma unroll
        for (int kt = 0; kt < 4; ++kt) {
            const float p0 = exp2f(sf[kt][0] - mnew);
            const float p1 = exp2f(sf[kt][1] - mnew);
            const float p2 = exp2f(sf[kt][2] - mnew);
            const float p3 = exp2f(sf[kt][3] - mnew);
            rs += (p0 + p1) + (p2 + p3);
            Pk4 z;
            z.h[0] = (_Float16)p0; z.h[1] = (_Float16)p1;
            z.h[2] = (_Float16)p2; z.h[3] = (_Float16)p3;
            *(uint2*)&Ps[col * 72 + kt * 16 + quad * 4] = z.u;
        }
        rs += __shfl_xor(rs, 16);
        rs += __shfl_xor(rs, 32);
        l_r += rs;

        // ---- O^T += V^T · P^T : 8 MFMA (intra-wave Ps round-trip) ----
        #pragma unroll
        for (int kc = 0; kc < 2; ++kc) {
            half8 pf = *(const half8*)&Ps[col * 72 + kc * 32 + quad * 8];
            #pragma unroll
            for (int dt = 0; dt < 4; ++dt) {
                const int pos = (((kc * 4 + quad) ^ (col & 7))) * 8;
                half8 vf = *(const half8*)&Vc[(dt * 16 + col) * 64 + pos];
                of[dt] = MFMA16(vf, pf, of[dt]);
            }
        }
    }

    // ---- normalize, store hi + lo' planes ----
    const float inv = 1.0f / l_r;
    const size_t base = (rowBase + q0 + wave * 16 + col) * 512 + h * 64;
    #pragma unroll
    for (int dt = 0; dt < 4; ++dt) {
        float v[4];
        #pragma unroll
        for (int r = 0; r < 4; ++r) v[r] = of[dt][r] * inv;
        Pk4 hh, ll;
        #pragma unroll
        for (int r = 0; r < 4; ++r) {
            hh.h[r] = (_Float16)v[r];
            ll.h[r] = (_Float16)((v[r] - (float)hh.h[r]) * SPLIT_SCALE);
        }
        *(uint2*)(Oh + base + dt * 16 + quad * 4) = hh.u;
        *(uint2*)(Ol + base + dt * 16 + quad * 4) = ll.u;
    }
}

// ============================================================================
// Output projection: full split-fp16 (3 MFMA/tile), fp32 out + bias. Pipelined.
// ============================================================================
__global__ __launch_bounds__(256, 1)
void gemm_out(const _Float16* __restrict__ Ah, const _Float16* __restrict__ Al,
              const _Float16* __restrict__ Wh, const _Float16* __restrict__ Wl,
              const float* __restrict__ bias, float* __restrict__ C) {
    __shared__ __align__(16) _Float16 sAh[128 * 72];
    __shared__ __align__(16) _Float16 sAl[128 * 72];
    __shared__ __align__(16) _Float16 sWh[128 * 72];
    __shared__ __align__(16) _Float16 sWl[128 * 72];

    const int t    = threadIdx.x;
    const int lane = t & 63, wave = t >> 6;
    const int col  = lane & 15, quad = lane >> 4;
    const int wm   = (wave & 1) * 64, wn = (wave >> 1) * 64;
    const int m0   = blockIdx.y * 128, n0 = blockIdx.x * 128;

    f32x4 acc_h[4][4] = {};
    f32x4 acc_x[4][4] = {};

    uint4 ah4[4], al4[4], wh4[4], wl4[4];
    #pragma unroll
    for (int i2 = 0; i2 < 4; ++i2) {
        const int slot = t + i2 * 256;
        const int r = slot >> 3, sl = slot & 7;
        ah4[i2] = *(const uint4*)(Ah + (size_t)(m0 + r) * 512 + sl * 8);
        al4[i2] = *(const uint4*)(Al + (size_t)(m0 + r) * 512 + sl * 8);
        wh4[i2] = *(const uint4*)(Wh + (size_t)(n0 + r) * 512 + sl * 8);
        wl4[i2] = *(const uint4*)(Wl + (size_t)(n0 + r) * 512 + sl * 8);
    }

    for (int k0 = 0; k0 < 512; k0 += 64) {
        __syncthreads();
        #pragma unroll
        for (int i2 = 0; i2 < 4; ++i2) {
            const int slot = t + i2 * 256;
            const int r = slot >> 3, sl = slot & 7;
            *(uint4*)&sAh[r * 72 + sl * 8] = ah4[i2];
            *(uint4*)&sAl[r * 72 + sl * 8] = al4[i2];
            *(uint4*)&sWh[r * 72 + sl * 8] = wh4[i2];
            *(uint4*)&sWl[r * 72 + sl * 8] = wl4[i2];
        }
        __syncthreads();

        if (k0 + 64 < 512) {
            #pragma unroll
            for (int i2 = 0; i2 < 4; ++i2) {
                const int slot = t + i2 * 256;
                const int r = slot >> 3, sl = slot & 7;
                ah4[i2] = *(const uint4*)(Ah + (size_t)(m0 + r) * 512 + k0 + 64 + sl * 8);
                al4[i2] = *(const uint4*)(Al + (size_t)(m0 + r) * 512 + k0 + 64 + sl * 8);
                wh4[i2] = *(const uint4*)(Wh + (size_t)(n0 + r) * 512 + k0 + 64 + sl * 8);
                wl4[i2] = *(const uint4*)(Wl + (size_t)(n0 + r) * 512 + k0 + 64 + sl * 8);
            }
        }

        #pragma unroll
        for (int kc = 0; kc < 2; ++kc) {
            half8 ahf[4], alf[4], whf[4], wlf[4];
            #pragma unroll
            for (int mt = 0; mt < 4; ++mt) {
                ahf[mt] = *(const half8*)&sAh[(wm + mt * 16 + col) * 72 + kc * 32 + quad * 8];
                alf[mt] = *(const half8*)&sAl[(wm + mt * 16 + col) * 72 + kc * 32 + quad * 8];
            }
            #pragma unroll
            for (int nt = 0; nt < 4; ++nt) {
                whf[nt] = *(const half8*)&sWh[(wn + nt * 16 + col) * 72 + kc * 32 + quad * 8];
                wlf[nt] = *(const half8*)&sWl[(wn + nt * 16 + col) * 72 + kc * 32 + quad * 8];
            }
            #pragma unroll
            for (int mt = 0; mt < 4; ++mt)
                #pragma unroll
                for (int nt = 0; nt < 4; ++nt) {
                    acc_h[mt][nt] = MFMA16(ahf[mt], whf[nt], acc_h[mt][nt]);
                    acc_x[mt][nt] = MFMA16(ahf[mt], wlf[nt], acc_x[mt][nt]);
                    acc_x[mt][nt] = MFMA16(alf[mt], whf[nt], acc_x[mt][nt]);
                }
        }
    }

    float bv4[4];
    #pragma unroll
    for (int nt = 0; nt < 4; ++nt) bv4[nt] = bias[n0 + wn + nt * 16 + col];

    #pragma unroll
    for (int mt = 0; mt < 4; ++mt) {
        const int m = m0 + wm + mt * 16 + quad * 4;
        #pragma unroll
        for (int nt = 0; nt < 4; ++nt) {
            const int n = n0 + wn + nt * 16 + col;
            #pragma unroll
            for (int r = 0; r < 4; ++r)
                C[(size_t)(m + r) * 512 + n] =
                    acc_h[mt][nt][r] + acc_x[mt][nt][r] * INV_SPLIT + bv4[nt];
        }
    }
}

// ============================================================================
extern "C" void kernel_launch(void* const* d_in, const int* in_sizes, int n_in,
                              void* d_out, int out_size, void* d_ws, size_t ws_size,
                              hipStream_t stream) {
    const float* query = (const float*)d_in[0];
    const float* key   = (const float*)d_in[1];
    const float* value = (const float*)d_in[2];
    const float* w_q   = (const float*)d_in[3];
    const float* b_q   = (const float*)d_in[4];
    const float* w_k   = (const float*)d_in[5];
    const float* b_k   = (const float*)d_in[6];
    const float* w_v   = (const float*)d_in[7];
    const float* b_v   = (const float*)d_in[8];
    const float* w_o   = (const float*)d_in[9];
    const float* b_o   = (const float*)d_in[10];
    float* out = (float*)d_out;

    const int WN = D_MODEL * D_MODEL;          // 262144
    _Float16* base = (_Float16*)d_ws;
    _Float16* whq = base;            _Float16* whk = whq + WN;
    _Float16* whv = whk + WN;        _Float16* who = whv + WN;
    _Float16* wlo = who + WN;
    const size_t plane = (size_t)BATCH * SEQ * D_MODEL;
    _Float16* Qf  = wlo + WN;
    _Float16* Kf  = Qf + plane;
    _Float16* Vtf = Kf + plane;
    _Float16* Oh  = Vtf + plane;
    _Float16* Ol  = Oh + plane;

    dim3 blk(256);

    hipLaunchKernelGGL(split4, dim3(WN / 1024, 4), blk, 0, stream,
                       w_q, w_k, w_v, w_o,
                       whq, whk, whv, who, wlo, WN);

    hipLaunchKernelGGL(gemm_qkv, dim3(D_MODEL / 128, BATCH * SEQ / 128, 3), blk, 0, stream,
                       query, key, value,
                       whq, whk, whv,
                       b_q, b_k, b_v, Qf, Kf, Vtf);

    hipLaunchKernelGGL(attn_mfma, dim3(SEQ / 64, NHEADS, BATCH), blk, 0, stream,
                       Qf, Kf, Vtf, Oh, Ol);

    hipLaunchKernelGGL(gemm_out, dim3(D_MODEL / 128, BATCH * SEQ / 128), blk, 0, stream,
                       Oh, Ol, who, wlo, b_o, out);
}

// Round 8
// 375.430 us; speedup vs baseline: 1.4637x; 1.0722x over previous
//
#include <hip/hip_runtime.h>
#include <math.h>

#define D_MODEL 512
#define NHEADS 8
#define DK 64
#define BATCH 2
#define SEQ 4096
// log2(e)/8 folded into Q projection: scores in log2 domain, softmax uses exp2.
#define ATTN_SCALE 0.18033688011112043f
#define SPLIT_SCALE 2048.0f     // 2^11: lo plane pre-scaled to stay in fp16 normal range
#define INV_SPLIT  (1.0f/2048.0f)

typedef _Float16 half8 __attribute__((ext_vector_type(8)));
typedef float f32x4 __attribute__((ext_vector_type(4)));

union Pk8 { _Float16 h[8]; uint4 u; };
union Pk4 { _Float16 h[4]; uint2 u; };

#define MFMA16(a, b, c) __builtin_amdgcn_mfma_f32_16x16x32_f16((a), (b), (c), 0, 0, 0)

// async global->LDS, 16 B/lane; LDS dest = wave-uniform base + lane*16
__device__ __forceinline__ void gload_lds16(const _Float16* g, _Float16* l) {
    __builtin_amdgcn_global_load_lds(
        (const __attribute__((address_space(1))) void*)g,
        (__attribute__((address_space(3))) void*)l, 16, 0, 0);
}

// ============================================================================
// split4: hi planes for all four weights; lo plane only for w_o (w==3).
// grid = (n/1024, 4)
// ============================================================================
__global__ __launch_bounds__(256)
void split4(const float* __restrict__ s0, const float* __restrict__ s1,
            const float* __restrict__ s2, const float* __restrict__ s3,
            _Float16* __restrict__ h0, _Float16* __restrict__ h1,
            _Float16* __restrict__ h2, _Float16* __restrict__ h3,
            _Float16* __restrict__ l3, int n) {
    const int w = blockIdx.y;
    const float* src = w == 0 ? s0 : (w == 1 ? s1 : (w == 2 ? s2 : s3));
    _Float16* hi = w == 0 ? h0 : (w == 1 ? h1 : (w == 2 ? h2 : h3));
    const int i = (blockIdx.x * 256 + threadIdx.x) * 4;
    if (i >= n) return;
    float4 v = *(const float4*)(src + i);
    Pk4 h;
    h.h[0] = (_Float16)v.x; h.h[1] = (_Float16)v.y;
    h.h[2] = (_Float16)v.z; h.h[3] = (_Float16)v.w;
    *(uint2*)(hi + i) = h.u;
    if (w == 3) {
        Pk4 l;
        l.h[0] = (_Float16)((v.x - (float)h.h[0]) * SPLIT_SCALE);
        l.h[1] = (_Float16)((v.y - (float)h.h[1]) * SPLIT_SCALE);
        l.h[2] = (_Float16)((v.z - (float)h.h[2]) * SPLIT_SCALE);
        l.h[3] = (_Float16)((v.w - (float)h.h[3]) * SPLIT_SCALE);
        *(uint2*)(l3 + i) = l.u;
    }
}

// ============================================================================
// QKV projection GEMM, MFMA fp16, hi-only weights (1 MFMA/tile).
// z=0: Q (alpha=ATTN_SCALE)  z=1: K  z=2: V transposed per-head [b*8+h][d][s].
// ============================================================================
__global__ __launch_bounds__(256, 2)
void gemm_qkv(const float* __restrict__ Aq, const float* __restrict__ Ak,
              const float* __restrict__ Av,
              const _Float16* __restrict__ Whq, const _Float16* __restrict__ Whk,
              const _Float16* __restrict__ Whv,
              const float* __restrict__ bq, const float* __restrict__ bk,
              const float* __restrict__ bv,
              _Float16* __restrict__ Qf, _Float16* __restrict__ Kf,
              _Float16* __restrict__ Vtf) {
    const int z = blockIdx.z;
    const float*     A    = z == 0 ? Aq  : (z == 1 ? Ak  : Av);
    const _Float16*  Wh   = z == 0 ? Whq : (z == 1 ? Whk : Whv);
    const float*     bias = z == 0 ? bq  : (z == 1 ? bk  : bv);

    __shared__ __align__(16) _Float16 sA [128 * 72];
    __shared__ __align__(16) _Float16 sWh[128 * 72];

    const int t    = threadIdx.x;
    const int lane = t & 63, wave = t >> 6;
    const int col  = lane & 15, quad = lane >> 4;
    const int wm   = (wave & 1) * 64, wn = (wave >> 1) * 64;
    const int m0   = blockIdx.y * 128, n0 = blockIdx.x * 128;

    f32x4 acc[4][4] = {};

    float4 a0[4], a1[4];
    uint4  wh4[4];

    #pragma unroll
    for (int i2 = 0; i2 < 4; ++i2) {
        const int slot = t + i2 * 256;
        const int r = slot >> 3, sl = slot & 7;
        const float* ap = A + (size_t)(m0 + r) * 512 + sl * 8;
        a0[i2] = *(const float4*)ap;
        a1[i2] = *(const float4*)(ap + 4);
        wh4[i2] = *(const uint4*)(Wh + (size_t)(n0 + r) * 512 + sl * 8);
    }

    for (int k0 = 0; k0 < 512; k0 += 64) {
        __syncthreads();
        #pragma unroll
        for (int i2 = 0; i2 < 4; ++i2) {
            const int slot = t + i2 * 256;
            const int r = slot >> 3, sl = slot & 7;
            Pk8 pk;
            pk.h[0] = (_Float16)a0[i2].x; pk.h[1] = (_Float16)a0[i2].y;
            pk.h[2] = (_Float16)a0[i2].z; pk.h[3] = (_Float16)a0[i2].w;
            pk.h[4] = (_Float16)a1[i2].x; pk.h[5] = (_Float16)a1[i2].y;
            pk.h[6] = (_Float16)a1[i2].z; pk.h[7] = (_Float16)a1[i2].w;
            *(uint4*)&sA [r * 72 + sl * 8] = pk.u;
            *(uint4*)&sWh[r * 72 + sl * 8] = wh4[i2];
        }
        __syncthreads();

        if (k0 + 64 < 512) {
            #pragma unroll
            for (int i2 = 0; i2 < 4; ++i2) {
                const int slot = t + i2 * 256;
                const int r = slot >> 3, sl = slot & 7;
                const float* ap = A + (size_t)(m0 + r) * 512 + k0 + 64 + sl * 8;
                a0[i2] = *(const float4*)ap;
                a1[i2] = *(const float4*)(ap + 4);
                wh4[i2] = *(const uint4*)(Wh + (size_t)(n0 + r) * 512 + k0 + 64 + sl * 8);
            }
        }

        #pragma unroll
        for (int kc = 0; kc < 2; ++kc) {
            half8 af[4], whf[4];
            #pragma unroll
            for (int mt = 0; mt < 4; ++mt)
                af[mt] = *(const half8*)&sA[(wm + mt * 16 + col) * 72 + kc * 32 + quad * 8];
            #pragma unroll
            for (int nt = 0; nt < 4; ++nt)
                whf[nt] = *(const half8*)&sWh[(wn + nt * 16 + col) * 72 + kc * 32 + quad * 8];
            #pragma unroll
            for (int mt = 0; mt < 4; ++mt)
                #pragma unroll
                for (int nt = 0; nt < 4; ++nt)
                    acc[mt][nt] = MFMA16(af[mt], whf[nt], acc[mt][nt]);
        }
    }

    float bv4[4];
    #pragma unroll
    for (int nt = 0; nt < 4; ++nt) bv4[nt] = bias[n0 + wn + nt * 16 + col];

    if (z < 2) {
        _Float16* Out = z == 0 ? Qf : Kf;
        const float alpha = z == 0 ? ATTN_SCALE : 1.0f;
        #pragma unroll
        for (int mt = 0; mt < 4; ++mt) {
            const int m = m0 + wm + mt * 16 + quad * 4;
            #pragma unroll
            for (int nt = 0; nt < 4; ++nt) {
                const int n = n0 + wn + nt * 16 + col;
                #pragma unroll
                for (int r = 0; r < 4; ++r)
                    Out[(size_t)(m + r) * 512 + n] = (_Float16)((acc[mt][nt][r] + bv4[nt]) * alpha);
            }
        }
    } else {
        #pragma unroll
        for (int mt = 0; mt < 4; ++mt) {
            const int m = m0 + wm + mt * 16 + quad * 4;
            const int b = m >> 12, s = m & (SEQ - 1);
            #pragma unroll
            for (int nt = 0; nt < 4; ++nt) {
                const int n = n0 + wn + nt * 16 + col;
                const int hh = n >> 6, d = n & (DK - 1);
                Pk4 p;
                #pragma unroll
                for (int r = 0; r < 4; ++r)
                    p.h[r] = (_Float16)(acc[mt][nt][r] + bv4[nt]);
                *(uint2*)&Vtf[((size_t)((b * NHEADS + hh) * DK + d)) * SEQ + s] = p.u;
            }
        }
    }
}

// ============================================================================
// Flash attention, fp16 MFMA. 64 queries/block (16/wave), 64-key iterations.
// LAZY online softmax: P = exp2(s - m_running) with m from PREVIOUS tiles
// (iter 0 eager) — removes the max-tree + shuffles from the per-iteration
// critical path; running-max update + O/l rescale happen after the PV MFMA,
// guarded by __any (rare). l is per-lane partial, reduced once after the loop.
// K/V staged via async DMA, double-buffered, XOR-swizzled 64x64 tiles.
// LDS = 16K(sK)+16K(sV)+8K(sP) = 40960 B -> exactly 4 blocks/CU.
// Q stages through sP (per-wave rows = own P region), then sP becomes P.
// ============================================================================
__global__ __launch_bounds__(256)
void attn_mfma(const _Float16* __restrict__ Qf, const _Float16* __restrict__ Kf,
               const _Float16* __restrict__ Vtf,
               _Float16* __restrict__ Oh, _Float16* __restrict__ Ol) {
    __shared__ __align__(16) _Float16 sK[2][64 * 64];   // swizzled, DMA-filled
    __shared__ __align__(16) _Float16 sV[2][64 * 64];   // dim-major (V^T), swizzled
    __shared__ __align__(16) _Float16 sP[64 * 64];      // Q staging, then per-wave P

    const int t    = threadIdx.x;
    const int lane = t & 63;
    const int wave = t >> 6;
    const int col  = lane & 15;
    const int quad = lane >> 4;

    const int q0 = blockIdx.x * 64;
    const int h  = blockIdx.y;
    const int b  = blockIdx.z;

    const size_t rowBase = (size_t)b * SEQ;
    const size_t vBase   = ((size_t)(b * NHEADS + h)) * DK * SEQ;

    // ---- issue first K/V tile DMA immediately (lands during Q staging) ----
    const int subrow = lane >> 3;                    // 0..7
    const int schunk = ((lane & 7) ^ subrow) * 8;    // swizzled source chunk (halves)
    #define STAGE_KV(K0, BUF)                                                        \
        do {                                                                          \
            _Pragma("unroll")                                                         \
            for (int j = 0; j < 2; ++j) {                                             \
                const int rw = wave * 16 + j * 8;                                     \
                gload_lds16(Kf + (rowBase + (K0) + rw + subrow) * 512 + h * 64 + schunk, \
                            &sK[BUF][rw * 64]);                                       \
                gload_lds16(Vtf + vBase + (size_t)(rw + subrow) * SEQ + (K0) + schunk,   \
                            &sV[BUF][rw * 64]);                                       \
            }                                                                         \
        } while (0)

    STAGE_KV(0, 0);

    // ---- stage Q tile (64x64 halves) into sP, same XOR swizzle as K tiles ----
    {
        uint4 qv[2];
        #pragma unroll
        for (int i2 = 0; i2 < 2; ++i2) {
            const int slot = t + i2 * 256;           // 64 rows x 8 chunks of 8 halves
            const int r = slot >> 3, sl = slot & 7;
            qv[i2] = *(const uint4*)(Qf + (rowBase + q0 + r) * 512 + h * 64 + sl * 8);
        }
        #pragma unroll
        for (int i2 = 0; i2 < 2; ++i2) {
            const int slot = t + i2 * 256;
            const int r = slot >> 3, sl = slot & 7;
            *(uint4*)&sP[r * 64 + (sl ^ (r & 7)) * 8] = qv[i2];
        }
    }
    __syncthreads();

    half8 qf[2];
    #pragma unroll
    for (int kc = 0; kc < 2; ++kc)
        qf[kc] = *(const half8*)&sP[(wave * 16 + col) * 64 + ((kc * 4 + quad) ^ (col & 7)) * 8];
    // sP rows [16*wave, 16*wave+16) now become this wave's P buffer.
    // First P write happens after the it=0 loop-top barrier, so all waves'
    // qf reads (which cross wave row regions) are complete by then.

    _Float16* Ps = sP + wave * 16 * 64;
    const int pmsk = (col & 7) << 1;   // P chunk swizzle (4-half chunks)

    float m_r = -INFINITY;
    float l_r = 0.0f;
    f32x4 of[4] = {};

    for (int it = 0; it < SEQ / 64; ++it) {
        const int cur = it & 1;
        __syncthreads();   // drains prefetch DMA; all waves done with alt buffer
        if (it + 1 < SEQ / 64) STAGE_KV((it + 1) * 64, cur ^ 1);

        const _Float16* Kc = sK[cur];
        const _Float16* Vc = sV[cur];

        // ---- S^T = K · Q^T : 8 MFMA (swizzled frag reads) ----
        f32x4 sf[4] = {};
        #pragma unroll
        for (int kc = 0; kc < 2; ++kc) {
            const int pos = ((kc * 4 + quad) ^ (col & 7)) * 8;
            #pragma unroll
            for (int kt = 0; kt < 4; ++kt) {
                half8 kf = *(const half8*)&Kc[(kt * 16 + col) * 64 + pos];
                sf[kt] = MFMA16(kf, qf[kc], sf[kt]);
            }
        }

        // ---- iteration 0: eager max (establish scale) ----
        if (it == 0) {
            float mx = sf[0][0];
            #pragma unroll
            for (int kt = 0; kt < 4; ++kt)
                #pragma unroll
                for (int r = 0; r < 4; ++r)
                    mx = fmaxf(mx, sf[kt][r]);
            mx = fmaxf(mx, __shfl_xor(mx, 16));
            mx = fmaxf(mx, __shfl_xor(mx, 32));
            m_r = mx;
        }

        // ---- P = exp2(s - m_r) at the RUNNING scale (no reduce on the path) ----
        float lrs = 0.0f;
        #pragma unroll
        for (int kt = 0; kt < 4; ++kt) {
            const float p0 = exp2f(sf[kt][0] - m_r);
            const float p1 = exp2f(sf[kt][1] - m_r);
            const float p2 = exp2f(sf[kt][2] - m_r);
            const float p3 = exp2f(sf[kt][3] - m_r);
            lrs += (p0 + p1) + (p2 + p3);
            Pk4 z;
            z.h[0] = (_Float16)p0; z.h[1] = (_Float16)p1;
            z.h[2] = (_Float16)p2; z.h[3] = (_Float16)p3;
            *(uint2*)&Ps[col * 64 + ((kt * 4 + quad) ^ pmsk) * 4] = z.u;
        }

        // ---- tile max for the running update (overlaps PV below) ----
        float mxr = m_r;
        if (it > 0) {
            float mx = sf[0][0];
            #pragma unroll
            for (int kt = 0; kt < 4; ++kt)
                #pragma unroll
                for (int r = 0; r < 4; ++r)
                    mx = fmaxf(mx, sf[kt][r]);
            mx = fmaxf(mx, __shfl_xor(mx, 16));
            mx = fmaxf(mx, __shfl_xor(mx, 32));
            mxr = mx;
        }

        // ---- O^T += V^T · P^T : 8 MFMA (intra-wave Ps round-trip) ----
        #pragma unroll
        for (int kc = 0; kc < 2; ++kc) {
            half8 pf = *(const half8*)&Ps[col * 64 + ((kc * 8 + quad * 2) ^ pmsk) * 4];
            const int pos = ((kc * 4 + quad) ^ (col & 7)) * 8;
            #pragma unroll
            for (int dt = 0; dt < 4; ++dt) {
                half8 vf = *(const half8*)&Vc[(dt * 16 + col) * 64 + pos];
                of[dt] = MFMA16(vf, pf, of[dt]);
            }
        }

        l_r += lrs;

        // ---- rare rescale: only when this tile raised the running max ----
        if (__any(mxr > m_r)) {
            const float mnew = fmaxf(m_r, mxr);
            const float al   = exp2f(m_r - mnew);
            l_r *= al;
            #pragma unroll
            for (int dt = 0; dt < 4; ++dt)
                #pragma unroll
                for (int r = 0; r < 4; ++r)
                    of[dt][r] *= al;
            m_r = mnew;
        }
    }

    // ---- final l reduction across the 4 quad lanes of each query ----
    l_r += __shfl_xor(l_r, 16);
    l_r += __shfl_xor(l_r, 32);

    // ---- normalize, store hi + lo' planes ----
    const float inv = 1.0f / l_r;
    const size_t base = (rowBase + q0 + wave * 16 + col) * 512 + h * 64;
    #pragma unroll
    for (int dt = 0; dt < 4; ++dt) {
        float v[4];
        #pragma unroll
        for (int r = 0; r < 4; ++r) v[r] = of[dt][r] * inv;
        Pk4 hh, ll;
        #pragma unroll
        for (int r = 0; r < 4; ++r) {
            hh.h[r] = (_Float16)v[r];
            ll.h[r] = (_Float16)((v[r] - (float)hh.h[r]) * SPLIT_SCALE);
        }
        *(uint2*)(Oh + base + dt * 16 + quad * 4) = hh.u;
        *(uint2*)(Ol + base + dt * 16 + quad * 4) = ll.u;
    }
}

// ============================================================================
// Output projection: full split-fp16 (3 MFMA/tile), fp32 out + bias. Pipelined.
// ============================================================================
__global__ __launch_bounds__(256, 1)
void gemm_out(const _Float16* __restrict__ Ah, const _Float16* __restrict__ Al,
              const _Float16* __restrict__ Wh, const _Float16* __restrict__ Wl,
              const float* __restrict__ bias, float* __restrict__ C) {
    __shared__ __align__(16) _Float16 sAh[128 * 72];
    __shared__ __align__(16) _Float16 sAl[128 * 72];
    __shared__ __align__(16) _Float16 sWh[128 * 72];
    __shared__ __align__(16) _Float16 sWl[128 * 72];

    const int t    = threadIdx.x;
    const int lane = t & 63, wave = t >> 6;
    const int col  = lane & 15, quad = lane >> 4;
    const int wm   = (wave & 1) * 64, wn = (wave >> 1) * 64;
    const int m0   = blockIdx.y * 128, n0 = blockIdx.x * 128;

    f32x4 acc_h[4][4] = {};
    f32x4 acc_x[4][4] = {};

    uint4 ah4[4], al4[4], wh4[4], wl4[4];
    #pragma unroll
    for (int i2 = 0; i2 < 4; ++i2) {
        const int slot = t + i2 * 256;
        const int r = slot >> 3, sl = slot & 7;
        ah4[i2] = *(const uint4*)(Ah + (size_t)(m0 + r) * 512 + sl * 8);
        al4[i2] = *(const uint4*)(Al + (size_t)(m0 + r) * 512 + sl * 8);
        wh4[i2] = *(const uint4*)(Wh + (size_t)(n0 + r) * 512 + sl * 8);
        wl4[i2] = *(const uint4*)(Wl + (size_t)(n0 + r) * 512 + sl * 8);
    }

    for (int k0 = 0; k0 < 512; k0 += 64) {
        __syncthreads();
        #pragma unroll
        for (int i2 = 0; i2 < 4; ++i2) {
            const int slot = t + i2 * 256;
            const int r = slot >> 3, sl = slot & 7;
            *(uint4*)&sAh[r * 72 + sl * 8] = ah4[i2];
            *(uint4*)&sAl[r * 72 + sl * 8] = al4[i2];
            *(uint4*)&sWh[r * 72 + sl * 8] = wh4[i2];
            *(uint4*)&sWl[r * 72 + sl * 8] = wl4[i2];
        }
        __syncthreads();

        if (k0 + 64 < 512) {
            #pragma unroll
            for (int i2 = 0; i2 < 4; ++i2) {
                const int slot = t + i2 * 256;
                const int r = slot >> 3, sl = slot & 7;
                ah4[i2] = *(const uint4*)(Ah + (size_t)(m0 + r) * 512 + k0 + 64 + sl * 8);
                al4[i2] = *(const uint4*)(Al + (size_t)(m0 + r) * 512 + k0 + 64 + sl * 8);
                wh4[i2] = *(const uint4*)(Wh + (size_t)(n0 + r) * 512 + k0 + 64 + sl * 8);
                wl4[i2] = *(const uint4*)(Wl + (size_t)(n0 + r) * 512 + k0 + 64 + sl * 8);
            }
        }

        #pragma unroll
        for (int kc = 0; kc < 2; ++kc) {
            half8 ahf[4], alf[4], whf[4], wlf[4];
            #pragma unroll
            for (int mt = 0; mt < 4; ++mt) {
                ahf[mt] = *(const half8*)&sAh[(wm + mt * 16 + col) * 72 + kc * 32 + quad * 8];
                alf[mt] = *(const half8*)&sAl[(wm + mt * 16 + col) * 72 + kc * 32 + quad * 8];
            }
            #pragma unroll
            for (int nt = 0; nt < 4; ++nt) {
                whf[nt] = *(const half8*)&sWh[(wn + nt * 16 + col) * 72 + kc * 32 + quad * 8];
                wlf[nt] = *(const half8*)&sWl[(wn + nt * 16 + col) * 72 + kc * 32 + quad * 8];
            }
            #pragma unroll
            for (int mt = 0; mt < 4; ++mt)
                #pragma unroll
                for (int nt = 0; nt < 4; ++nt) {
                    acc_h[mt][nt] = MFMA16(ahf[mt], whf[nt], acc_h[mt][nt]);
                    acc_x[mt][nt] = MFMA16(ahf[mt], wlf[nt], acc_x[mt][nt]);
                    acc_x[mt][nt] = MFMA16(alf[mt], whf[nt], acc_x[mt][nt]);
                }
        }
    }

    float bv4[4];
    #pragma unroll
    for (int nt = 0; nt < 4; ++nt) bv4[nt] = bias[n0 + wn + nt * 16 + col];

    #pragma unroll
    for (int mt = 0; mt < 4; ++mt) {
        const int m = m0 + wm + mt * 16 + quad * 4;
        #pragma unroll
        for (int nt = 0; nt < 4; ++nt) {
            const int n = n0 + wn + nt * 16 + col;
            #pragma unroll
            for (int r = 0; r < 4; ++r)
                C[(size_t)(m + r) * 512 + n] =
                    acc_h[mt][nt][r] + acc_x[mt][nt][r] * INV_SPLIT + bv4[nt];
        }
    }
}

// ============================================================================
extern "C" void kernel_launch(void* const* d_in, const int* in_sizes, int n_in,
                              void* d_out, int out_size, void* d_ws, size_t ws_size,
                              hipStream_t stream) {
    const float* query = (const float*)d_in[0];
    const float* key   = (const float*)d_in[1];
    const float* value = (const float*)d_in[2];
    const float* w_q   = (const float*)d_in[3];
    const float* b_q   = (const float*)d_in[4];
    const float* w_k   = (const float*)d_in[5];
    const float* b_k   = (const float*)d_in[6];
    const float* w_v   = (const float*)d_in[7];
    const float* b_v   = (const float*)d_in[8];
    const float* w_o   = (const float*)d_in[9];
    const float* b_o   = (const float*)d_in[10];
    float* out = (float*)d_out;

    const int WN = D_MODEL * D_MODEL;          // 262144
    _Float16* base = (_Float16*)d_ws;
    _Float16* whq = base;            _Float16* whk = whq + WN;
    _Float16* whv = whk + WN;        _Float16* who = whv + WN;
    _Float16* wlo = who + WN;
    const size_t plane = (size_t)BATCH * SEQ * D_MODEL;
    _Float16* Qf  = wlo + WN;
    _Float16* Kf  = Qf + plane;
    _Float16* Vtf = Kf + plane;
    _Float16* Oh  = Vtf + plane;
    _Float16* Ol  = Oh + plane;

    dim3 blk(256);

    hipLaunchKernelGGL(split4, dim3(WN / 1024, 4), blk, 0, stream,
                       w_q, w_k, w_v, w_o,
                       whq, whk, whv, who, wlo, WN);

    hipLaunchKernelGGL(gemm_qkv, dim3(D_MODEL / 128, BATCH * SEQ / 128, 3), blk, 0, stream,
                       query, key, value,
                       whq, whk, whv,
                       b_q, b_k, b_v, Qf, Kf, Vtf);

    hipLaunchKernelGGL(attn_mfma, dim3(SEQ / 64, NHEADS, BATCH), blk, 0, stream,
                       Qf, Kf, Vtf, Oh, Ol);

    hipLaunchKernelGGL(gemm_out, dim3(D_MODEL / 128, BATCH * SEQ / 128), blk, 0, stream,
                       Oh, Ol, who, wlo, b_o, out);
}

// Round 9
// 325.390 us; speedup vs baseline: 1.6888x; 1.1538x over previous
//
#include <hip/hip_runtime.h>
#include <math.h>

#define D_MODEL 512
#define NHEADS 8
#define DK 64
#define BATCH 2
#define SEQ 4096
// log2(e)/8 folded into Q projection: scores in log2 domain, softmax uses exp2.
#define ATTN_SCALE 0.18033688011112043f
#define SPLIT_SCALE 2048.0f     // 2^11: lo plane pre-scaled to stay in fp16 normal range
#define INV_SPLIT  (1.0f/2048.0f)

typedef _Float16 half8 __attribute__((ext_vector_type(8)));
typedef float f32x4 __attribute__((ext_vector_type(4)));

union Pk8 { _Float16 h[8]; uint4 u; };
union Pk4 { _Float16 h[4]; uint2 u; };

#define MFMA16(a, b, c) __builtin_amdgcn_mfma_f32_16x16x32_f16((a), (b), (c), 0, 0, 0)

// async global->LDS, 16 B/lane; LDS dest = wave-uniform base + lane*16
__device__ __forceinline__ void gload_lds16(const _Float16* g, _Float16* l) {
    __builtin_amdgcn_global_load_lds(
        (const __attribute__((address_space(1))) void*)g,
        (__attribute__((address_space(3))) void*)l, 16, 0, 0);
}

// ============================================================================
// cvt3: fp32 -> fp16 for the three activation tensors. grid (n/1024, 3).
// ============================================================================
__global__ __launch_bounds__(256)
void cvt3(const float* __restrict__ s0, const float* __restrict__ s1,
          const float* __restrict__ s2,
          _Float16* __restrict__ d0, _Float16* __restrict__ d1,
          _Float16* __restrict__ d2) {
    const int w = blockIdx.y;
    const float* src = w == 0 ? s0 : (w == 1 ? s1 : s2);
    _Float16*   dst = w == 0 ? d0 : (w == 1 ? d1 : d2);
    const int i = (blockIdx.x * 256 + threadIdx.x) * 4;
    float4 v = *(const float4*)(src + i);
    Pk4 h;
    h.h[0] = (_Float16)v.x; h.h[1] = (_Float16)v.y;
    h.h[2] = (_Float16)v.z; h.h[3] = (_Float16)v.w;
    *(uint2*)(dst + i) = h.u;
}

// ============================================================================
// split_w: hi planes for all four weights; lo plane only for w_o (w==3).
// grid = (n/1024, 4)
// ============================================================================
__global__ __launch_bounds__(256)
void split_w(const float* __restrict__ s0, const float* __restrict__ s1,
             const float* __restrict__ s2, const float* __restrict__ s3,
             _Float16* __restrict__ h0, _Float16* __restrict__ h1,
             _Float16* __restrict__ h2, _Float16* __restrict__ h3,
             _Float16* __restrict__ l3, int n) {
    const int w = blockIdx.y;
    const float* src = w == 0 ? s0 : (w == 1 ? s1 : (w == 2 ? s2 : s3));
    _Float16* hi = w == 0 ? h0 : (w == 1 ? h1 : (w == 2 ? h2 : h3));
    const int i = (blockIdx.x * 256 + threadIdx.x) * 4;
    if (i >= n) return;
    float4 v = *(const float4*)(src + i);
    Pk4 h;
    h.h[0] = (_Float16)v.x; h.h[1] = (_Float16)v.y;
    h.h[2] = (_Float16)v.z; h.h[3] = (_Float16)v.w;
    *(uint2*)(hi + i) = h.u;
    if (w == 3) {
        Pk4 l;
        l.h[0] = (_Float16)((v.x - (float)h.h[0]) * SPLIT_SCALE);
        l.h[1] = (_Float16)((v.y - (float)h.h[1]) * SPLIT_SCALE);
        l.h[2] = (_Float16)((v.z - (float)h.h[2]) * SPLIT_SCALE);
        l.h[3] = (_Float16)((v.w - (float)h.h[3]) * SPLIT_SCALE);
        *(uint2*)(l3 + i) = l.u;
    }
}

// ============================================================================
// QKV projection GEMM, m97-style: ALL staging via global_load_lds DMA (zero
// staging registers, no pack VALU), unpadded XOR-swizzled LDS, 2-barrier
// K-loop. Block 128x128, BK=64, 4 waves 2x2. LDS 32 KB.
// z=0: Q (alpha=ATTN_SCALE)  z=1: K  z=2: V transposed per-head [b*8+h][d][s].
// ============================================================================
__global__ __launch_bounds__(256)
void gemm_qkv(const _Float16* __restrict__ Aq, const _Float16* __restrict__ Ak,
              const _Float16* __restrict__ Av,
              const _Float16* __restrict__ Whq, const _Float16* __restrict__ Whk,
              const _Float16* __restrict__ Whv,
              const float* __restrict__ bq, const float* __restrict__ bk,
              const float* __restrict__ bv,
              _Float16* __restrict__ Qf, _Float16* __restrict__ Kf,
              _Float16* __restrict__ Vtf) {
    const int z = blockIdx.z;
    const _Float16* A    = z == 0 ? Aq  : (z == 1 ? Ak  : Av);
    const _Float16* Wh   = z == 0 ? Whq : (z == 1 ? Whk : Whv);
    const float*    bias = z == 0 ? bq  : (z == 1 ? bk  : bv);

    __shared__ __align__(16) _Float16 sA[128 * 64];
    __shared__ __align__(16) _Float16 sW[128 * 64];

    const int t    = threadIdx.x;
    const int lane = t & 63, wave = t >> 6;
    const int col  = lane & 15, quad = lane >> 4;
    const int wm   = (wave & 1) * 64, wn = (wave >> 1) * 64;
    const int m0   = blockIdx.y * 128, n0 = blockIdx.x * 128;

    const int subrow = lane >> 3;                  // 0..7
    const int schunk = ((lane & 7) ^ subrow) * 8;  // swizzled source chunk (halves)

    f32x4 acc[4][4] = {};

    for (int k0 = 0; k0 < 512; k0 += 64) {
        __syncthreads();   // all waves done reading previous chunk
        #pragma unroll
        for (int j = 0; j < 4; ++j) {
            const int rw = wave * 32 + j * 8;
            gload_lds16(A  + (size_t)(m0 + rw + subrow) * 512 + k0 + schunk, &sA[rw * 64]);
            gload_lds16(Wh + (size_t)(n0 + rw + subrow) * 512 + k0 + schunk, &sW[rw * 64]);
        }
        __syncthreads();   // vmcnt drained before barrier -> tiles complete

        #pragma unroll
        for (int kc = 0; kc < 2; ++kc) {
            const int pos = ((kc * 4 + quad) ^ (col & 7)) * 8;
            half8 af[4], wf[4];
            #pragma unroll
            for (int mt = 0; mt < 4; ++mt)
                af[mt] = *(const half8*)&sA[(wm + mt * 16 + col) * 64 + pos];
            #pragma unroll
            for (int nt = 0; nt < 4; ++nt)
                wf[nt] = *(const half8*)&sW[(wn + nt * 16 + col) * 64 + pos];
            #pragma unroll
            for (int mt = 0; mt < 4; ++mt)
                #pragma unroll
                for (int nt = 0; nt < 4; ++nt)
                    acc[mt][nt] = MFMA16(af[mt], wf[nt], acc[mt][nt]);
        }
    }

    float bv4[4];
    #pragma unroll
    for (int nt = 0; nt < 4; ++nt) bv4[nt] = bias[n0 + wn + nt * 16 + col];

    if (z < 2) {
        _Float16* Out = z == 0 ? Qf : Kf;
        const float alpha = z == 0 ? ATTN_SCALE : 1.0f;
        #pragma unroll
        for (int mt = 0; mt < 4; ++mt) {
            const int m = m0 + wm + mt * 16 + quad * 4;
            #pragma unroll
            for (int nt = 0; nt < 4; ++nt) {
                const int n = n0 + wn + nt * 16 + col;
                #pragma unroll
                for (int r = 0; r < 4; ++r)
                    Out[(size_t)(m + r) * 512 + n] = (_Float16)((acc[mt][nt][r] + bv4[nt]) * alpha);
            }
        }
    } else {
        #pragma unroll
        for (int mt = 0; mt < 4; ++mt) {
            const int m = m0 + wm + mt * 16 + quad * 4;
            const int b = m >> 12, s = m & (SEQ - 1);
            #pragma unroll
            for (int nt = 0; nt < 4; ++nt) {
                const int n = n0 + wn + nt * 16 + col;
                const int hh = n >> 6, d = n & (DK - 1);
                Pk4 p;
                #pragma unroll
                for (int r = 0; r < 4; ++r)
                    p.h[r] = (_Float16)(acc[mt][nt][r] + bv4[nt]);
                *(uint2*)&Vtf[((size_t)((b * NHEADS + hh) * DK + d)) * SEQ + s] = p.u;
            }
        }
    }
}

// ============================================================================
// Flash attention, fp16 MFMA. Unchanged from round 8 (180 us):
// lazy online softmax, async-DMA double-buffered K/V, XOR-swizzled LDS,
// 40960 B LDS -> 4 blocks/CU, 64 queries/block.
// ============================================================================
__global__ __launch_bounds__(256)
void attn_mfma(const _Float16* __restrict__ Qf, const _Float16* __restrict__ Kf,
               const _Float16* __restrict__ Vtf,
               _Float16* __restrict__ Oh, _Float16* __restrict__ Ol) {
    __shared__ __align__(16) _Float16 sK[2][64 * 64];
    __shared__ __align__(16) _Float16 sV[2][64 * 64];
    __shared__ __align__(16) _Float16 sP[64 * 64];

    const int t    = threadIdx.x;
    const int lane = t & 63;
    const int wave = t >> 6;
    const int col  = lane & 15;
    const int quad = lane >> 4;

    const int q0 = blockIdx.x * 64;
    const int h  = blockIdx.y;
    const int b  = blockIdx.z;

    const size_t rowBase = (size_t)b * SEQ;
    const size_t vBase   = ((size_t)(b * NHEADS + h)) * DK * SEQ;

    const int subrow = lane >> 3;
    const int schunk = ((lane & 7) ^ subrow) * 8;
    #define STAGE_KV(K0, BUF)                                                        \
        do {                                                                          \
            _Pragma("unroll")                                                         \
            for (int j = 0; j < 2; ++j) {                                             \
                const int rw = wave * 16 + j * 8;                                     \
                gload_lds16(Kf + (rowBase + (K0) + rw + subrow) * 512 + h * 64 + schunk, \
                            &sK[BUF][rw * 64]);                                       \
                gload_lds16(Vtf + vBase + (size_t)(rw + subrow) * SEQ + (K0) + schunk,   \
                            &sV[BUF][rw * 64]);                                       \
            }                                                                         \
        } while (0)

    STAGE_KV(0, 0);

    {
        uint4 qv[2];
        #pragma unroll
        for (int i2 = 0; i2 < 2; ++i2) {
            const int slot = t + i2 * 256;
            const int r = slot >> 3, sl = slot & 7;
            qv[i2] = *(const uint4*)(Qf + (rowBase + q0 + r) * 512 + h * 64 + sl * 8);
        }
        #pragma unroll
        for (int i2 = 0; i2 < 2; ++i2) {
            const int slot = t + i2 * 256;
            const int r = slot >> 3, sl = slot & 7;
            *(uint4*)&sP[r * 64 + (sl ^ (r & 7)) * 8] = qv[i2];
        }
    }
    __syncthreads();

    half8 qf[2];
    #pragma unroll
    for (int kc = 0; kc < 2; ++kc)
        qf[kc] = *(const half8*)&sP[(wave * 16 + col) * 64 + ((kc * 4 + quad) ^ (col & 7)) * 8];

    _Float16* Ps = sP + wave * 16 * 64;
    const int pmsk = (col & 7) << 1;

    float m_r = -INFINITY;
    float l_r = 0.0f;
    f32x4 of[4] = {};

    for (int it = 0; it < SEQ / 64; ++it) {
        const int cur = it & 1;
        __syncthreads();
        if (it + 1 < SEQ / 64) STAGE_KV((it + 1) * 64, cur ^ 1);

        const _Float16* Kc = sK[cur];
        const _Float16* Vc = sV[cur];

        f32x4 sf[4] = {};
        #pragma unroll
        for (int kc = 0; kc < 2; ++kc) {
            const int pos = ((kc * 4 + quad) ^ (col & 7)) * 8;
            #pragma unroll
            for (int kt = 0; kt < 4; ++kt) {
                half8 kf = *(const half8*)&Kc[(kt * 16 + col) * 64 + pos];
                sf[kt] = MFMA16(kf, qf[kc], sf[kt]);
            }
        }

        if (it == 0) {
            float mx = sf[0][0];
            #pragma unroll
            for (int kt = 0; kt < 4; ++kt)
                #pragma unroll
                for (int r = 0; r < 4; ++r)
                    mx = fmaxf(mx, sf[kt][r]);
            mx = fmaxf(mx, __shfl_xor(mx, 16));
            mx = fmaxf(mx, __shfl_xor(mx, 32));
            m_r = mx;
        }

        float lrs = 0.0f;
        #pragma unroll
        for (int kt = 0; kt < 4; ++kt) {
            const float p0 = exp2f(sf[kt][0] - m_r);
            const float p1 = exp2f(sf[kt][1] - m_r);
            const float p2 = exp2f(sf[kt][2] - m_r);
            const float p3 = exp2f(sf[kt][3] - m_r);
            lrs += (p0 + p1) + (p2 + p3);
            Pk4 z;
            z.h[0] = (_Float16)p0; z.h[1] = (_Float16)p1;
            z.h[2] = (_Float16)p2; z.h[3] = (_Float16)p3;
            *(uint2*)&Ps[col * 64 + ((kt * 4 + quad) ^ pmsk) * 4] = z.u;
        }

        float mxr = m_r;
        if (it > 0) {
            float mx = sf[0][0];
            #pragma unroll
            for (int kt = 0; kt < 4; ++kt)
                #pragma unroll
                for (int r = 0; r < 4; ++r)
                    mx = fmaxf(mx, sf[kt][r]);
            mx = fmaxf(mx, __shfl_xor(mx, 16));
            mx = fmaxf(mx, __shfl_xor(mx, 32));
            mxr = mx;
        }

        #pragma unroll
        for (int kc = 0; kc < 2; ++kc) {
            half8 pf = *(const half8*)&Ps[col * 64 + ((kc * 8 + quad * 2) ^ pmsk) * 4];
            const int pos = ((kc * 4 + quad) ^ (col & 7)) * 8;
            #pragma unroll
            for (int dt = 0; dt < 4; ++dt) {
                half8 vf = *(const half8*)&Vc[(dt * 16 + col) * 64 + pos];
                of[dt] = MFMA16(vf, pf, of[dt]);
            }
        }

        l_r += lrs;

        if (__any(mxr > m_r)) {
            const float mnew = fmaxf(m_r, mxr);
            const float al   = exp2f(m_r - mnew);
            l_r *= al;
            #pragma unroll
            for (int dt = 0; dt < 4; ++dt)
                #pragma unroll
                for (int r = 0; r < 4; ++r)
                    of[dt][r] *= al;
            m_r = mnew;
        }
    }

    l_r += __shfl_xor(l_r, 16);
    l_r += __shfl_xor(l_r, 32);

    const float inv = 1.0f / l_r;
    const size_t base = (rowBase + q0 + wave * 16 + col) * 512 + h * 64;
    #pragma unroll
    for (int dt = 0; dt < 4; ++dt) {
        float v[4];
        #pragma unroll
        for (int r = 0; r < 4; ++r) v[r] = of[dt][r] * inv;
        Pk4 hh, ll;
        #pragma unroll
        for (int r = 0; r < 4; ++r) {
            hh.h[r] = (_Float16)v[r];
            ll.h[r] = (_Float16)((v[r] - (float)hh.h[r]) * SPLIT_SCALE);
        }
        *(uint2*)(Oh + base + dt * 16 + quad * 4) = hh.u;
        *(uint2*)(Ol + base + dt * 16 + quad * 4) = ll.u;
    }
}

// ============================================================================
// Output projection, DMA-staged. A split (hi+lo from attention), W hi-only
// (round-6 evidence: W-lo contributes <1e-3). Block 128x64 -> 512 blocks.
// LDS 40 KB -> 4 blocks/CU. 2 MFMA per tile. fp32 out + bias.
// ============================================================================
__global__ __launch_bounds__(256)
void gemm_out(const _Float16* __restrict__ Ah, const _Float16* __restrict__ Al,
              const _Float16* __restrict__ Wh,
              const float* __restrict__ bias, float* __restrict__ C) {
    __shared__ __align__(16) _Float16 sAh[128 * 64];
    __shared__ __align__(16) _Float16 sAl[128 * 64];
    __shared__ __align__(16) _Float16 sWh[64 * 64];

    const int t    = threadIdx.x;
    const int lane = t & 63, wave = t >> 6;
    const int col  = lane & 15, quad = lane >> 4;
    const int wm   = (wave & 1) * 64, wn = (wave >> 1) * 32;
    const int m0   = blockIdx.y * 128, n0 = blockIdx.x * 64;

    const int subrow = lane >> 3;
    const int schunk = ((lane & 7) ^ subrow) * 8;

    f32x4 acc_h[4][2] = {};
    f32x4 acc_x[4][2] = {};

    for (int k0 = 0; k0 < 512; k0 += 64) {
        __syncthreads();
        #pragma unroll
        for (int j = 0; j < 4; ++j) {
            const int rw = wave * 32 + j * 8;
            gload_lds16(Ah + (size_t)(m0 + rw + subrow) * 512 + k0 + schunk, &sAh[rw * 64]);
            gload_lds16(Al + (size_t)(m0 + rw + subrow) * 512 + k0 + schunk, &sAl[rw * 64]);
        }
        #pragma unroll
        for (int j = 0; j < 2; ++j) {
            const int rw = wave * 16 + j * 8;
            gload_lds16(Wh + (size_t)(n0 + rw + subrow) * 512 + k0 + schunk, &sWh[rw * 64]);
        }
        __syncthreads();

        #pragma unroll
        for (int kc = 0; kc < 2; ++kc) {
            const int pos = ((kc * 4 + quad) ^ (col & 7)) * 8;
            half8 ahf[4], alf[4], whf[2];
            #pragma unroll
            for (int mt = 0; mt < 4; ++mt) {
                ahf[mt] = *(const half8*)&sAh[(wm + mt * 16 + col) * 64 + pos];
                alf[mt] = *(const half8*)&sAl[(wm + mt * 16 + col) * 64 + pos];
            }
            #pragma unroll
            for (int nt = 0; nt < 2; ++nt)
                whf[nt] = *(const half8*)&sWh[(wn + nt * 16 + col) * 64 + pos];
            #pragma unroll
            for (int mt = 0; mt < 4; ++mt)
                #pragma unroll
                for (int nt = 0; nt < 2; ++nt) {
                    acc_h[mt][nt] = MFMA16(ahf[mt], whf[nt], acc_h[mt][nt]);
                    acc_x[mt][nt] = MFMA16(alf[mt], whf[nt], acc_x[mt][nt]);
                }
        }
    }

    float bv2[2];
    #pragma unroll
    for (int nt = 0; nt < 2; ++nt) bv2[nt] = bias[n0 + wn + nt * 16 + col];

    #pragma unroll
    for (int mt = 0; mt < 4; ++mt) {
        const int m = m0 + wm + mt * 16 + quad * 4;
        #pragma unroll
        for (int nt = 0; nt < 2; ++nt) {
            const int n = n0 + wn + nt * 16 + col;
            #pragma unroll
            for (int r = 0; r < 4; ++r)
                C[(size_t)(m + r) * 512 + n] =
                    acc_h[mt][nt][r] + acc_x[mt][nt][r] * INV_SPLIT + bv2[nt];
        }
    }
}

// ============================================================================
extern "C" void kernel_launch(void* const* d_in, const int* in_sizes, int n_in,
                              void* d_out, int out_size, void* d_ws, size_t ws_size,
                              hipStream_t stream) {
    const float* query = (const float*)d_in[0];
    const float* key   = (const float*)d_in[1];
    const float* value = (const float*)d_in[2];
    const float* w_q   = (const float*)d_in[3];
    const float* b_q   = (const float*)d_in[4];
    const float* w_k   = (const float*)d_in[5];
    const float* b_k   = (const float*)d_in[6];
    const float* w_v   = (const float*)d_in[7];
    const float* b_v   = (const float*)d_in[8];
    const float* w_o   = (const float*)d_in[9];
    const float* b_o   = (const float*)d_in[10];
    float* out = (float*)d_out;

    const int WN = D_MODEL * D_MODEL;                     // 262144
    const size_t plane = (size_t)BATCH * SEQ * D_MODEL;   // 4.19M halves

    _Float16* base = (_Float16*)d_ws;
    _Float16* Aq16 = base;                 // activations fp16 (later reused: Oh)
    _Float16* Ak16 = Aq16 + plane;         // (later reused: Ol)
    _Float16* Av16 = Ak16 + plane;
    _Float16* whq  = Av16 + plane;
    _Float16* whk  = whq + WN;
    _Float16* whv  = whk + WN;
    _Float16* who  = whv + WN;
    _Float16* wlo  = who + WN;
    _Float16* Qf   = wlo + WN;
    _Float16* Kf   = Qf + plane;
    _Float16* Vtf  = Kf + plane;           // total ws: ~53 MB
    _Float16* Oh   = Aq16;                 // alias: activations dead after gemm_qkv
    _Float16* Ol   = Ak16;

    dim3 blk(256);

    hipLaunchKernelGGL(cvt3, dim3((int)(plane / 1024), 3), blk, 0, stream,
                       query, key, value, Aq16, Ak16, Av16);

    hipLaunchKernelGGL(split_w, dim3(WN / 1024, 4), blk, 0, stream,
                       w_q, w_k, w_v, w_o,
                       whq, whk, whv, who, wlo, WN);

    hipLaunchKernelGGL(gemm_qkv, dim3(D_MODEL / 128, BATCH * SEQ / 128, 3), blk, 0, stream,
                       Aq16, Ak16, Av16,
                       whq, whk, whv,
                       b_q, b_k, b_v, Qf, Kf, Vtf);

    hipLaunchKernelGGL(attn_mfma, dim3(SEQ / 64, NHEADS, BATCH), blk, 0, stream,
                       Qf, Kf, Vtf, Oh, Ol);

    hipLaunchKernelGGL(gemm_out, dim3(D_MODEL / 64, BATCH * SEQ / 128), blk, 0, stream,
                       Oh, Ol, who, b_o, out);
}

// Round 10
// 310.563 us; speedup vs baseline: 1.7695x; 1.0477x over previous
//
#include <hip/hip_runtime.h>
#include <math.h>

#define D_MODEL 512
#define NHEADS 8
#define DK 64
#define BATCH 2
#define SEQ 4096
// log2(e)/8 folded into Q projection: scores in log2 domain, softmax uses exp2.
#define ATTN_SCALE 0.18033688011112043f
#define SPLIT_SCALE 2048.0f     // 2^11: lo plane pre-scaled to stay in fp16 normal range
#define INV_SPLIT  (1.0f/2048.0f)

typedef _Float16 half8 __attribute__((ext_vector_type(8)));
typedef float f32x4 __attribute__((ext_vector_type(4)));

union Pk8 { _Float16 h[8]; uint4 u; };
union Pk4 { _Float16 h[4]; uint2 u; };

#define MFMA16(a, b, c) __builtin_amdgcn_mfma_f32_16x16x32_f16((a), (b), (c), 0, 0, 0)

// async global->LDS, 16 B/lane; LDS dest = wave-uniform base + lane*16
__device__ __forceinline__ void gload_lds16(const _Float16* g, _Float16* l) {
    __builtin_amdgcn_global_load_lds(
        (const __attribute__((address_space(1))) void*)g,
        (__attribute__((address_space(3))) void*)l, 16, 0, 0);
}

// ============================================================================
// prep: one launch does fp32->fp16 conversion of the 3 activation tensors AND
// the 4 weight hi-planes (+ lo plane for w_o). Flattened 1-D grid:
//   blocks [0, 3*4096)          -> activations (plane = 4.19M elems each)
//   blocks [3*4096, 3*4096+4*256) -> weights   (WN = 262144 elems each)
// ============================================================================
#define ABLK 4096   // plane / 1024
#define WBLK 256    // WN / 1024
__global__ __launch_bounds__(256)
void prep(const float* __restrict__ aq, const float* __restrict__ ak,
          const float* __restrict__ av,
          const float* __restrict__ wq, const float* __restrict__ wk,
          const float* __restrict__ wv, const float* __restrict__ wo,
          _Float16* __restrict__ dq, _Float16* __restrict__ dk,
          _Float16* __restrict__ dv,
          _Float16* __restrict__ hq, _Float16* __restrict__ hk,
          _Float16* __restrict__ hv, _Float16* __restrict__ ho,
          _Float16* __restrict__ lo) {
    int gid = blockIdx.x;
    const float* src;
    _Float16 *hi, *lw = nullptr;
    if (gid < 3 * ABLK) {
        const int w = gid / ABLK;
        gid -= w * ABLK;
        src = w == 0 ? aq : (w == 1 ? ak : av);
        hi  = w == 0 ? dq : (w == 1 ? dk : dv);
    } else {
        int g = gid - 3 * ABLK;
        const int w = g / WBLK;
        gid = g - w * WBLK;
        src = w == 0 ? wq : (w == 1 ? wk : (w == 2 ? wv : wo));
        hi  = w == 0 ? hq : (w == 1 ? hk : (w == 2 ? hv : ho));
        if (w == 3) lw = lo;
    }
    const int i = (gid * 256 + threadIdx.x) * 4;
    float4 v = *(const float4*)(src + i);
    Pk4 h;
    h.h[0] = (_Float16)v.x; h.h[1] = (_Float16)v.y;
    h.h[2] = (_Float16)v.z; h.h[3] = (_Float16)v.w;
    *(uint2*)(hi + i) = h.u;
    if (lw) {
        Pk4 l;
        l.h[0] = (_Float16)((v.x - (float)h.h[0]) * SPLIT_SCALE);
        l.h[1] = (_Float16)((v.y - (float)h.h[1]) * SPLIT_SCALE);
        l.h[2] = (_Float16)((v.z - (float)h.h[2]) * SPLIT_SCALE);
        l.h[3] = (_Float16)((v.w - (float)h.h[3]) * SPLIT_SCALE);
        *(uint2*)(lw + i) = l.u;
    }
}

// ============================================================================
// QKV projection GEMM, m97-style DMA staging, unpadded XOR-swizzled LDS,
// 2-barrier K-loop. Block 128x128, BK=64, 4 waves 2x2. LDS 32 KB.
// z=0: Q (alpha=ATTN_SCALE)  z=1: K  z=2: V transposed per-head [b*8+h][d][s].
// ============================================================================
__global__ __launch_bounds__(256)
void gemm_qkv(const _Float16* __restrict__ Aq, const _Float16* __restrict__ Ak,
              const _Float16* __restrict__ Av,
              const _Float16* __restrict__ Whq, const _Float16* __restrict__ Whk,
              const _Float16* __restrict__ Whv,
              const float* __restrict__ bq, const float* __restrict__ bk,
              const float* __restrict__ bv,
              _Float16* __restrict__ Qf, _Float16* __restrict__ Kf,
              _Float16* __restrict__ Vtf) {
    const int z = blockIdx.z;
    const _Float16* A    = z == 0 ? Aq  : (z == 1 ? Ak  : Av);
    const _Float16* Wh   = z == 0 ? Whq : (z == 1 ? Whk : Whv);
    const float*    bias = z == 0 ? bq  : (z == 1 ? bk  : bv);

    __shared__ __align__(16) _Float16 sA[128 * 64];
    __shared__ __align__(16) _Float16 sW[128 * 64];

    const int t    = threadIdx.x;
    const int lane = t & 63, wave = t >> 6;
    const int col  = lane & 15, quad = lane >> 4;
    const int wm   = (wave & 1) * 64, wn = (wave >> 1) * 64;
    const int m0   = blockIdx.y * 128, n0 = blockIdx.x * 128;

    const int subrow = lane >> 3;
    const int schunk = ((lane & 7) ^ subrow) * 8;

    f32x4 acc[4][4] = {};

    for (int k0 = 0; k0 < 512; k0 += 64) {
        __syncthreads();
        #pragma unroll
        for (int j = 0; j < 4; ++j) {
            const int rw = wave * 32 + j * 8;
            gload_lds16(A  + (size_t)(m0 + rw + subrow) * 512 + k0 + schunk, &sA[rw * 64]);
            gload_lds16(Wh + (size_t)(n0 + rw + subrow) * 512 + k0 + schunk, &sW[rw * 64]);
        }
        __syncthreads();

        #pragma unroll
        for (int kc = 0; kc < 2; ++kc) {
            const int pos = ((kc * 4 + quad) ^ (col & 7)) * 8;
            half8 af[4], wf[4];
            #pragma unroll
            for (int mt = 0; mt < 4; ++mt)
                af[mt] = *(const half8*)&sA[(wm + mt * 16 + col) * 64 + pos];
            #pragma unroll
            for (int nt = 0; nt < 4; ++nt)
                wf[nt] = *(const half8*)&sW[(wn + nt * 16 + col) * 64 + pos];
            #pragma unroll
            for (int mt = 0; mt < 4; ++mt)
                #pragma unroll
                for (int nt = 0; nt < 4; ++nt)
                    acc[mt][nt] = MFMA16(af[mt], wf[nt], acc[mt][nt]);
        }
    }

    float bv4[4];
    #pragma unroll
    for (int nt = 0; nt < 4; ++nt) bv4[nt] = bias[n0 + wn + nt * 16 + col];

    if (z < 2) {
        _Float16* Out = z == 0 ? Qf : Kf;
        const float alpha = z == 0 ? ATTN_SCALE : 1.0f;
        #pragma unroll
        for (int mt = 0; mt < 4; ++mt) {
            const int m = m0 + wm + mt * 16 + quad * 4;
            #pragma unroll
            for (int nt = 0; nt < 4; ++nt) {
                const int n = n0 + wn + nt * 16 + col;
                #pragma unroll
                for (int r = 0; r < 4; ++r)
                    Out[(size_t)(m + r) * 512 + n] = (_Float16)((acc[mt][nt][r] + bv4[nt]) * alpha);
            }
        }
    } else {
        #pragma unroll
        for (int mt = 0; mt < 4; ++mt) {
            const int m = m0 + wm + mt * 16 + quad * 4;
            const int b = m >> 12, s = m & (SEQ - 1);
            #pragma unroll
            for (int nt = 0; nt < 4; ++nt) {
                const int n = n0 + wn + nt * 16 + col;
                const int hh = n >> 6, d = n & (DK - 1);
                Pk4 p;
                #pragma unroll
                for (int r = 0; r < 4; ++r)
                    p.h[r] = (_Float16)(acc[mt][nt][r] + bv4[nt]);
                *(uint2*)&Vtf[((size_t)((b * NHEADS + hh) * DK + d)) * SEQ + s] = p.u;
            }
        }
    }
}

// ============================================================================
// Flash attention, fp16 MFMA. 64 queries/block (16/wave), 64-key iterations.
// LRS-GUARD lazy softmax: m_r frozen after the eager tile-0 max; fast path is
// exp2 + sum + pack only. Overflow detected via the already-computed lrs sum
// (__any(lrs > 1024) -> some p >= 64); the guard tile's contribution is still
// exact (fp16 holds 65504), slow path computes the true max, rescales of/l,
// and bumps m_r for future tiles. Removes 15 fmax + 2 LDS-pipe shuffles/iter.
// Async-DMA double-buffered K/V, XOR-swizzled LDS, 40960 B -> 4 blocks/CU.
// ============================================================================
__global__ __launch_bounds__(256)
void attn_mfma(const _Float16* __restrict__ Qf, const _Float16* __restrict__ Kf,
               const _Float16* __restrict__ Vtf,
               _Float16* __restrict__ Oh, _Float16* __restrict__ Ol) {
    __shared__ __align__(16) _Float16 sK[2][64 * 64];
    __shared__ __align__(16) _Float16 sV[2][64 * 64];
    __shared__ __align__(16) _Float16 sP[64 * 64];

    const int t    = threadIdx.x;
    const int lane = t & 63;
    const int wave = t >> 6;
    const int col  = lane & 15;
    const int quad = lane >> 4;

    const int q0 = blockIdx.x * 64;
    const int h  = blockIdx.y;
    const int b  = blockIdx.z;

    const size_t rowBase = (size_t)b * SEQ;
    const size_t vBase   = ((size_t)(b * NHEADS + h)) * DK * SEQ;

    const int subrow = lane >> 3;
    const int schunk = ((lane & 7) ^ subrow) * 8;
    #define STAGE_KV(K0, BUF)                                                        \
        do {                                                                          \
            _Pragma("unroll")                                                         \
            for (int j = 0; j < 2; ++j) {                                             \
                const int rw = wave * 16 + j * 8;                                     \
                gload_lds16(Kf + (rowBase + (K0) + rw + subrow) * 512 + h * 64 + schunk, \
                            &sK[BUF][rw * 64]);                                       \
                gload_lds16(Vtf + vBase + (size_t)(rw + subrow) * SEQ + (K0) + schunk,   \
                            &sV[BUF][rw * 64]);                                       \
            }                                                                         \
        } while (0)

    STAGE_KV(0, 0);

    {
        uint4 qv[2];
        #pragma unroll
        for (int i2 = 0; i2 < 2; ++i2) {
            const int slot = t + i2 * 256;
            const int r = slot >> 3, sl = slot & 7;
            qv[i2] = *(const uint4*)(Qf + (rowBase + q0 + r) * 512 + h * 64 + sl * 8);
        }
        #pragma unroll
        for (int i2 = 0; i2 < 2; ++i2) {
            const int slot = t + i2 * 256;
            const int r = slot >> 3, sl = slot & 7;
            *(uint4*)&sP[r * 64 + (sl ^ (r & 7)) * 8] = qv[i2];
        }
    }
    __syncthreads();

    half8 qf[2];
    #pragma unroll
    for (int kc = 0; kc < 2; ++kc)
        qf[kc] = *(const half8*)&sP[(wave * 16 + col) * 64 + ((kc * 4 + quad) ^ (col & 7)) * 8];

    _Float16* Ps = sP + wave * 16 * 64;
    const int pmsk = (col & 7) << 1;

    float m_r = -INFINITY;
    float l_r = 0.0f;
    f32x4 of[4] = {};

    for (int it = 0; it < SEQ / 64; ++it) {
        const int cur = it & 1;
        __syncthreads();
        if (it + 1 < SEQ / 64) STAGE_KV((it + 1) * 64, cur ^ 1);

        const _Float16* Kc = sK[cur];
        const _Float16* Vc = sV[cur];

        // ---- S^T = K · Q^T : 8 MFMA ----
        f32x4 sf[4] = {};
        #pragma unroll
        for (int kc = 0; kc < 2; ++kc) {
            const int pos = ((kc * 4 + quad) ^ (col & 7)) * 8;
            #pragma unroll
            for (int kt = 0; kt < 4; ++kt) {
                half8 kf = *(const half8*)&Kc[(kt * 16 + col) * 64 + pos];
                sf[kt] = MFMA16(kf, qf[kc], sf[kt]);
            }
        }

        // ---- tile 0: eager max establishes the frozen scale ----
        if (it == 0) {
            float mx = sf[0][0];
            #pragma unroll
            for (int kt = 0; kt < 4; ++kt)
                #pragma unroll
                for (int r = 0; r < 4; ++r)
                    mx = fmaxf(mx, sf[kt][r]);
            mx = fmaxf(mx, __shfl_xor(mx, 16));
            mx = fmaxf(mx, __shfl_xor(mx, 32));
            m_r = mx;
        }

        // ---- fast path: P = exp2(s - m_r), sum, pack (no max, no shuffles) ----
        float lrs = 0.0f;
        #pragma unroll
        for (int kt = 0; kt < 4; ++kt) {
            const float p0 = exp2f(sf[kt][0] - m_r);
            const float p1 = exp2f(sf[kt][1] - m_r);
            const float p2 = exp2f(sf[kt][2] - m_r);
            const float p3 = exp2f(sf[kt][3] - m_r);
            lrs += (p0 + p1) + (p2 + p3);
            Pk4 z;
            z.h[0] = (_Float16)p0; z.h[1] = (_Float16)p1;
            z.h[2] = (_Float16)p2; z.h[3] = (_Float16)p3;
            *(uint2*)&Ps[col * 64 + ((kt * 4 + quad) ^ pmsk) * 4] = z.u;
        }

        // ---- O^T += V^T · P^T : 8 MFMA ----
        #pragma unroll
        for (int kc = 0; kc < 2; ++kc) {
            half8 pf = *(const half8*)&Ps[col * 64 + ((kc * 8 + quad * 2) ^ pmsk) * 4];
            const int pos = ((kc * 4 + quad) ^ (col & 7)) * 8;
            #pragma unroll
            for (int dt = 0; dt < 4; ++dt) {
                half8 vf = *(const half8*)&Vc[(dt * 16 + col) * 64 + pos];
                of[dt] = MFMA16(vf, pf, of[dt]);
            }
        }

        l_r += lrs;

        // ---- rare slow path: some p >= 64 -> re-center the scale ----
        if (__any(lrs > 1024.0f)) {
            float mx = sf[0][0];
            #pragma unroll
            for (int kt = 0; kt < 4; ++kt)
                #pragma unroll
                for (int r = 0; r < 4; ++r)
                    mx = fmaxf(mx, sf[kt][r]);
            mx = fmaxf(mx, __shfl_xor(mx, 16));
            mx = fmaxf(mx, __shfl_xor(mx, 32));
            if (mx > m_r) {
                const float al = exp2f(m_r - mx);
                l_r *= al;
                #pragma unroll
                for (int dt = 0; dt < 4; ++dt)
                    #pragma unroll
                    for (int r = 0; r < 4; ++r)
                        of[dt][r] *= al;
                m_r = mx;
            }
        }
    }

    l_r += __shfl_xor(l_r, 16);
    l_r += __shfl_xor(l_r, 32);

    const float inv = 1.0f / l_r;
    const size_t base = (rowBase + q0 + wave * 16 + col) * 512 + h * 64;
    #pragma unroll
    for (int dt = 0; dt < 4; ++dt) {
        float v[4];
        #pragma unroll
        for (int r = 0; r < 4; ++r) v[r] = of[dt][r] * inv;
        Pk4 hh, ll;
        #pragma unroll
        for (int r = 0; r < 4; ++r) {
            hh.h[r] = (_Float16)v[r];
            ll.h[r] = (_Float16)((v[r] - (float)hh.h[r]) * SPLIT_SCALE);
        }
        *(uint2*)(Oh + base + dt * 16 + quad * 4) = hh.u;
        *(uint2*)(Ol + base + dt * 16 + quad * 4) = ll.u;
    }
}

// ============================================================================
// Output projection, DMA-staged. A split (hi+lo), W hi-only. Block 128x64.
// LDS 40 KB. 2 MFMA per tile. fp32 out + bias.
// ============================================================================
__global__ __launch_bounds__(256)
void gemm_out(const _Float16* __restrict__ Ah, const _Float16* __restrict__ Al,
              const _Float16* __restrict__ Wh,
              const float* __restrict__ bias, float* __restrict__ C) {
    __shared__ __align__(16) _Float16 sAh[128 * 64];
    __shared__ __align__(16) _Float16 sAl[128 * 64];
    __shared__ __align__(16) _Float16 sWh[64 * 64];

    const int t    = threadIdx.x;
    const int lane = t & 63, wave = t >> 6;
    const int col  = lane & 15, quad = lane >> 4;
    const int wm   = (wave & 1) * 64, wn = (wave >> 1) * 32;
    const int m0   = blockIdx.y * 128, n0 = blockIdx.x * 64;

    const int subrow = lane >> 3;
    const int schunk = ((lane & 7) ^ subrow) * 8;

    f32x4 acc_h[4][2] = {};
    f32x4 acc_x[4][2] = {};

    for (int k0 = 0; k0 < 512; k0 += 64) {
        __syncthreads();
        #pragma unroll
        for (int j = 0; j < 4; ++j) {
            const int rw = wave * 32 + j * 8;
            gload_lds16(Ah + (size_t)(m0 + rw + subrow) * 512 + k0 + schunk, &sAh[rw * 64]);
            gload_lds16(Al + (size_t)(m0 + rw + subrow) * 512 + k0 + schunk, &sAl[rw * 64]);
        }
        #pragma unroll
        for (int j = 0; j < 2; ++j) {
            const int rw = wave * 16 + j * 8;
            gload_lds16(Wh + (size_t)(n0 + rw + subrow) * 512 + k0 + schunk, &sWh[rw * 64]);
        }
        __syncthreads();

        #pragma unroll
        for (int kc = 0; kc < 2; ++kc) {
            const int pos = ((kc * 4 + quad) ^ (col & 7)) * 8;
            half8 ahf[4], alf[4], whf[2];
            #pragma unroll
            for (int mt = 0; mt < 4; ++mt) {
                ahf[mt] = *(const half8*)&sAh[(wm + mt * 16 + col) * 64 + pos];
                alf[mt] = *(const half8*)&sAl[(wm + mt * 16 + col) * 64 + pos];
            }
            #pragma unroll
            for (int nt = 0; nt < 2; ++nt)
                whf[nt] = *(const half8*)&sWh[(wn + nt * 16 + col) * 64 + pos];
            #pragma unroll
            for (int mt = 0; mt < 4; ++mt)
                #pragma unroll
                for (int nt = 0; nt < 2; ++nt) {
                    acc_h[mt][nt] = MFMA16(ahf[mt], whf[nt], acc_h[mt][nt]);
                    acc_x[mt][nt] = MFMA16(alf[mt], whf[nt], acc_x[mt][nt]);
                }
        }
    }

    float bv2[2];
    #pragma unroll
    for (int nt = 0; nt < 2; ++nt) bv2[nt] = bias[n0 + wn + nt * 16 + col];

    #pragma unroll
    for (int mt = 0; mt < 4; ++mt) {
        const int m = m0 + wm + mt * 16 + quad * 4;
        #pragma unroll
        for (int nt = 0; nt < 2; ++nt) {
            const int n = n0 + wn + nt * 16 + col;
            #pragma unroll
            for (int r = 0; r < 4; ++r)
                C[(size_t)(m + r) * 512 + n] =
                    acc_h[mt][nt][r] + acc_x[mt][nt][r] * INV_SPLIT + bv2[nt];
        }
    }
}

// ============================================================================
extern "C" void kernel_launch(void* const* d_in, const int* in_sizes, int n_in,
                              void* d_out, int out_size, void* d_ws, size_t ws_size,
                              hipStream_t stream) {
    const float* query = (const float*)d_in[0];
    const float* key   = (const float*)d_in[1];
    const float* value = (const float*)d_in[2];
    const float* w_q   = (const float*)d_in[3];
    const float* b_q   = (const float*)d_in[4];
    const float* w_k   = (const float*)d_in[5];
    const float* b_k   = (const float*)d_in[6];
    const float* w_v   = (const float*)d_in[7];
    const float* b_v   = (const float*)d_in[8];
    const float* w_o   = (const float*)d_in[9];
    const float* b_o   = (const float*)d_in[10];
    float* out = (float*)d_out;

    const int WN = D_MODEL * D_MODEL;                     // 262144
    const size_t plane = (size_t)BATCH * SEQ * D_MODEL;   // 4.19M halves

    _Float16* base = (_Float16*)d_ws;
    _Float16* Aq16 = base;                 // activations fp16 (later reused: Oh)
    _Float16* Ak16 = Aq16 + plane;         // (later reused: Ol)
    _Float16* Av16 = Ak16 + plane;
    _Float16* whq  = Av16 + plane;
    _Float16* whk  = whq + WN;
    _Float16* whv  = whk + WN;
    _Float16* who  = whv + WN;
    _Float16* wlo  = who + WN;
    _Float16* Qf   = wlo + WN;
    _Float16* Kf   = Qf + plane;
    _Float16* Vtf  = Kf + plane;           // total ws: ~53 MB
    _Float16* Oh   = Aq16;                 // alias: activations dead after gemm_qkv
    _Float16* Ol   = Ak16;

    dim3 blk(256);

    hipLaunchKernelGGL(prep, dim3(3 * ABLK + 4 * WBLK), blk, 0, stream,
                       query, key, value, w_q, w_k, w_v, w_o,
                       Aq16, Ak16, Av16, whq, whk, whv, who, wlo);

    hipLaunchKernelGGL(gemm_qkv, dim3(D_MODEL / 128, BATCH * SEQ / 128, 3), blk, 0, stream,
                       Aq16, Ak16, Av16,
                       whq, whk, whv,
                       b_q, b_k, b_v, Qf, Kf, Vtf);

    hipLaunchKernelGGL(attn_mfma, dim3(SEQ / 64, NHEADS, BATCH), blk, 0, stream,
                       Qf, Kf, Vtf, Oh, Ol);

    hipLaunchKernelGGL(gemm_out, dim3(D_MODEL / 64, BATCH * SEQ / 128), blk, 0, stream,
                       Oh, Ol, who, b_o, out);
}

// Round 11
// 298.154 us; speedup vs baseline: 1.8431x; 1.0416x over previous
//
#include <hip/hip_runtime.h>
#include <math.h>

#define D_MODEL 512
#define NHEADS 8
#define DK 64
#define BATCH 2
#define SEQ 4096
// log2(e)/8 folded into Q projection: scores in log2 domain, softmax uses exp2.
#define ATTN_SCALE 0.18033688011112043f
#define SPLIT_SCALE 2048.0f     // 2^11: lo plane pre-scaled to stay in fp16 normal range
#define INV_SPLIT  (1.0f/2048.0f)

typedef _Float16 half8 __attribute__((ext_vector_type(8)));
typedef float f32x4 __attribute__((ext_vector_type(4)));

union Pk8 { _Float16 h[8]; uint4 u; };
union Pk4 { _Float16 h[4]; uint2 u; };

#define MFMA16(a, b, c) __builtin_amdgcn_mfma_f32_16x16x32_f16((a), (b), (c), 0, 0, 0)

// async global->LDS, 16 B/lane; LDS dest = wave-uniform base + lane*16
__device__ __forceinline__ void gload_lds16(const _Float16* g, _Float16* l) {
    __builtin_amdgcn_global_load_lds(
        (const __attribute__((address_space(1))) void*)g,
        (__attribute__((address_space(3))) void*)l, 16, 0, 0);
}

// ============================================================================
// prep: fp32->fp16 for 3 activations + 4 weight hi-planes (+ lo for w_o).
// ============================================================================
#define ABLK 4096   // plane / 1024
#define WBLK 256    // WN / 1024
__global__ __launch_bounds__(256)
void prep(const float* __restrict__ aq, const float* __restrict__ ak,
          const float* __restrict__ av,
          const float* __restrict__ wq, const float* __restrict__ wk,
          const float* __restrict__ wv, const float* __restrict__ wo,
          _Float16* __restrict__ dq, _Float16* __restrict__ dk,
          _Float16* __restrict__ dv,
          _Float16* __restrict__ hq, _Float16* __restrict__ hk,
          _Float16* __restrict__ hv, _Float16* __restrict__ ho,
          _Float16* __restrict__ lo) {
    int gid = blockIdx.x;
    const float* src;
    _Float16 *hi, *lw = nullptr;
    if (gid < 3 * ABLK) {
        const int w = gid / ABLK;
        gid -= w * ABLK;
        src = w == 0 ? aq : (w == 1 ? ak : av);
        hi  = w == 0 ? dq : (w == 1 ? dk : dv);
    } else {
        int g = gid - 3 * ABLK;
        const int w = g / WBLK;
        gid = g - w * WBLK;
        src = w == 0 ? wq : (w == 1 ? wk : (w == 2 ? wv : wo));
        hi  = w == 0 ? hq : (w == 1 ? hk : (w == 2 ? hv : ho));
        if (w == 3) lw = lo;
    }
    const int i = (gid * 256 + threadIdx.x) * 4;
    float4 v = *(const float4*)(src + i);
    Pk4 h;
    h.h[0] = (_Float16)v.x; h.h[1] = (_Float16)v.y;
    h.h[2] = (_Float16)v.z; h.h[3] = (_Float16)v.w;
    *(uint2*)(hi + i) = h.u;
    if (lw) {
        Pk4 l;
        l.h[0] = (_Float16)((v.x - (float)h.h[0]) * SPLIT_SCALE);
        l.h[1] = (_Float16)((v.y - (float)h.h[1]) * SPLIT_SCALE);
        l.h[2] = (_Float16)((v.z - (float)h.h[2]) * SPLIT_SCALE);
        l.h[3] = (_Float16)((v.w - (float)h.h[3]) * SPLIT_SCALE);
        *(uint2*)(lw + i) = l.u;
    }
}

// ============================================================================
// QKV projection GEMM. DOUBLE-BUFFERED DMA staging (attn round-7 pattern):
// one barrier per chunk; chunk k+1 DMA issued right after, landing during
// compute of chunk k. Block 128x128, BK=64, LDS 64 KB -> 2 blocks/CU.
// z=0: Q (alpha=ATTN_SCALE)  z=1: K  z=2: V transposed per-head [b*8+h][d][s].
// ============================================================================
__global__ __launch_bounds__(256)
void gemm_qkv(const _Float16* __restrict__ Aq, const _Float16* __restrict__ Ak,
              const _Float16* __restrict__ Av,
              const _Float16* __restrict__ Whq, const _Float16* __restrict__ Whk,
              const _Float16* __restrict__ Whv,
              const float* __restrict__ bq, const float* __restrict__ bk,
              const float* __restrict__ bv,
              _Float16* __restrict__ Qf, _Float16* __restrict__ Kf,
              _Float16* __restrict__ Vtf) {
    const int z = blockIdx.z;
    const _Float16* A    = z == 0 ? Aq  : (z == 1 ? Ak  : Av);
    const _Float16* Wh   = z == 0 ? Whq : (z == 1 ? Whk : Whv);
    const float*    bias = z == 0 ? bq  : (z == 1 ? bk  : bv);

    __shared__ __align__(16) _Float16 sA[2][128 * 64];
    __shared__ __align__(16) _Float16 sW[2][128 * 64];

    const int t    = threadIdx.x;
    const int lane = t & 63, wave = t >> 6;
    const int col  = lane & 15, quad = lane >> 4;
    const int wm   = (wave & 1) * 64, wn = (wave >> 1) * 64;
    const int m0   = blockIdx.y * 128, n0 = blockIdx.x * 128;

    const int subrow = lane >> 3;
    const int schunk = ((lane & 7) ^ subrow) * 8;

    #define STAGE_AW(K0, BUF)                                                        \
        do {                                                                          \
            _Pragma("unroll")                                                         \
            for (int j = 0; j < 4; ++j) {                                             \
                const int rw = wave * 32 + j * 8;                                     \
                gload_lds16(A  + (size_t)(m0 + rw + subrow) * 512 + (K0) + schunk,    \
                            &sA[BUF][rw * 64]);                                       \
                gload_lds16(Wh + (size_t)(n0 + rw + subrow) * 512 + (K0) + schunk,    \
                            &sW[BUF][rw * 64]);                                       \
            }                                                                         \
        } while (0)

    f32x4 acc[4][4] = {};

    STAGE_AW(0, 0);
    for (int ck = 0; ck < 8; ++ck) {
        const int cur = ck & 1;
        __syncthreads();   // drains DMA for chunk ck; all waves done with alt buffer
        if (ck + 1 < 8) STAGE_AW((ck + 1) * 64, cur ^ 1);

        #pragma unroll
        for (int kc = 0; kc < 2; ++kc) {
            const int pos = ((kc * 4 + quad) ^ (col & 7)) * 8;
            half8 af[4], wf[4];
            #pragma unroll
            for (int mt = 0; mt < 4; ++mt)
                af[mt] = *(const half8*)&sA[cur][(wm + mt * 16 + col) * 64 + pos];
            #pragma unroll
            for (int nt = 0; nt < 4; ++nt)
                wf[nt] = *(const half8*)&sW[cur][(wn + nt * 16 + col) * 64 + pos];
            #pragma unroll
            for (int mt = 0; mt < 4; ++mt)
                #pragma unroll
                for (int nt = 0; nt < 4; ++nt)
                    acc[mt][nt] = MFMA16(af[mt], wf[nt], acc[mt][nt]);
        }
    }

    float bv4[4];
    #pragma unroll
    for (int nt = 0; nt < 4; ++nt) bv4[nt] = bias[n0 + wn + nt * 16 + col];

    if (z < 2) {
        _Float16* Out = z == 0 ? Qf : Kf;
        const float alpha = z == 0 ? ATTN_SCALE : 1.0f;
        #pragma unroll
        for (int mt = 0; mt < 4; ++mt) {
            const int m = m0 + wm + mt * 16 + quad * 4;
            #pragma unroll
            for (int nt = 0; nt < 4; ++nt) {
                const int n = n0 + wn + nt * 16 + col;
                #pragma unroll
                for (int r = 0; r < 4; ++r)
                    Out[(size_t)(m + r) * 512 + n] = (_Float16)((acc[mt][nt][r] + bv4[nt]) * alpha);
            }
        }
    } else {
        #pragma unroll
        for (int mt = 0; mt < 4; ++mt) {
            const int m = m0 + wm + mt * 16 + quad * 4;
            const int b = m >> 12, s = m & (SEQ - 1);
            #pragma unroll
            for (int nt = 0; nt < 4; ++nt) {
                const int n = n0 + wn + nt * 16 + col;
                const int hh = n >> 6, d = n & (DK - 1);
                Pk4 p;
                #pragma unroll
                for (int r = 0; r < 4; ++r)
                    p.h[r] = (_Float16)(acc[mt][nt][r] + bv4[nt]);
                *(uint2*)&Vtf[((size_t)((b * NHEADS + hh) * DK + d)) * SEQ + s] = p.u;
            }
        }
    }
}

// ============================================================================
// Flash attention, fp16 MFMA. 128 queries/block, 32 PER WAVE (2 nt tiles):
// K/V frag reads don't scale with queries, so doubling queries/wave cuts LDS
// traffic per unit work 1.67x (the round-10 LDS-pipe bottleneck: ~100 us of
// b128 serialization at 16q/wave). 32 MFMA per wave-iter. LRS-guard lazy
// softmax (per-nt state). LDS 48 KB (sK 16 + sV 16 + sP 16) -> grid 512,
// 2 blocks/CU.
// ============================================================================
__global__ __launch_bounds__(256)
void attn_mfma(const _Float16* __restrict__ Qf, const _Float16* __restrict__ Kf,
               const _Float16* __restrict__ Vtf,
               _Float16* __restrict__ Oh, _Float16* __restrict__ Ol) {
    __shared__ __align__(16) _Float16 sK[2][64 * 64];
    __shared__ __align__(16) _Float16 sV[2][64 * 64];
    __shared__ __align__(16) _Float16 sP[128 * 64];   // Q staging, then per-wave P (32 rows)

    const int t    = threadIdx.x;
    const int lane = t & 63;
    const int wave = t >> 6;
    const int col  = lane & 15;
    const int quad = lane >> 4;

    const int q0 = blockIdx.x * 128;
    const int h  = blockIdx.y;
    const int b  = blockIdx.z;

    const size_t rowBase = (size_t)b * SEQ;
    const size_t vBase   = ((size_t)(b * NHEADS + h)) * DK * SEQ;

    const int subrow = lane >> 3;
    const int schunk = ((lane & 7) ^ subrow) * 8;
    #define STAGE_KV(K0, BUF)                                                        \
        do {                                                                          \
            _Pragma("unroll")                                                         \
            for (int j = 0; j < 2; ++j) {                                             \
                const int rw = wave * 16 + j * 8;                                     \
                gload_lds16(Kf + (rowBase + (K0) + rw + subrow) * 512 + h * 64 + schunk, \
                            &sK[BUF][rw * 64]);                                       \
                gload_lds16(Vtf + vBase + (size_t)(rw + subrow) * SEQ + (K0) + schunk,   \
                            &sV[BUF][rw * 64]);                                       \
            }                                                                         \
        } while (0)

    STAGE_KV(0, 0);

    // ---- stage Q tile (128 x 64 halves) into sP with the row XOR swizzle ----
    {
        uint4 qv[4];
        #pragma unroll
        for (int i2 = 0; i2 < 4; ++i2) {
            const int slot = t + i2 * 256;           // 128 rows x 8 chunks
            const int r = slot >> 3, sl = slot & 7;
            qv[i2] = *(const uint4*)(Qf + (rowBase + q0 + r) * 512 + h * 64 + sl * 8);
        }
        #pragma unroll
        for (int i2 = 0; i2 < 4; ++i2) {
            const int slot = t + i2 * 256;
            const int r = slot >> 3, sl = slot & 7;
            *(uint4*)&sP[r * 64 + (sl ^ (r & 7)) * 8] = qv[i2];
        }
    }
    __syncthreads();

    half8 qf[2][2];   // [nt][kc]; wave owns query rows wave*32 .. +31
    #pragma unroll
    for (int nt = 0; nt < 2; ++nt)
        #pragma unroll
        for (int kc = 0; kc < 2; ++kc)
            qf[nt][kc] = *(const half8*)&sP[(wave * 32 + nt * 16 + col) * 64 +
                                            ((kc * 4 + quad) ^ (col & 7)) * 8];

    _Float16* Ps = sP + wave * 32 * 64;   // 32 rows x 64, private to this wave
    const int pmsk = (col & 7) << 1;

    float m_r[2] = { -INFINITY, -INFINITY };
    float l_r[2] = { 0.0f, 0.0f };
    f32x4 of[4][2] = {};

    for (int it = 0; it < SEQ / 64; ++it) {
        const int cur = it & 1;
        __syncthreads();   // drains prefetch DMA; also protects sP Q-frag reads on it=0
        if (it + 1 < SEQ / 64) STAGE_KV((it + 1) * 64, cur ^ 1);

        const _Float16* Kc = sK[cur];
        const _Float16* Vc = sV[cur];

        // ---- S^T = K · Q^T : 16 MFMA ----
        f32x4 sf[4][2] = {};
        #pragma unroll
        for (int kc = 0; kc < 2; ++kc) {
            const int pos = ((kc * 4 + quad) ^ (col & 7)) * 8;
            #pragma unroll
            for (int kt = 0; kt < 4; ++kt) {
                half8 kf = *(const half8*)&Kc[(kt * 16 + col) * 64 + pos];
                #pragma unroll
                for (int nt = 0; nt < 2; ++nt)
                    sf[kt][nt] = MFMA16(kf, qf[nt][kc], sf[kt][nt]);
            }
        }

        // ---- tile 0: eager max establishes the frozen scale ----
        if (it == 0) {
            #pragma unroll
            for (int nt = 0; nt < 2; ++nt) {
                float mx = sf[0][nt][0];
                #pragma unroll
                for (int kt = 0; kt < 4; ++kt)
                    #pragma unroll
                    for (int r = 0; r < 4; ++r)
                        mx = fmaxf(mx, sf[kt][nt][r]);
                mx = fmaxf(mx, __shfl_xor(mx, 16));
                mx = fmaxf(mx, __shfl_xor(mx, 32));
                m_r[nt] = mx;
            }
        }

        // ---- fast path: P = exp2(s - m_r), sum, pack ----
        float lrs[2];
        #pragma unroll
        for (int nt = 0; nt < 2; ++nt) {
            float ls = 0.0f;
            #pragma unroll
            for (int kt = 0; kt < 4; ++kt) {
                const float p0 = exp2f(sf[kt][nt][0] - m_r[nt]);
                const float p1 = exp2f(sf[kt][nt][1] - m_r[nt]);
                const float p2 = exp2f(sf[kt][nt][2] - m_r[nt]);
                const float p3 = exp2f(sf[kt][nt][3] - m_r[nt]);
                ls += (p0 + p1) + (p2 + p3);
                Pk4 z;
                z.h[0] = (_Float16)p0; z.h[1] = (_Float16)p1;
                z.h[2] = (_Float16)p2; z.h[3] = (_Float16)p3;
                *(uint2*)&Ps[(nt * 16 + col) * 64 + ((kt * 4 + quad) ^ pmsk) * 4] = z.u;
            }
            lrs[nt] = ls;
        }

        // ---- O^T += V^T · P^T : 16 MFMA ----
        #pragma unroll
        for (int kc = 0; kc < 2; ++kc) {
            half8 pf[2];
            #pragma unroll
            for (int nt = 0; nt < 2; ++nt)
                pf[nt] = *(const half8*)&Ps[(nt * 16 + col) * 64 +
                                            ((kc * 8 + quad * 2) ^ pmsk) * 4];
            const int pos = ((kc * 4 + quad) ^ (col & 7)) * 8;
            #pragma unroll
            for (int dt = 0; dt < 4; ++dt) {
                half8 vf = *(const half8*)&Vc[(dt * 16 + col) * 64 + pos];
                of[dt][0] = MFMA16(vf, pf[0], of[dt][0]);
                of[dt][1] = MFMA16(vf, pf[1], of[dt][1]);
            }
        }

        l_r[0] += lrs[0];
        l_r[1] += lrs[1];

        // ---- rare slow path: some p >= 64 -> re-center the scale ----
        if (__any(fmaxf(lrs[0], lrs[1]) > 1024.0f)) {
            #pragma unroll
            for (int nt = 0; nt < 2; ++nt) {
                float mx = sf[0][nt][0];
                #pragma unroll
                for (int kt = 0; kt < 4; ++kt)
                    #pragma unroll
                    for (int r = 0; r < 4; ++r)
                        mx = fmaxf(mx, sf[kt][nt][r]);
                mx = fmaxf(mx, __shfl_xor(mx, 16));
                mx = fmaxf(mx, __shfl_xor(mx, 32));
                if (mx > m_r[nt]) {
                    const float al = exp2f(m_r[nt] - mx);
                    l_r[nt] *= al;
                    #pragma unroll
                    for (int dt = 0; dt < 4; ++dt)
                        #pragma unroll
                        for (int r = 0; r < 4; ++r)
                            of[dt][nt][r] *= al;
                    m_r[nt] = mx;
                }
            }
        }
    }

    // ---- finalize ----
    #pragma unroll
    for (int nt = 0; nt < 2; ++nt) {
        float l = l_r[nt];
        l += __shfl_xor(l, 16);
        l += __shfl_xor(l, 32);
        const float inv = 1.0f / l;
        const size_t base = (rowBase + q0 + wave * 32 + nt * 16 + col) * 512 + h * 64;
        #pragma unroll
        for (int dt = 0; dt < 4; ++dt) {
            float v[4];
            #pragma unroll
            for (int r = 0; r < 4; ++r) v[r] = of[dt][nt][r] * inv;
            Pk4 hh, ll;
            #pragma unroll
            for (int r = 0; r < 4; ++r) {
                hh.h[r] = (_Float16)v[r];
                ll.h[r] = (_Float16)((v[r] - (float)hh.h[r]) * SPLIT_SCALE);
            }
            *(uint2*)(Oh + base + dt * 16 + quad * 4) = hh.u;
            *(uint2*)(Ol + base + dt * 16 + quad * 4) = ll.u;
        }
    }
}

// ============================================================================
// Output projection, DOUBLE-BUFFERED DMA staging. A split (hi+lo), W hi-only.
// Block 128x64, LDS 80 KB -> 2 blocks/CU. 2 MFMA per tile. fp32 out + bias.
// ============================================================================
__global__ __launch_bounds__(256)
void gemm_out(const _Float16* __restrict__ Ah, const _Float16* __restrict__ Al,
              const _Float16* __restrict__ Wh,
              const float* __restrict__ bias, float* __restrict__ C) {
    __shared__ __align__(16) _Float16 sAh[2][128 * 64];
    __shared__ __align__(16) _Float16 sAl[2][128 * 64];
    __shared__ __align__(16) _Float16 sWh[2][64 * 64];

    const int t    = threadIdx.x;
    const int lane = t & 63, wave = t >> 6;
    const int col  = lane & 15, quad = lane >> 4;
    const int wm   = (wave & 1) * 64, wn = (wave >> 1) * 32;
    const int m0   = blockIdx.y * 128, n0 = blockIdx.x * 64;

    const int subrow = lane >> 3;
    const int schunk = ((lane & 7) ^ subrow) * 8;

    #define STAGE_OUT(K0, BUF)                                                       \
        do {                                                                          \
            _Pragma("unroll")                                                         \
            for (int j = 0; j < 4; ++j) {                                             \
                const int rw = wave * 32 + j * 8;                                     \
                gload_lds16(Ah + (size_t)(m0 + rw + subrow) * 512 + (K0) + schunk,    \
                            &sAh[BUF][rw * 64]);                                      \
                gload_lds16(Al + (size_t)(m0 + rw + subrow) * 512 + (K0) + schunk,    \
                            &sAl[BUF][rw * 64]);                                      \
            }                                                                         \
            _Pragma("unroll")                                                         \
            for (int j = 0; j < 2; ++j) {                                             \
                const int rw = wave * 16 + j * 8;                                     \
                gload_lds16(Wh + (size_t)(n0 + rw + subrow) * 512 + (K0) + schunk,    \
                            &sWh[BUF][rw * 64]);                                      \
            }                                                                         \
        } while (0)

    f32x4 acc_h[4][2] = {};
    f32x4 acc_x[4][2] = {};

    STAGE_OUT(0, 0);
    for (int ck = 0; ck < 8; ++ck) {
        const int cur = ck & 1;
        __syncthreads();
        if (ck + 1 < 8) STAGE_OUT((ck + 1) * 64, cur ^ 1);

        #pragma unroll
        for (int kc = 0; kc < 2; ++kc) {
            const int pos = ((kc * 4 + quad) ^ (col & 7)) * 8;
            half8 ahf[4], alf[4], whf[2];
            #pragma unroll
            for (int mt = 0; mt < 4; ++mt) {
                ahf[mt] = *(const half8*)&sAh[cur][(wm + mt * 16 + col) * 64 + pos];
                alf[mt] = *(const half8*)&sAl[cur][(wm + mt * 16 + col) * 64 + pos];
            }
            #pragma unroll
            for (int nt = 0; nt < 2; ++nt)
                whf[nt] = *(const half8*)&sWh[cur][(wn + nt * 16 + col) * 64 + pos];
            #pragma unroll
            for (int mt = 0; mt < 4; ++mt)
                #pragma unroll
                for (int nt = 0; nt < 2; ++nt) {
                    acc_h[mt][nt] = MFMA16(ahf[mt], whf[nt], acc_h[mt][nt]);
                    acc_x[mt][nt] = MFMA16(alf[mt], whf[nt], acc_x[mt][nt]);
                }
        }
    }

    float bv2[2];
    #pragma unroll
    for (int nt = 0; nt < 2; ++nt) bv2[nt] = bias[n0 + wn + nt * 16 + col];

    #pragma unroll
    for (int mt = 0; mt < 4; ++mt) {
        const int m = m0 + wm + mt * 16 + quad * 4;
        #pragma unroll
        for (int nt = 0; nt < 2; ++nt) {
            const int n = n0 + wn + nt * 16 + col;
            #pragma unroll
            for (int r = 0; r < 4; ++r)
                C[(size_t)(m + r) * 512 + n] =
                    acc_h[mt][nt][r] + acc_x[mt][nt][r] * INV_SPLIT + bv2[nt];
        }
    }
}

// ============================================================================
extern "C" void kernel_launch(void* const* d_in, const int* in_sizes, int n_in,
                              void* d_out, int out_size, void* d_ws, size_t ws_size,
                              hipStream_t stream) {
    const float* query = (const float*)d_in[0];
    const float* key   = (const float*)d_in[1];
    const float* value = (const float*)d_in[2];
    const float* w_q   = (const float*)d_in[3];
    const float* b_q   = (const float*)d_in[4];
    const float* w_k   = (const float*)d_in[5];
    const float* b_k   = (const float*)d_in[6];
    const float* w_v   = (const float*)d_in[7];
    const float* b_v   = (const float*)d_in[8];
    const float* w_o   = (const float*)d_in[9];
    const float* b_o   = (const float*)d_in[10];
    float* out = (float*)d_out;

    const int WN = D_MODEL * D_MODEL;                     // 262144
    const size_t plane = (size_t)BATCH * SEQ * D_MODEL;   // 4.19M halves

    _Float16* base = (_Float16*)d_ws;
    _Float16* Aq16 = base;                 // activations fp16 (later reused: Oh)
    _Float16* Ak16 = Aq16 + plane;         // (later reused: Ol)
    _Float16* Av16 = Ak16 + plane;
    _Float16* whq  = Av16 + plane;
    _Float16* whk  = whq + WN;
    _Float16* whv  = whk + WN;
    _Float16* who  = whv + WN;
    _Float16* wlo  = who + WN;
    _Float16* Qf   = wlo + WN;
    _Float16* Kf   = Qf + plane;
    _Float16* Vtf  = Kf + plane;           // total ws: ~53 MB
    _Float16* Oh   = Aq16;                 // alias: activations dead after gemm_qkv
    _Float16* Ol   = Ak16;

    dim3 blk(256);

    hipLaunchKernelGGL(prep, dim3(3 * ABLK + 4 * WBLK), blk, 0, stream,
                       query, key, value, w_q, w_k, w_v, w_o,
                       Aq16, Ak16, Av16, whq, whk, whv, who, wlo);

    hipLaunchKernelGGL(gemm_qkv, dim3(D_MODEL / 128, BATCH * SEQ / 128, 3), blk, 0, stream,
                       Aq16, Ak16, Av16,
                       whq, whk, whv,
                       b_q, b_k, b_v, Qf, Kf, Vtf);

    hipLaunchKernelGGL(attn_mfma, dim3(SEQ / 128, NHEADS, BATCH), blk, 0, stream,
                       Qf, Kf, Vtf, Oh, Ol);

    hipLaunchKernelGGL(gemm_out, dim3(D_MODEL / 64, BATCH * SEQ / 128), blk, 0, stream,
                       Oh, Ol, who, b_o, out);
}

// Round 12
// 275.294 us; speedup vs baseline: 1.9962x; 1.0830x over previous
//
#include <hip/hip_runtime.h>
#include <math.h>

#define D_MODEL 512
#define NHEADS 8
#define DK 64
#define BATCH 2
#define SEQ 4096
#define NIT 32          // 2048 keys per split / 64-key tiles
// log2(e)/8 folded into Q projection: scores in log2 domain, softmax uses exp2.
#define ATTN_SCALE 0.18033688011112043f
#define SPLIT_SCALE 2048.0f
#define INV_SPLIT  (1.0f/2048.0f)

typedef _Float16 half8 __attribute__((ext_vector_type(8)));
typedef __fp16 pkhalf2 __attribute__((ext_vector_type(2)));
typedef float f32x4 __attribute__((ext_vector_type(4)));

union Pk8 { _Float16 h[8]; uint4 u; };
union Pk4 { _Float16 h[4]; uint2 u; };
union Pkz { pkhalf2 h2[2]; uint2 u; };
union Un4 { uint2 u; _Float16 h[4]; };

#if __has_builtin(__builtin_amdgcn_exp2f)
#define EXP2F __builtin_amdgcn_exp2f
#else
#define EXP2F exp2f
#endif

#define MFMA16(a, b, c) __builtin_amdgcn_mfma_f32_16x16x32_f16((a), (b), (c), 0, 0, 0)

__device__ __forceinline__ void gload_lds16(const _Float16* g, _Float16* l) {
    __builtin_amdgcn_global_load_lds(
        (const __attribute__((address_space(1))) void*)g,
        (__attribute__((address_space(3))) void*)l, 16, 0, 0);
}

// ============================================================================
// prep: fp32->fp16 for 3 activations + 4 weight hi-planes (+ lo for w_o).
// ============================================================================
#define ABLK 4096
#define WBLK 256
__global__ __launch_bounds__(256)
void prep(const float* __restrict__ aq, const float* __restrict__ ak,
          const float* __restrict__ av,
          const float* __restrict__ wq, const float* __restrict__ wk,
          const float* __restrict__ wv, const float* __restrict__ wo,
          _Float16* __restrict__ dq, _Float16* __restrict__ dk,
          _Float16* __restrict__ dv,
          _Float16* __restrict__ hq, _Float16* __restrict__ hk,
          _Float16* __restrict__ hv, _Float16* __restrict__ ho,
          _Float16* __restrict__ lo) {
    int gid = blockIdx.x;
    const float* src;
    _Float16 *hi, *lw = nullptr;
    if (gid < 3 * ABLK) {
        const int w = gid / ABLK;
        gid -= w * ABLK;
        src = w == 0 ? aq : (w == 1 ? ak : av);
        hi  = w == 0 ? dq : (w == 1 ? dk : dv);
    } else {
        int g = gid - 3 * ABLK;
        const int w = g / WBLK;
        gid = g - w * WBLK;
        src = w == 0 ? wq : (w == 1 ? wk : (w == 2 ? wv : wo));
        hi  = w == 0 ? hq : (w == 1 ? hk : (w == 2 ? hv : ho));
        if (w == 3) lw = lo;
    }
    const int i = (gid * 256 + threadIdx.x) * 4;
    float4 v = *(const float4*)(src + i);
    Pk4 h;
    h.h[0] = (_Float16)v.x; h.h[1] = (_Float16)v.y;
    h.h[2] = (_Float16)v.z; h.h[3] = (_Float16)v.w;
    *(uint2*)(hi + i) = h.u;
    if (lw) {
        Pk4 l;
        l.h[0] = (_Float16)((v.x - (float)h.h[0]) * SPLIT_SCALE);
        l.h[1] = (_Float16)((v.y - (float)h.h[1]) * SPLIT_SCALE);
        l.h[2] = (_Float16)((v.z - (float)h.h[2]) * SPLIT_SCALE);
        l.h[3] = (_Float16)((v.w - (float)h.h[3]) * SPLIT_SCALE);
        *(uint2*)(lw + i) = l.u;
    }
}

// ============================================================================
// QKV projection GEMM (unchanged r11): double-buffered DMA, 128x128, BK=64.
// ============================================================================
__global__ __launch_bounds__(256)
void gemm_qkv(const _Float16* __restrict__ Aq, const _Float16* __restrict__ Ak,
              const _Float16* __restrict__ Av,
              const _Float16* __restrict__ Whq, const _Float16* __restrict__ Whk,
              const _Float16* __restrict__ Whv,
              const float* __restrict__ bq, const float* __restrict__ bk,
              const float* __restrict__ bv,
              _Float16* __restrict__ Qf, _Float16* __restrict__ Kf,
              _Float16* __restrict__ Vtf) {
    const int z = blockIdx.z;
    const _Float16* A    = z == 0 ? Aq  : (z == 1 ? Ak  : Av);
    const _Float16* Wh   = z == 0 ? Whq : (z == 1 ? Whk : Whv);
    const float*    bias = z == 0 ? bq  : (z == 1 ? bk  : bv);

    __shared__ __align__(16) _Float16 sA[2][128 * 64];
    __shared__ __align__(16) _Float16 sW[2][128 * 64];

    const int t    = threadIdx.x;
    const int lane = t & 63, wave = t >> 6;
    const int col  = lane & 15, quad = lane >> 4;
    const int wm   = (wave & 1) * 64, wn = (wave >> 1) * 64;
    const int m0   = blockIdx.y * 128, n0 = blockIdx.x * 128;

    const int subrow = lane >> 3;
    const int schunk = ((lane & 7) ^ subrow) * 8;

    #define STAGE_AW(K0, BUF)                                                        \
        do {                                                                          \
            _Pragma("unroll")                                                         \
            for (int j = 0; j < 4; ++j) {                                             \
                const int rw = wave * 32 + j * 8;                                     \
                gload_lds16(A  + (size_t)(m0 + rw + subrow) * 512 + (K0) + schunk,    \
                            &sA[BUF][rw * 64]);                                       \
                gload_lds16(Wh + (size_t)(n0 + rw + subrow) * 512 + (K0) + schunk,    \
                            &sW[BUF][rw * 64]);                                       \
            }                                                                         \
        } while (0)

    f32x4 acc[4][4] = {};

    STAGE_AW(0, 0);
    for (int ck = 0; ck < 8; ++ck) {
        const int cur = ck & 1;
        __syncthreads();
        if (ck + 1 < 8) STAGE_AW((ck + 1) * 64, cur ^ 1);

        #pragma unroll
        for (int kc = 0; kc < 2; ++kc) {
            const int pos = ((kc * 4 + quad) ^ (col & 7)) * 8;
            half8 af[4], wf[4];
            #pragma unroll
            for (int mt = 0; mt < 4; ++mt)
                af[mt] = *(const half8*)&sA[cur][(wm + mt * 16 + col) * 64 + pos];
            #pragma unroll
            for (int nt = 0; nt < 4; ++nt)
                wf[nt] = *(const half8*)&sW[cur][(wn + nt * 16 + col) * 64 + pos];
            #pragma unroll
            for (int mt = 0; mt < 4; ++mt)
                #pragma unroll
                for (int nt = 0; nt < 4; ++nt)
                    acc[mt][nt] = MFMA16(af[mt], wf[nt], acc[mt][nt]);
        }
    }

    float bv4[4];
    #pragma unroll
    for (int nt = 0; nt < 4; ++nt) bv4[nt] = bias[n0 + wn + nt * 16 + col];

    if (z < 2) {
        _Float16* Out = z == 0 ? Qf : Kf;
        const float alpha = z == 0 ? ATTN_SCALE : 1.0f;
        #pragma unroll
        for (int mt = 0; mt < 4; ++mt) {
            const int m = m0 + wm + mt * 16 + quad * 4;
            #pragma unroll
            for (int nt = 0; nt < 4; ++nt) {
                const int n = n0 + wn + nt * 16 + col;
                #pragma unroll
                for (int r = 0; r < 4; ++r)
                    Out[(size_t)(m + r) * 512 + n] = (_Float16)((acc[mt][nt][r] + bv4[nt]) * alpha);
            }
        }
    } else {
        #pragma unroll
        for (int mt = 0; mt < 4; ++mt) {
            const int m = m0 + wm + mt * 16 + quad * 4;
            const int b = m >> 12, s = m & (SEQ - 1);
            #pragma unroll
            for (int nt = 0; nt < 4; ++nt) {
                const int n = n0 + wn + nt * 16 + col;
                const int hh = n >> 6, d = n & (DK - 1);
                Pk4 p;
                #pragma unroll
                for (int r = 0; r < 4; ++r)
                    p.h[r] = (_Float16)(acc[mt][nt][r] + bv4[nt]);
                *(uint2*)&Vtf[((size_t)((b * NHEADS + hh) * DK + d)) * SEQ + s] = p.u;
            }
        }
    }
}

// ============================================================================
// Flash attention, K-SPLIT x2: blockIdx.z = b*2+split; each block does 2048
// keys (32 iters) over 128 queries (32/wave). Outputs per-split normalized O
// (fp16) + per-query (m, l) for the flash-combine merge kernel.
// LDS 40 KB (sK 16 dbuf + sV 16 dbuf + sP 8) -> 4 blocks/CU, 16 waves/CU.
// P processed per-nt through a 16-row/wave sP (V-frags re-read per nt — the
// price of the 8 KB sP). Loop 2-unrolled so `cur` is compile-time: all LDS
// addresses loop-invariant. exp2 via raw v_exp_f32; packing via cvt_pkrtz.
// ============================================================================
__global__ __launch_bounds__(256)
void attn_mfma(const _Float16* __restrict__ Qf, const _Float16* __restrict__ Kf,
               const _Float16* __restrict__ Vtf,
               _Float16* __restrict__ Op0, _Float16* __restrict__ Op1,
               float2* __restrict__ Ml) {
    __shared__ __align__(16) _Float16 sK[2][64 * 64];
    __shared__ __align__(16) _Float16 sV[2][64 * 64];
    __shared__ __align__(16) _Float16 sP[64 * 64];   // 16 rows per wave

    const int t    = threadIdx.x;
    const int lane = t & 63;
    const int wave = t >> 6;
    const int col  = lane & 15;
    const int quad = lane >> 4;

    const int q0 = blockIdx.x * 128;
    const int h  = blockIdx.y;
    const int b  = blockIdx.z >> 1;
    const int sp = blockIdx.z & 1;
    const int kBase = sp * (SEQ / 2);

    const size_t rowBase = (size_t)b * SEQ;
    const size_t vBase   = ((size_t)(b * NHEADS + h)) * DK * SEQ;

    // ---- stage Q tile (128x64) through the sK region (16 KB), read frags ----
    {
        _Float16* sQ = &sK[0][0];
        uint4 qv[4];
        #pragma unroll
        for (int i2 = 0; i2 < 4; ++i2) {
            const int slot = t + i2 * 256;
            const int r = slot >> 3, sl = slot & 7;
            qv[i2] = *(const uint4*)(Qf + (rowBase + q0 + r) * 512 + h * 64 + sl * 8);
        }
        #pragma unroll
        for (int i2 = 0; i2 < 4; ++i2) {
            const int slot = t + i2 * 256;
            const int r = slot >> 3, sl = slot & 7;
            *(uint4*)&sQ[r * 64 + (sl ^ (r & 7)) * 8] = qv[i2];
        }
    }
    __syncthreads();

    half8 qf[2][2];
    {
        const _Float16* sQ = &sK[0][0];
        #pragma unroll
        for (int nt = 0; nt < 2; ++nt)
            #pragma unroll
            for (int kc = 0; kc < 2; ++kc)
                qf[nt][kc] = *(const half8*)&sQ[(wave * 32 + nt * 16 + col) * 64 +
                                                ((kc * 4 + quad) ^ (col & 7)) * 8];
    }
    __syncthreads();   // all waves read their Q frags before DMA overwrites sK

    // ---- DMA pointers (advance by one 64-key tile per stage) ----
    const int subrow = lane >> 3;
    const int schunk = ((lane & 7) ^ subrow) * 8;
    const _Float16* kP[2];
    const _Float16* vP[2];
    #pragma unroll
    for (int j = 0; j < 2; ++j) {
        const int rw = wave * 16 + j * 8;
        kP[j] = Kf + (rowBase + kBase + rw + subrow) * 512 + h * 64 + schunk;
        vP[j] = Vtf + vBase + (size_t)(rw + subrow) * SEQ + kBase + schunk;
    }
    // issue tile 0
    #pragma unroll
    for (int j = 0; j < 2; ++j) {
        const int rw = wave * 16 + j * 8;
        gload_lds16(kP[j], &sK[0][rw * 64]);
        gload_lds16(vP[j], &sV[0][rw * 64]);
        kP[j] += 64 * 512;
        vP[j] += 64;
    }

    _Float16* Ps = sP + wave * 16 * 64;
    const int pmsk = (col & 7) << 1;

    float m_r[2] = { -INFINITY, -INFINITY };
    float l_r[2] = { 0.0f, 0.0f };
    f32x4 of[4][2] = {};

    for (int itp = 0; itp < NIT; itp += 2) {
        #pragma unroll
        for (int cur = 0; cur < 2; ++cur) {     // compile-time cur
            const int it = itp + cur;
            __syncthreads();   // drains prefetch DMA; alt buffer free
            if (it + 1 < NIT) {
                #pragma unroll
                for (int j = 0; j < 2; ++j) {
                    const int rw = wave * 16 + j * 8;
                    gload_lds16(kP[j], &sK[cur ^ 1][rw * 64]);
                    gload_lds16(vP[j], &sV[cur ^ 1][rw * 64]);
                    kP[j] += 64 * 512;
                    vP[j] += 64;
                }
            }

            // ---- S^T = K · Q^T : 16 MFMA ----
            f32x4 sf[4][2] = {};
            #pragma unroll
            for (int kc = 0; kc < 2; ++kc) {
                const int pos = ((kc * 4 + quad) ^ (col & 7)) * 8;
                #pragma unroll
                for (int kt = 0; kt < 4; ++kt) {
                    half8 kf = *(const half8*)&sK[cur][(kt * 16 + col) * 64 + pos];
                    #pragma unroll
                    for (int nt = 0; nt < 2; ++nt)
                        sf[kt][nt] = MFMA16(kf, qf[nt][kc], sf[kt][nt]);
                }
            }

            if (it == 0) {      // eager scale for this split
                #pragma unroll
                for (int nt = 0; nt < 2; ++nt) {
                    float mx = sf[0][nt][0];
                    #pragma unroll
                    for (int kt = 0; kt < 4; ++kt)
                        #pragma unroll
                        for (int r = 0; r < 4; ++r)
                            mx = fmaxf(mx, sf[kt][nt][r]);
                    mx = fmaxf(mx, __shfl_xor(mx, 16));
                    mx = fmaxf(mx, __shfl_xor(mx, 32));
                    m_r[nt] = mx;
                }
            }

            // ---- per-nt: exp2 -> P(16 rows) -> PV (V re-read per nt) ----
            float lrs[2];
            #pragma unroll
            for (int nt = 0; nt < 2; ++nt) {
                float ls = 0.0f;
                #pragma unroll
                for (int kt = 0; kt < 4; ++kt) {
                    const float p0 = EXP2F(sf[kt][nt][0] - m_r[nt]);
                    const float p1 = EXP2F(sf[kt][nt][1] - m_r[nt]);
                    const float p2 = EXP2F(sf[kt][nt][2] - m_r[nt]);
                    const float p3 = EXP2F(sf[kt][nt][3] - m_r[nt]);
                    ls += (p0 + p1) + (p2 + p3);
                    Pkz z;
                    z.h2[0] = __builtin_amdgcn_cvt_pkrtz(p0, p1);
                    z.h2[1] = __builtin_amdgcn_cvt_pkrtz(p2, p3);
                    *(uint2*)&Ps[col * 64 + ((kt * 4 + quad) ^ pmsk) * 4] = z.u;
                }
                lrs[nt] = ls;
                #pragma unroll
                for (int kc = 0; kc < 2; ++kc) {
                    half8 pf = *(const half8*)&Ps[col * 64 + ((kc * 8 + quad * 2) ^ pmsk) * 4];
                    const int pos = ((kc * 4 + quad) ^ (col & 7)) * 8;
                    #pragma unroll
                    for (int dt = 0; dt < 4; ++dt) {
                        half8 vf = *(const half8*)&sV[cur][(dt * 16 + col) * 64 + pos];
                        of[dt][nt] = MFMA16(vf, pf, of[dt][nt]);
                    }
                }
            }

            l_r[0] += lrs[0];
            l_r[1] += lrs[1];

            // ---- rare re-center ----
            if (__any(fmaxf(lrs[0], lrs[1]) > 1024.0f)) {
                #pragma unroll
                for (int nt = 0; nt < 2; ++nt) {
                    float mx = sf[0][nt][0];
                    #pragma unroll
                    for (int kt = 0; kt < 4; ++kt)
                        #pragma unroll
                        for (int r = 0; r < 4; ++r)
                            mx = fmaxf(mx, sf[kt][nt][r]);
                    mx = fmaxf(mx, __shfl_xor(mx, 16));
                    mx = fmaxf(mx, __shfl_xor(mx, 32));
                    if (mx > m_r[nt]) {
                        const float al = EXP2F(m_r[nt] - mx);
                        l_r[nt] *= al;
                        #pragma unroll
                        for (int dt = 0; dt < 4; ++dt)
                            #pragma unroll
                            for (int r = 0; r < 4; ++r)
                                of[dt][nt][r] *= al;
                        m_r[nt] = mx;
                    }
                }
            }
        }
    }

    // ---- finalize: per-split normalized O (fp16) + (m, l) ----
    _Float16* Opx = sp ? Op1 : Op0;
    #pragma unroll
    for (int nt = 0; nt < 2; ++nt) {
        float l = l_r[nt];
        l += __shfl_xor(l, 16);
        l += __shfl_xor(l, 32);
        const float inv = 1.0f / l;
        const int q = q0 + wave * 32 + nt * 16 + col;
        const size_t R = (size_t)b * SEQ + q;
        #pragma unroll
        for (int dt = 0; dt < 4; ++dt) {
            Pkz z;
            z.h2[0] = __builtin_amdgcn_cvt_pkrtz(of[dt][nt][0] * inv, of[dt][nt][1] * inv);
            z.h2[1] = __builtin_amdgcn_cvt_pkrtz(of[dt][nt][2] * inv, of[dt][nt][3] * inv);
            *(uint2*)(Opx + R * 512 + h * 64 + dt * 16 + quad * 4) = z.u;
        }
        if (quad == 0)
            Ml[(size_t)(sp * BATCH * SEQ) * NHEADS + R * NHEADS + h] = make_float2(m_r[nt], l);
    }
}

// ============================================================================
// attn_merge: flash-combine of the two K-split partials -> Oh/Ol (hi+lo fp16).
// One float4-of-dims per thread; 8192*512/4 = 1,048,576 threads -> 4096 blocks.
// ============================================================================
__global__ __launch_bounds__(256)
void attn_merge(const _Float16* __restrict__ Op0, const _Float16* __restrict__ Op1,
                const float2* __restrict__ Ml,
                _Float16* __restrict__ Oh, _Float16* __restrict__ Ol) {
    const int i4 = (blockIdx.x * 256 + threadIdx.x) * 4;
    const int R = i4 >> 9;
    const int c = i4 & 511;
    const int h = c >> 6;

    const float2 ml1 = Ml[(size_t)R * NHEADS + h];
    const float2 ml2 = Ml[(size_t)(BATCH * SEQ) * NHEADS + (size_t)R * NHEADS + h];
    const float m = fmaxf(ml1.x, ml2.x);
    float w1 = EXP2F(ml1.x - m) * ml1.y;
    float w2 = EXP2F(ml2.x - m) * ml2.y;
    const float inv = 1.0f / (w1 + w2);
    w1 *= inv; w2 *= inv;

    Un4 a, bb;
    a.u  = *(const uint2*)(Op0 + (size_t)R * 512 + c);
    bb.u = *(const uint2*)(Op1 + (size_t)R * 512 + c);

    Pk4 hh, ll;
    #pragma unroll
    for (int r = 0; r < 4; ++r) {
        const float v = w1 * (float)a.h[r] + w2 * (float)bb.h[r];
        hh.h[r] = (_Float16)v;
        ll.h[r] = (_Float16)((v - (float)hh.h[r]) * SPLIT_SCALE);
    }
    *(uint2*)(Oh + (size_t)R * 512 + c) = hh.u;
    *(uint2*)(Ol + (size_t)R * 512 + c) = ll.u;
}

// ============================================================================
// Output projection (unchanged r11): double-buffered DMA, A hi+lo, W hi-only.
// ============================================================================
__global__ __launch_bounds__(256)
void gemm_out(const _Float16* __restrict__ Ah, const _Float16* __restrict__ Al,
              const _Float16* __restrict__ Wh,
              const float* __restrict__ bias, float* __restrict__ C) {
    __shared__ __align__(16) _Float16 sAh[2][128 * 64];
    __shared__ __align__(16) _Float16 sAl[2][128 * 64];
    __shared__ __align__(16) _Float16 sWh[2][64 * 64];

    const int t    = threadIdx.x;
    const int lane = t & 63, wave = t >> 6;
    const int col  = lane & 15, quad = lane >> 4;
    const int wm   = (wave & 1) * 64, wn = (wave >> 1) * 32;
    const int m0   = blockIdx.y * 128, n0 = blockIdx.x * 64;

    const int subrow = lane >> 3;
    const int schunk = ((lane & 7) ^ subrow) * 8;

    #define STAGE_OUT(K0, BUF)                                                       \
        do {                                                                          \
            _Pragma("unroll")                                                         \
            for (int j = 0; j < 4; ++j) {                                             \
                const int rw = wave * 32 + j * 8;                                     \
                gload_lds16(Ah + (size_t)(m0 + rw + subrow) * 512 + (K0) + schunk,    \
                            &sAh[BUF][rw * 64]);                                      \
                gload_lds16(Al + (size_t)(m0 + rw + subrow) * 512 + (K0) + schunk,    \
                            &sAl[BUF][rw * 64]);                                      \
            }                                                                         \
            _Pragma("unroll")                                                         \
            for (int j = 0; j < 2; ++j) {                                             \
                const int rw = wave * 16 + j * 8;                                     \
                gload_lds16(Wh + (size_t)(n0 + rw + subrow) * 512 + (K0) + schunk,    \
                            &sWh[BUF][rw * 64]);                                      \
            }                                                                         \
        } while (0)

    f32x4 acc_h[4][2] = {};
    f32x4 acc_x[4][2] = {};

    STAGE_OUT(0, 0);
    for (int ck = 0; ck < 8; ++ck) {
        const int cur = ck & 1;
        __syncthreads();
        if (ck + 1 < 8) STAGE_OUT((ck + 1) * 64, cur ^ 1);

        #pragma unroll
        for (int kc = 0; kc < 2; ++kc) {
            const int pos = ((kc * 4 + quad) ^ (col & 7)) * 8;
            half8 ahf[4], alf[4], whf[2];
            #pragma unroll
            for (int mt = 0; mt < 4; ++mt) {
                ahf[mt] = *(const half8*)&sAh[cur][(wm + mt * 16 + col) * 64 + pos];
                alf[mt] = *(const half8*)&sAl[cur][(wm + mt * 16 + col) * 64 + pos];
            }
            #pragma unroll
            for (int nt = 0; nt < 2; ++nt)
                whf[nt] = *(const half8*)&sWh[cur][(wn + nt * 16 + col) * 64 + pos];
            #pragma unroll
            for (int mt = 0; mt < 4; ++mt)
                #pragma unroll
                for (int nt = 0; nt < 2; ++nt) {
                    acc_h[mt][nt] = MFMA16(ahf[mt], whf[nt], acc_h[mt][nt]);
                    acc_x[mt][nt] = MFMA16(alf[mt], whf[nt], acc_x[mt][nt]);
                }
        }
    }

    float bv2[2];
    #pragma unroll
    for (int nt = 0; nt < 2; ++nt) bv2[nt] = bias[n0 + wn + nt * 16 + col];

    #pragma unroll
    for (int mt = 0; mt < 4; ++mt) {
        const int m = m0 + wm + mt * 16 + quad * 4;
        #pragma unroll
        for (int nt = 0; nt < 2; ++nt) {
            const int n = n0 + wn + nt * 16 + col;
            #pragma unroll
            for (int r = 0; r < 4; ++r)
                C[(size_t)(m + r) * 512 + n] =
                    acc_h[mt][nt][r] + acc_x[mt][nt][r] * INV_SPLIT + bv2[nt];
        }
    }
}

// ============================================================================
extern "C" void kernel_launch(void* const* d_in, const int* in_sizes, int n_in,
                              void* d_out, int out_size, void* d_ws, size_t ws_size,
                              hipStream_t stream) {
    const float* query = (const float*)d_in[0];
    const float* key   = (const float*)d_in[1];
    const float* value = (const float*)d_in[2];
    const float* w_q   = (const float*)d_in[3];
    const float* b_q   = (const float*)d_in[4];
    const float* w_k   = (const float*)d_in[5];
    const float* b_k   = (const float*)d_in[6];
    const float* w_v   = (const float*)d_in[7];
    const float* b_v   = (const float*)d_in[8];
    const float* w_o   = (const float*)d_in[9];
    const float* b_o   = (const float*)d_in[10];
    float* out = (float*)d_out;

    const int WN = D_MODEL * D_MODEL;                     // 262144
    const size_t plane = (size_t)BATCH * SEQ * D_MODEL;   // 4.19M halves

    _Float16* base = (_Float16*)d_ws;
    _Float16* Aq16 = base;                 // -> Oh after qkv
    _Float16* Ak16 = Aq16 + plane;         // -> Ol after qkv
    _Float16* Av16 = Ak16 + plane;         // -> Op0 after qkv
    _Float16* whq  = Av16 + plane;
    _Float16* whk  = whq + WN;
    _Float16* whv  = whk + WN;
    _Float16* who  = whv + WN;
    _Float16* wlo  = who + WN;             // unused by gemm_out now, kept by prep
    _Float16* Qf   = wlo + WN;
    _Float16* Kf   = Qf + plane;
    _Float16* Vtf  = Kf + plane;
    _Float16* Op1  = Vtf + plane;
    float2*   Ml   = (float2*)(Op1 + plane);  // 2*BATCH*SEQ*NHEADS float2 = 1 MB
    _Float16* Oh   = Aq16;
    _Float16* Ol   = Ak16;
    _Float16* Op0  = Av16;

    dim3 blk(256);

    hipLaunchKernelGGL(prep, dim3(3 * ABLK + 4 * WBLK), blk, 0, stream,
                       query, key, value, w_q, w_k, w_v, w_o,
                       Aq16, Ak16, Av16, whq, whk, whv, who, wlo);

    hipLaunchKernelGGL(gemm_qkv, dim3(D_MODEL / 128, BATCH * SEQ / 128, 3), blk, 0, stream,
                       Aq16, Ak16, Av16,
                       whq, whk, whv,
                       b_q, b_k, b_v, Qf, Kf, Vtf);

    hipLaunchKernelGGL(attn_mfma, dim3(SEQ / 128, NHEADS, BATCH * 2), blk, 0, stream,
                       Qf, Kf, Vtf, Op0, Op1, Ml);

    hipLaunchKernelGGL(attn_merge, dim3(BATCH * SEQ * D_MODEL / 4 / 256), blk, 0, stream,
                       Op0, Op1, Ml, Oh, Ol);

    hipLaunchKernelGGL(gemm_out, dim3(D_MODEL / 64, BATCH * SEQ / 128), blk, 0, stream,
                       Oh, Ol, who, b_o, out);
}

// Round 13
// 264.813 us; speedup vs baseline: 2.0752x; 1.0396x over previous
//
#include <hip/hip_runtime.h>
#include <math.h>

#define D_MODEL 512
#define NHEADS 8
#define DK 64
#define BATCH 2
#define SEQ 4096
#define NIT 32          // 2048 keys per split / 64-key tiles
// log2(e)/8 folded into Q projection: scores in log2 domain, softmax uses exp2.
#define ATTN_SCALE 0.18033688011112043f
#define SPLIT_SCALE 2048.0f
#define INV_SPLIT  (1.0f/2048.0f)

typedef _Float16 half8 __attribute__((ext_vector_type(8)));
typedef __fp16 pkhalf2 __attribute__((ext_vector_type(2)));
typedef float f32x4 __attribute__((ext_vector_type(4)));

union Pk8 { _Float16 h[8]; uint4 u; };
union Pk4 { _Float16 h[4]; uint2 u; };
union Pkz { pkhalf2 h2[2]; uint2 u; };
union Un4 { uint2 u; _Float16 h[4]; };

#if __has_builtin(__builtin_amdgcn_exp2f)
#define EXP2F __builtin_amdgcn_exp2f
#else
#define EXP2F exp2f
#endif

#define MFMA16(a, b, c) __builtin_amdgcn_mfma_f32_16x16x32_f16((a), (b), (c), 0, 0, 0)

__device__ __forceinline__ void gload_lds16(const _Float16* g, _Float16* l) {
    __builtin_amdgcn_global_load_lds(
        (const __attribute__((address_space(1))) void*)g,
        (__attribute__((address_space(3))) void*)l, 16, 0, 0);
}

// ============================================================================
// prep: fp32->fp16 for 3 activations + 4 weight hi-planes (lo plane no longer
// needed anywhere — dropped entirely).
// ============================================================================
#define ABLK 4096
#define WBLK 256
__global__ __launch_bounds__(256)
void prep(const float* __restrict__ aq, const float* __restrict__ ak,
          const float* __restrict__ av,
          const float* __restrict__ wq, const float* __restrict__ wk,
          const float* __restrict__ wv, const float* __restrict__ wo,
          _Float16* __restrict__ dq, _Float16* __restrict__ dk,
          _Float16* __restrict__ dv,
          _Float16* __restrict__ hq, _Float16* __restrict__ hk,
          _Float16* __restrict__ hv, _Float16* __restrict__ ho) {
    int gid = blockIdx.x;
    const float* src;
    _Float16* hi;
    if (gid < 3 * ABLK) {
        const int w = gid / ABLK;
        gid -= w * ABLK;
        src = w == 0 ? aq : (w == 1 ? ak : av);
        hi  = w == 0 ? dq : (w == 1 ? dk : dv);
    } else {
        int g = gid - 3 * ABLK;
        const int w = g / WBLK;
        gid = g - w * WBLK;
        src = w == 0 ? wq : (w == 1 ? wk : (w == 2 ? wv : wo));
        hi  = w == 0 ? hq : (w == 1 ? hk : (w == 2 ? hv : ho));
    }
    const int i = (gid * 256 + threadIdx.x) * 4;
    float4 v = *(const float4*)(src + i);
    Pkz h;
    h.h2[0] = __builtin_amdgcn_cvt_pkrtz(v.x, v.y);
    h.h2[1] = __builtin_amdgcn_cvt_pkrtz(v.z, v.w);
    *(uint2*)(hi + i) = h.u;
}

// ============================================================================
// QKV projection GEMM (unchanged r12): double-buffered DMA, 128x128, BK=64.
// ============================================================================
__global__ __launch_bounds__(256)
void gemm_qkv(const _Float16* __restrict__ Aq, const _Float16* __restrict__ Ak,
              const _Float16* __restrict__ Av,
              const _Float16* __restrict__ Whq, const _Float16* __restrict__ Whk,
              const _Float16* __restrict__ Whv,
              const float* __restrict__ bq, const float* __restrict__ bk,
              const float* __restrict__ bv,
              _Float16* __restrict__ Qf, _Float16* __restrict__ Kf,
              _Float16* __restrict__ Vtf) {
    const int z = blockIdx.z;
    const _Float16* A    = z == 0 ? Aq  : (z == 1 ? Ak  : Av);
    const _Float16* Wh   = z == 0 ? Whq : (z == 1 ? Whk : Whv);
    const float*    bias = z == 0 ? bq  : (z == 1 ? bk  : bv);

    __shared__ __align__(16) _Float16 sA[2][128 * 64];
    __shared__ __align__(16) _Float16 sW[2][128 * 64];

    const int t    = threadIdx.x;
    const int lane = t & 63, wave = t >> 6;
    const int col  = lane & 15, quad = lane >> 4;
    const int wm   = (wave & 1) * 64, wn = (wave >> 1) * 64;
    const int m0   = blockIdx.y * 128, n0 = blockIdx.x * 128;

    const int subrow = lane >> 3;
    const int schunk = ((lane & 7) ^ subrow) * 8;

    #define STAGE_AW(K0, BUF)                                                        \
        do {                                                                          \
            _Pragma("unroll")                                                         \
            for (int j = 0; j < 4; ++j) {                                             \
                const int rw = wave * 32 + j * 8;                                     \
                gload_lds16(A  + (size_t)(m0 + rw + subrow) * 512 + (K0) + schunk,    \
                            &sA[BUF][rw * 64]);                                       \
                gload_lds16(Wh + (size_t)(n0 + rw + subrow) * 512 + (K0) + schunk,    \
                            &sW[BUF][rw * 64]);                                       \
            }                                                                         \
        } while (0)

    f32x4 acc[4][4] = {};

    STAGE_AW(0, 0);
    for (int ck = 0; ck < 8; ++ck) {
        const int cur = ck & 1;
        __syncthreads();
        if (ck + 1 < 8) STAGE_AW((ck + 1) * 64, cur ^ 1);

        #pragma unroll
        for (int kc = 0; kc < 2; ++kc) {
            const int pos = ((kc * 4 + quad) ^ (col & 7)) * 8;
            half8 af[4], wf[4];
            #pragma unroll
            for (int mt = 0; mt < 4; ++mt)
                af[mt] = *(const half8*)&sA[cur][(wm + mt * 16 + col) * 64 + pos];
            #pragma unroll
            for (int nt = 0; nt < 4; ++nt)
                wf[nt] = *(const half8*)&sW[cur][(wn + nt * 16 + col) * 64 + pos];
            #pragma unroll
            for (int mt = 0; mt < 4; ++mt)
                #pragma unroll
                for (int nt = 0; nt < 4; ++nt)
                    acc[mt][nt] = MFMA16(af[mt], wf[nt], acc[mt][nt]);
        }
    }

    float bv4[4];
    #pragma unroll
    for (int nt = 0; nt < 4; ++nt) bv4[nt] = bias[n0 + wn + nt * 16 + col];

    if (z < 2) {
        _Float16* Out = z == 0 ? Qf : Kf;
        const float alpha = z == 0 ? ATTN_SCALE : 1.0f;
        #pragma unroll
        for (int mt = 0; mt < 4; ++mt) {
            const int m = m0 + wm + mt * 16 + quad * 4;
            #pragma unroll
            for (int nt = 0; nt < 4; ++nt) {
                const int n = n0 + wn + nt * 16 + col;
                #pragma unroll
                for (int r = 0; r < 4; ++r)
                    Out[(size_t)(m + r) * 512 + n] = (_Float16)((acc[mt][nt][r] + bv4[nt]) * alpha);
            }
        }
    } else {
        #pragma unroll
        for (int mt = 0; mt < 4; ++mt) {
            const int m = m0 + wm + mt * 16 + quad * 4;
            const int b = m >> 12, s = m & (SEQ - 1);
            #pragma unroll
            for (int nt = 0; nt < 4; ++nt) {
                const int n = n0 + wn + nt * 16 + col;
                const int hh = n >> 6, d = n & (DK - 1);
                Pk4 p;
                #pragma unroll
                for (int r = 0; r < 4; ++r)
                    p.h[r] = (_Float16)(acc[mt][nt][r] + bv4[nt]);
                *(uint2*)&Vtf[((size_t)((b * NHEADS + hh) * DK + d)) * SEQ + s] = p.u;
            }
        }
    }
}

// ============================================================================
// Flash attention, K-split x2 (r12) + shared-V inner loop (r11): sP is a full
// 32-row-per-wave buffer (16 KB) so V-frags are read ONCE per iteration —
// LDS traffic 32 -> 24 b128-equiv/wave-iter (the r12 binding pipe).
// LDS 48 KB (sK 16 dbuf + sV 16 dbuf + sP 16) -> 3 blocks/CU.
// Q stages through sP (it becomes the P buffer); first K/V DMA overlaps it.
// Compile-time `cur` via 2-unroll; exp2 = raw v_exp_f32.
// ============================================================================
__global__ __launch_bounds__(256)
void attn_mfma(const _Float16* __restrict__ Qf, const _Float16* __restrict__ Kf,
               const _Float16* __restrict__ Vtf,
               _Float16* __restrict__ Op0, _Float16* __restrict__ Op1,
               float2* __restrict__ Ml) {
    __shared__ __align__(16) _Float16 sK[2][64 * 64];
    __shared__ __align__(16) _Float16 sV[2][64 * 64];
    __shared__ __align__(16) _Float16 sP[128 * 64];   // Q staging, then 32 rows/wave P

    const int t    = threadIdx.x;
    const int lane = t & 63;
    const int wave = t >> 6;
    const int col  = lane & 15;
    const int quad = lane >> 4;

    const int q0 = blockIdx.x * 128;
    const int h  = blockIdx.y;
    const int b  = blockIdx.z >> 1;
    const int sp = blockIdx.z & 1;
    const int kBase = sp * (SEQ / 2);

    const size_t rowBase = (size_t)b * SEQ;
    const size_t vBase   = ((size_t)(b * NHEADS + h)) * DK * SEQ;

    // ---- DMA pointers; issue K/V tile 0 immediately (overlaps Q staging) ----
    const int subrow = lane >> 3;
    const int schunk = ((lane & 7) ^ subrow) * 8;
    const _Float16* kP[2];
    const _Float16* vP[2];
    #pragma unroll
    for (int j = 0; j < 2; ++j) {
        const int rw = wave * 16 + j * 8;
        kP[j] = Kf + (rowBase + kBase + rw + subrow) * 512 + h * 64 + schunk;
        vP[j] = Vtf + vBase + (size_t)(rw + subrow) * SEQ + kBase + schunk;
        gload_lds16(kP[j], &sK[0][rw * 64]);
        gload_lds16(vP[j], &sV[0][rw * 64]);
        kP[j] += 64 * 512;
        vP[j] += 64;
    }

    // ---- stage Q tile (128x64) into sP with the row XOR swizzle ----
    {
        uint4 qv[4];
        #pragma unroll
        for (int i2 = 0; i2 < 4; ++i2) {
            const int slot = t + i2 * 256;
            const int r = slot >> 3, sl = slot & 7;
            qv[i2] = *(const uint4*)(Qf + (rowBase + q0 + r) * 512 + h * 64 + sl * 8);
        }
        #pragma unroll
        for (int i2 = 0; i2 < 4; ++i2) {
            const int slot = t + i2 * 256;
            const int r = slot >> 3, sl = slot & 7;
            *(uint4*)&sP[r * 64 + (sl ^ (r & 7)) * 8] = qv[i2];
        }
    }
    __syncthreads();

    half8 qf[2][2];
    #pragma unroll
    for (int nt = 0; nt < 2; ++nt)
        #pragma unroll
        for (int kc = 0; kc < 2; ++kc)
            qf[nt][kc] = *(const half8*)&sP[(wave * 32 + nt * 16 + col) * 64 +
                                            ((kc * 4 + quad) ^ (col & 7)) * 8];
    // qf reads touch only this wave's own 32 sP rows; P writes below are to the
    // same region -> intra-wave ordering suffices, no extra barrier needed.

    _Float16* Ps = sP + wave * 32 * 64;
    const int pmsk = (col & 7) << 1;

    float m_r[2] = { -INFINITY, -INFINITY };
    float l_r[2] = { 0.0f, 0.0f };
    f32x4 of[4][2] = {};

    for (int itp = 0; itp < NIT; itp += 2) {
        #pragma unroll
        for (int cur = 0; cur < 2; ++cur) {     // compile-time cur
            const int it = itp + cur;
            __syncthreads();   // drains prefetch DMA; alt buffer free
            if (it + 1 < NIT) {
                #pragma unroll
                for (int j = 0; j < 2; ++j) {
                    const int rw = wave * 16 + j * 8;
                    gload_lds16(kP[j], &sK[cur ^ 1][rw * 64]);
                    gload_lds16(vP[j], &sV[cur ^ 1][rw * 64]);
                    kP[j] += 64 * 512;
                    vP[j] += 64;
                }
            }

            // ---- S^T = K · Q^T : 16 MFMA ----
            f32x4 sf[4][2] = {};
            #pragma unroll
            for (int kc = 0; kc < 2; ++kc) {
                const int pos = ((kc * 4 + quad) ^ (col & 7)) * 8;
                #pragma unroll
                for (int kt = 0; kt < 4; ++kt) {
                    half8 kf = *(const half8*)&sK[cur][(kt * 16 + col) * 64 + pos];
                    #pragma unroll
                    for (int nt = 0; nt < 2; ++nt)
                        sf[kt][nt] = MFMA16(kf, qf[nt][kc], sf[kt][nt]);
                }
            }

            if (it == 0) {      // eager scale for this split
                #pragma unroll
                for (int nt = 0; nt < 2; ++nt) {
                    float mx = sf[0][nt][0];
                    #pragma unroll
                    for (int kt = 0; kt < 4; ++kt)
                        #pragma unroll
                        for (int r = 0; r < 4; ++r)
                            mx = fmaxf(mx, sf[kt][nt][r]);
                    mx = fmaxf(mx, __shfl_xor(mx, 16));
                    mx = fmaxf(mx, __shfl_xor(mx, 32));
                    m_r[nt] = mx;
                }
            }

            // ---- fast path: P = exp2(s - m_r) into 32-row sP ----
            float lrs[2];
            #pragma unroll
            for (int nt = 0; nt < 2; ++nt) {
                float ls = 0.0f;
                #pragma unroll
                for (int kt = 0; kt < 4; ++kt) {
                    const float p0 = EXP2F(sf[kt][nt][0] - m_r[nt]);
                    const float p1 = EXP2F(sf[kt][nt][1] - m_r[nt]);
                    const float p2 = EXP2F(sf[kt][nt][2] - m_r[nt]);
                    const float p3 = EXP2F(sf[kt][nt][3] - m_r[nt]);
                    ls += (p0 + p1) + (p2 + p3);
                    Pkz z;
                    z.h2[0] = __builtin_amdgcn_cvt_pkrtz(p0, p1);
                    z.h2[1] = __builtin_amdgcn_cvt_pkrtz(p2, p3);
                    *(uint2*)&Ps[(nt * 16 + col) * 64 + ((kt * 4 + quad) ^ pmsk) * 4] = z.u;
                }
                lrs[nt] = ls;
            }

            // ---- O^T += V^T · P^T : 16 MFMA, V-frags read ONCE ----
            #pragma unroll
            for (int kc = 0; kc < 2; ++kc) {
                half8 pf[2];
                #pragma unroll
                for (int nt = 0; nt < 2; ++nt)
                    pf[nt] = *(const half8*)&Ps[(nt * 16 + col) * 64 +
                                                ((kc * 8 + quad * 2) ^ pmsk) * 4];
                const int pos = ((kc * 4 + quad) ^ (col & 7)) * 8;
                #pragma unroll
                for (int dt = 0; dt < 4; ++dt) {
                    half8 vf = *(const half8*)&sV[cur][(dt * 16 + col) * 64 + pos];
                    of[dt][0] = MFMA16(vf, pf[0], of[dt][0]);
                    of[dt][1] = MFMA16(vf, pf[1], of[dt][1]);
                }
            }

            l_r[0] += lrs[0];
            l_r[1] += lrs[1];

            // ---- rare re-center ----
            if (__any(fmaxf(lrs[0], lrs[1]) > 1024.0f)) {
                #pragma unroll
                for (int nt = 0; nt < 2; ++nt) {
                    float mx = sf[0][nt][0];
                    #pragma unroll
                    for (int kt = 0; kt < 4; ++kt)
                        #pragma unroll
                        for (int r = 0; r < 4; ++r)
                            mx = fmaxf(mx, sf[kt][nt][r]);
                    mx = fmaxf(mx, __shfl_xor(mx, 16));
                    mx = fmaxf(mx, __shfl_xor(mx, 32));
                    if (mx > m_r[nt]) {
                        const float al = EXP2F(m_r[nt] - mx);
                        l_r[nt] *= al;
                        #pragma unroll
                        for (int dt = 0; dt < 4; ++dt)
                            #pragma unroll
                            for (int r = 0; r < 4; ++r)
                                of[dt][nt][r] *= al;
                        m_r[nt] = mx;
                    }
                }
            }
        }
    }

    // ---- finalize: per-split normalized O (fp16) + (m, l) ----
    _Float16* Opx = sp ? Op1 : Op0;
    #pragma unroll
    for (int nt = 0; nt < 2; ++nt) {
        float l = l_r[nt];
        l += __shfl_xor(l, 16);
        l += __shfl_xor(l, 32);
        const float inv = 1.0f / l;
        const int q = q0 + wave * 32 + nt * 16 + col;
        const size_t R = (size_t)b * SEQ + q;
        #pragma unroll
        for (int dt = 0; dt < 4; ++dt) {
            Pkz z;
            z.h2[0] = __builtin_amdgcn_cvt_pkrtz(of[dt][nt][0] * inv, of[dt][nt][1] * inv);
            z.h2[1] = __builtin_amdgcn_cvt_pkrtz(of[dt][nt][2] * inv, of[dt][nt][3] * inv);
            *(uint2*)(Opx + R * 512 + h * 64 + dt * 16 + quad * 4) = z.u;
        }
        if (quad == 0)
            Ml[(size_t)(sp * BATCH * SEQ) * NHEADS + R * NHEADS + h] = make_float2(m_r[nt], l);
    }
}

// ============================================================================
// attn_merge: flash-combine of the two K-split partials -> Oh (hi fp16 only;
// gemm_out is now hi-only on A).
// ============================================================================
__global__ __launch_bounds__(256)
void attn_merge(const _Float16* __restrict__ Op0, const _Float16* __restrict__ Op1,
                const float2* __restrict__ Ml, _Float16* __restrict__ Oh) {
    const int i4 = (blockIdx.x * 256 + threadIdx.x) * 4;
    const int R = i4 >> 9;
    const int c = i4 & 511;
    const int h = c >> 6;

    const float2 ml1 = Ml[(size_t)R * NHEADS + h];
    const float2 ml2 = Ml[(size_t)(BATCH * SEQ) * NHEADS + (size_t)R * NHEADS + h];
    const float m = fmaxf(ml1.x, ml2.x);
    float w1 = EXP2F(ml1.x - m) * ml1.y;
    float w2 = EXP2F(ml2.x - m) * ml2.y;
    const float inv = 1.0f / (w1 + w2);
    w1 *= inv; w2 *= inv;

    Un4 a, bb;
    a.u  = *(const uint2*)(Op0 + (size_t)R * 512 + c);
    bb.u = *(const uint2*)(Op1 + (size_t)R * 512 + c);

    Pkz hh;
    hh.h2[0] = __builtin_amdgcn_cvt_pkrtz(w1 * (float)a.h[0] + w2 * (float)bb.h[0],
                                          w1 * (float)a.h[1] + w2 * (float)bb.h[1]);
    hh.h2[1] = __builtin_amdgcn_cvt_pkrtz(w1 * (float)a.h[2] + w2 * (float)bb.h[2],
                                          w1 * (float)a.h[3] + w2 * (float)bb.h[3]);
    *(uint2*)(Oh + (size_t)R * 512 + c) = hh.u;
}

// ============================================================================
// Output projection: hi-only A and W (1 MFMA/tile). Double-buffered DMA.
// Block 128x64, LDS 48 KB -> 3 blocks/CU. fp32 out + bias.
// ============================================================================
__global__ __launch_bounds__(256)
void gemm_out(const _Float16* __restrict__ Ah, const _Float16* __restrict__ Wh,
              const float* __restrict__ bias, float* __restrict__ C) {
    __shared__ __align__(16) _Float16 sAh[2][128 * 64];
    __shared__ __align__(16) _Float16 sWh[2][64 * 64];

    const int t    = threadIdx.x;
    const int lane = t & 63, wave = t >> 6;
    const int col  = lane & 15, quad = lane >> 4;
    const int wm   = (wave & 1) * 64, wn = (wave >> 1) * 32;
    const int m0   = blockIdx.y * 128, n0 = blockIdx.x * 64;

    const int subrow = lane >> 3;
    const int schunk = ((lane & 7) ^ subrow) * 8;

    #define STAGE_OUT(K0, BUF)                                                       \
        do {                                                                          \
            _Pragma("unroll")                                                         \
            for (int j = 0; j < 4; ++j) {                                             \
                const int rw = wave * 32 + j * 8;                                     \
                gload_lds16(Ah + (size_t)(m0 + rw + subrow) * 512 + (K0) + schunk,    \
                            &sAh[BUF][rw * 64]);                                      \
            }                                                                         \
            _Pragma("unroll")                                                         \
            for (int j = 0; j < 2; ++j) {                                             \
                const int rw = wave * 16 + j * 8;                                     \
                gload_lds16(Wh + (size_t)(n0 + rw + subrow) * 512 + (K0) + schunk,    \
                            &sWh[BUF][rw * 64]);                                      \
            }                                                                         \
        } while (0)

    f32x4 acc[4][2] = {};

    STAGE_OUT(0, 0);
    for (int ck = 0; ck < 8; ++ck) {
        const int cur = ck & 1;
        __syncthreads();
        if (ck + 1 < 8) STAGE_OUT((ck + 1) * 64, cur ^ 1);

        #pragma unroll
        for (int kc = 0; kc < 2; ++kc) {
            const int pos = ((kc * 4 + quad) ^ (col & 7)) * 8;
            half8 ahf[4], whf[2];
            #pragma unroll
            for (int mt = 0; mt < 4; ++mt)
                ahf[mt] = *(const half8*)&sAh[cur][(wm + mt * 16 + col) * 64 + pos];
            #pragma unroll
            for (int nt = 0; nt < 2; ++nt)
                whf[nt] = *(const half8*)&sWh[cur][(wn + nt * 16 + col) * 64 + pos];
            #pragma unroll
            for (int mt = 0; mt < 4; ++mt)
                #pragma unroll
                for (int nt = 0; nt < 2; ++nt)
                    acc[mt][nt] = MFMA16(ahf[mt], whf[nt], acc[mt][nt]);
        }
    }

    float bv2[2];
    #pragma unroll
    for (int nt = 0; nt < 2; ++nt) bv2[nt] = bias[n0 + wn + nt * 16 + col];

    #pragma unroll
    for (int mt = 0; mt < 4; ++mt) {
        const int m = m0 + wm + mt * 16 + quad * 4;
        #pragma unroll
        for (int nt = 0; nt < 2; ++nt) {
            const int n = n0 + wn + nt * 16 + col;
            #pragma unroll
            for (int r = 0; r < 4; ++r)
                C[(size_t)(m + r) * 512 + n] = acc[mt][nt][r] + bv2[nt];
        }
    }
}

// ============================================================================
extern "C" void kernel_launch(void* const* d_in, const int* in_sizes, int n_in,
                              void* d_out, int out_size, void* d_ws, size_t ws_size,
                              hipStream_t stream) {
    const float* query = (const float*)d_in[0];
    const float* key   = (const float*)d_in[1];
    const float* value = (const float*)d_in[2];
    const float* w_q   = (const float*)d_in[3];
    const float* b_q   = (const float*)d_in[4];
    const float* w_k   = (const float*)d_in[5];
    const float* b_k   = (const float*)d_in[6];
    const float* w_v   = (const float*)d_in[7];
    const float* b_v   = (const float*)d_in[8];
    const float* w_o   = (const float*)d_in[9];
    const float* b_o   = (const float*)d_in[10];
    float* out = (float*)d_out;

    const int WN = D_MODEL * D_MODEL;                     // 262144
    const size_t plane = (size_t)BATCH * SEQ * D_MODEL;   // 4.19M halves

    _Float16* base = (_Float16*)d_ws;
    _Float16* Aq16 = base;                 // -> Oh after qkv
    _Float16* Ak16 = Aq16 + plane;
    _Float16* Av16 = Ak16 + plane;         // -> Op0 after qkv
    _Float16* whq  = Av16 + plane;
    _Float16* whk  = whq + WN;
    _Float16* whv  = whk + WN;
    _Float16* who  = whv + WN;
    _Float16* Qf   = who + WN;
    _Float16* Kf   = Qf + plane;
    _Float16* Vtf  = Kf + plane;
    _Float16* Op1  = Vtf + plane;
    float2*   Ml   = (float2*)(Op1 + plane);  // 2*BATCH*SEQ*NHEADS float2 = 1 MB
    _Float16* Oh   = Aq16;
    _Float16* Op0  = Av16;

    dim3 blk(256);

    hipLaunchKernelGGL(prep, dim3(3 * ABLK + 4 * WBLK), blk, 0, stream,
                       query, key, value, w_q, w_k, w_v, w_o,
                       Aq16, Ak16, Av16, whq, whk, whv, who);

    hipLaunchKernelGGL(gemm_qkv, dim3(D_MODEL / 128, BATCH * SEQ / 128, 3), blk, 0, stream,
                       Aq16, Ak16, Av16,
                       whq, whk, whv,
                       b_q, b_k, b_v, Qf, Kf, Vtf);

    hipLaunchKernelGGL(attn_mfma, dim3(SEQ / 128, NHEADS, BATCH * 2), blk, 0, stream,
                       Qf, Kf, Vtf, Op0, Op1, Ml);

    hipLaunchKernelGGL(attn_merge, dim3(BATCH * SEQ * D_MODEL / 4 / 256), blk, 0, stream,
                       Op0, Op1, Ml, Oh);

    hipLaunchKernelGGL(gemm_out, dim3(D_MODEL / 64, BATCH * SEQ / 128), blk, 0, stream,
                       Oh, who, b_o, out);
}